// Round 1
// baseline (539.934 us; speedup 1.0000x reference)
//
#include <hip/hip_runtime.h>

// Problem constants (from reference): V=128, E=256, H=4, B=1024, L=64
// Workspace layout (floats):
//   pos[64*256] | posmean[256] | x2t[8192*256] f32 | qkvt[8192*3072] bf16 | attn_out[1024*1024] f32
// Total ~63 MB.

__device__ __forceinline__ float wred_sum(float v) {
#pragma unroll
  for (int off = 32; off > 0; off >>= 1) v += __shfl_xor(v, off, 64);
  return v;
}
__device__ __forceinline__ float wred_max(float v) {
#pragma unroll
  for (int off = 32; off > 0; off >>= 1) v = fmaxf(v, __shfl_xor(v, off, 64));
  return v;
}
__device__ __forceinline__ float bf2f(unsigned short u) {
  union { unsigned int i; float f; } x; x.i = ((unsigned int)u) << 16; return x.f;
}
__device__ __forceinline__ unsigned short f2bf(float f) {
  union { float f; unsigned int i; } x; x.f = f;
  unsigned int r = x.i + 0x7FFFu + ((x.i >> 16) & 1u);
  return (unsigned short)(r >> 16);
}

// ---------------- pos table ----------------
__global__ __launch_bounds__(256) void pos_kernel(float* pos) {
  int idx = blockIdx.x * 256 + threadIdx.x;   // 0..16383
  int l = idx >> 8, e = idx & 255;
  int i = e >> 1;
  float freq = powf(10000.0f, -(float)i * (1.0f / 128.0f));
  float ph = (float)l * freq;
  pos[idx] = (e & 1) ? cosf(ph) : sinf(ph);
}

__global__ __launch_bounds__(256) void posmean_kernel(const float* pos, float* posmean) {
  int e = threadIdx.x;
  float s = 0.f;
#pragma unroll 8
  for (int l = 0; l < 64; l++) s += pos[l * 256 + e];
  posmean[e] = s * (1.0f / 64.0f);
}

// ---------------- x2 table: LN0(emb[c]+pos[l]) + pos[l], 8192 rows ----------------
__global__ __launch_bounds__(256) void x2t_kernel(const float* emb, const float* pos,
                                                  const float* g, const float* b, float* x2t) {
  int w = threadIdx.x >> 6, lane = threadIdx.x & 63;
  int row = blockIdx.x * 4 + w;               // 0..8191
  int c = row >> 6, l = row & 63;
  int e0 = lane * 4;
  float4 ev = *(const float4*)(emb + c * 256 + e0);
  float4 pv = *(const float4*)(pos + l * 256 + e0);
  float v0 = ev.x + pv.x, v1 = ev.y + pv.y, v2 = ev.z + pv.z, v3 = ev.w + pv.w;
  float s = wred_sum(v0 + v1 + v2 + v3);
  float q = wred_sum(v0 * v0 + v1 * v1 + v2 * v2 + v3 * v3);
  float mean = s * (1.0f / 256.0f);
  float var = q * (1.0f / 256.0f) - mean * mean;
  float rstd = rsqrtf(var + 1e-5f);
  float4 gv = *(const float4*)(g + e0);
  float4 bv = *(const float4*)(b + e0);
  float4 o;
  o.x = (v0 - mean) * rstd * gv.x + bv.x + pv.x;
  o.y = (v1 - mean) * rstd * gv.y + bv.y + pv.y;
  o.z = (v2 - mean) * rstd * gv.z + bv.z + pv.z;
  o.w = (v3 - mean) * rstd * gv.w + bv.w + pv.w;
  *(float4*)(x2t + (size_t)row * 256 + e0) = o;
}

// ---------------- QKV table GEMM: (8192x256)@(256x3072)^T-layout, store bf16 ----------------
__global__ __launch_bounds__(256) void qkvt_kernel(const float* x2t, const float* qkv_w,
                                                   unsigned short* qkvt) {
  __shared__ float As[64][65];
  __shared__ float Bs[64][65];
  int t = threadIdx.x, tx = t & 15, ty = t >> 4;
  int n0 = blockIdx.x * 64;                   // 0..3071 (48 tiles)
  int m0 = blockIdx.y * 64;                   // 0..8191 (128 tiles)
  float acc[4][4] = {};
  for (int kc = 0; kc < 4; kc++) {
#pragma unroll
    for (int ii = 0; ii < 4; ii++) {
      int r = (t >> 4) + 16 * ii;
      int e4 = (t & 15) * 4;
      float4 a = *(const float4*)(x2t + (size_t)(m0 + r) * 256 + kc * 64 + e4);
      As[r][e4] = a.x; As[r][e4 + 1] = a.y; As[r][e4 + 2] = a.z; As[r][e4 + 3] = a.w;
      float4 bb = *(const float4*)(qkv_w + (size_t)(n0 + r) * 256 + kc * 64 + e4);
      Bs[r][e4] = bb.x; Bs[r][e4 + 1] = bb.y; Bs[r][e4 + 2] = bb.z; Bs[r][e4 + 3] = bb.w;
    }
    __syncthreads();
#pragma unroll 4
    for (int e = 0; e < 64; e++) {
      float a0 = As[ty * 4 + 0][e], a1 = As[ty * 4 + 1][e];
      float a2 = As[ty * 4 + 2][e], a3 = As[ty * 4 + 3][e];
      float b0 = Bs[tx * 4 + 0][e], b1 = Bs[tx * 4 + 1][e];
      float b2 = Bs[tx * 4 + 2][e], b3 = Bs[tx * 4 + 3][e];
      acc[0][0] = fmaf(a0, b0, acc[0][0]); acc[0][1] = fmaf(a0, b1, acc[0][1]);
      acc[0][2] = fmaf(a0, b2, acc[0][2]); acc[0][3] = fmaf(a0, b3, acc[0][3]);
      acc[1][0] = fmaf(a1, b0, acc[1][0]); acc[1][1] = fmaf(a1, b1, acc[1][1]);
      acc[1][2] = fmaf(a1, b2, acc[1][2]); acc[1][3] = fmaf(a1, b3, acc[1][3]);
      acc[2][0] = fmaf(a2, b0, acc[2][0]); acc[2][1] = fmaf(a2, b1, acc[2][1]);
      acc[2][2] = fmaf(a2, b2, acc[2][2]); acc[2][3] = fmaf(a2, b3, acc[2][3]);
      acc[3][0] = fmaf(a3, b0, acc[3][0]); acc[3][1] = fmaf(a3, b1, acc[3][1]);
      acc[3][2] = fmaf(a3, b2, acc[3][2]); acc[3][3] = fmaf(a3, b3, acc[3][3]);
    }
    __syncthreads();
  }
#pragma unroll
  for (int i = 0; i < 4; i++)
#pragma unroll
    for (int j = 0; j < 4; j++)
      qkvt[(size_t)(m0 + ty * 4 + i) * 3072 + n0 + tx * 4 + j] = f2bf(acc[i][j]);
}

// ---------------- attention per (b,h) ----------------
__device__ __forceinline__ void stage_rows(float dst[64][65], const unsigned short* qkvt,
                                           const int* s_cc, int h, int sel, int ec, int t) {
  int half = t >> 5;            // 0..7 : half-wave handles one row (32 lanes x ushort2)
  int el = (t & 31) * 2;        // 0..62
#pragma unroll
  for (int it = 0; it < 8; it++) {
    int r = it * 8 + half;
    int g = s_cc[r] * 64 + r;   // row in table
    const unsigned short* p = qkvt + (size_t)g * 3072 + h * 768 + sel + ec * 64 + el;
    ushort2 u = *(const ushort2*)p;
    dst[r][el] = bf2f(u.x);
    dst[r][el + 1] = bf2f(u.y);
  }
}

__global__ __launch_bounds__(256) void attn_kernel(const int* cc, const unsigned short* qkvt,
                                                   float* attn_out) {
  __shared__ float Qs[64][65];   // also reused as Vs
  __shared__ float Ks[64][65];
  __shared__ float Ss[64][65];
  __shared__ float s_sp[4][64];
  __shared__ float s_score[64];
  __shared__ float s_nm[64];
  __shared__ int s_cc[64];
  __shared__ float s_nwinv;
  int b = blockIdx.x >> 2, h = blockIdx.x & 3;
  int t = threadIdx.x, w = t >> 6, lane = t & 63;
  int tx = t & 15, ty = t >> 4;

  if (t < 64) {
    int c = cc[b * 64 + t];
    s_cc[t] = c;
    s_nm[t] = (c != 0) ? 1.0f : 0.0f;
  }
  __syncthreads();
  if (t < 64) {
    float s = wred_sum(s_nm[t]);
    if (t == 0) s_nwinv = 1.0f / s;
  }

  // ---- qk = Q @ K^T, E chunked by 64 ----
  float acc[4][4] = {};
  for (int ec = 0; ec < 4; ec++) {
    stage_rows(Qs, qkvt, s_cc, h, 0, ec, t);
    stage_rows(Ks, qkvt, s_cc, h, 256, ec, t);
    __syncthreads();
#pragma unroll 4
    for (int e = 0; e < 64; e++) {
      float a0 = Qs[ty * 4 + 0][e], a1 = Qs[ty * 4 + 1][e];
      float a2 = Qs[ty * 4 + 2][e], a3 = Qs[ty * 4 + 3][e];
      float b0 = Ks[tx * 4 + 0][e], b1 = Ks[tx * 4 + 1][e];
      float b2 = Ks[tx * 4 + 2][e], b3 = Ks[tx * 4 + 3][e];
      acc[0][0] = fmaf(a0, b0, acc[0][0]); acc[0][1] = fmaf(a0, b1, acc[0][1]);
      acc[0][2] = fmaf(a0, b2, acc[0][2]); acc[0][3] = fmaf(a0, b3, acc[0][3]);
      acc[1][0] = fmaf(a1, b0, acc[1][0]); acc[1][1] = fmaf(a1, b1, acc[1][1]);
      acc[1][2] = fmaf(a1, b2, acc[1][2]); acc[1][3] = fmaf(a1, b3, acc[1][3]);
      acc[2][0] = fmaf(a2, b0, acc[2][0]); acc[2][1] = fmaf(a2, b1, acc[2][1]);
      acc[2][2] = fmaf(a2, b2, acc[2][2]); acc[2][3] = fmaf(a2, b3, acc[2][3]);
      acc[3][0] = fmaf(a3, b0, acc[3][0]); acc[3][1] = fmaf(a3, b1, acc[3][1]);
      acc[3][2] = fmaf(a3, b2, acc[3][2]); acc[3][3] = fmaf(a3, b3, acc[3][3]);
    }
    __syncthreads();
  }
#pragma unroll
  for (int i = 0; i < 4; i++)
#pragma unroll
    for (int j = 0; j < 4; j++)
      Ss[ty * 4 + i][tx * 4 + j] = acc[i][j];
  __syncthreads();

  // ---- masked softmax (wave-parallel: lane = key) + query-averaged score ----
  float sp = 0.f;
#pragma unroll 2
  for (int i = 0; i < 16; i++) {
    int q = w * 16 + i;
    float v = Ss[q][lane] * 0.0625f;          // / sqrt(256)
    bool kmask = (s_cc[lane] == 0);
    if (kmask) v = -1e30f;
    float m = wred_max(v);
    float p = kmask ? 0.f : __expf(v - m);
    float ssum = wred_sum(p);
    sp += s_nm[q] * (p / ssum);
  }
  s_sp[w][lane] = sp;
  __syncthreads();
  if (t < 64) {
    s_score[t] = (s_sp[0][t] + s_sp[1][t] + s_sp[2][t] + s_sp[3][t]) * s_nwinv;
  }
  __syncthreads();

  // ---- out_h[e] = sum_k score[k] * V[k][e], E chunked by 64 (V aliases Qs) ----
  for (int ec = 0; ec < 4; ec++) {
    stage_rows(Qs, qkvt, s_cc, h, 512, ec, t);
    __syncthreads();
    if (t < 64) {
      float a = 0.f;
#pragma unroll 8
      for (int k = 0; k < 64; k++) a += s_score[k] * Qs[k][t];
      attn_out[b * 1024 + h * 256 + ec * 64 + t] = a;
    }
    __syncthreads();
  }
}

// ---------------- final: xmean gather + fc + LN chain ----------------
__device__ __forceinline__ float block_ln(float v, int t, float eps, const float* g,
                                          const float* b, float* s_part) {
  int w = t >> 6, lane = t & 63;
  __syncthreads();
  float s = wred_sum(v), q = wred_sum(v * v);
  if (lane == 0) { s_part[w] = s; s_part[4 + w] = q; }
  __syncthreads();
  float sum = s_part[0] + s_part[1] + s_part[2] + s_part[3];
  float sq = s_part[4] + s_part[5] + s_part[6] + s_part[7];
  float mean = sum * (1.0f / 256.0f);
  float var = sq * (1.0f / 256.0f) - mean * mean;
  float rstd = rsqrtf(var + eps);
  return (v - mean) * rstd * g[t] + b[t];
}

__global__ __launch_bounds__(256) void final_kernel(
    const int* cc, const float* x2t, const float* posmean, const float* ao,
    const float* fc_w, const float* fc_b,
    const float* sln_g, const float* sln_b, const float* ln1_g, const float* ln1_b,
    const float* ffln_g, const float* ffln_b, const float* ln2_g, const float* ln2_b,
    float* out) {
  __shared__ int s_cc[64];
  __shared__ float s_ao[1024];
  __shared__ float s_out[256];
  __shared__ float s_part[8];
  int b = blockIdx.x, t = threadIdx.x, w = t >> 6, lane = t & 63;
  if (t < 64) s_cc[t] = cc[b * 64 + t];
  *(float4*)(s_ao + t * 4) = *(const float4*)(ao + b * 1024 + t * 4);
  __syncthreads();

  // x.mean(1)[e] = mean_l x2t_row - posmean (x2t stores x+pos)
  float xa = 0.f;
#pragma unroll 8
  for (int l = 0; l < 64; l++) xa += x2t[(size_t)(s_cc[l] * 64 + l) * 256 + t];
  float xm = xa * (1.0f / 64.0f) - posmean[t];

  // fc: out[i] = fc_w[i,:] . ao[:]  (wave computes 64 rows, lanes j-parallel)
  for (int ii = 0; ii < 64; ii++) {
    int i = w * 64 + ii;
    const float4* wr = (const float4*)(fc_w + (size_t)i * 1024);
    float p = 0.f;
#pragma unroll
    for (int c4 = 0; c4 < 4; c4++) {
      float4 wv = wr[c4 * 64 + lane];
      float4 av = *(const float4*)(s_ao + c4 * 256 + lane * 4);
      p = fmaf(wv.x, av.x, p); p = fmaf(wv.y, av.y, p);
      p = fmaf(wv.z, av.z, p); p = fmaf(wv.w, av.w, p);
    }
    p = wred_sum(p);
    if (lane == 0) s_out[i] = p + fc_b[i];
  }
  __syncthreads();

  float v = s_out[t];
  v = block_ln(v, t, 1e-5f, sln_g, sln_b, s_part);        // sln
  v = v + xm;
  v = block_ln(v, t, 1e-5f, ln1_g, ln1_b, s_part);        // ln1 -> word
  float ff = block_ln(v, t, 1e-6f, ffln_g, ffln_b, s_part); // ffln
  float w2 = ff + v;
  float fin = block_ln(w2, t, 1e-5f, ln2_g, ln2_b, s_part); // ln2
  out[b * 256 + t] = fin;
}

extern "C" void kernel_launch(void* const* d_in, const int* in_sizes, int n_in,
                              void* d_out, int out_size, void* d_ws, size_t ws_size,
                              hipStream_t stream) {
  const int* char_code = (const int*)d_in[0];
  // d_in[1] = max_len (always 64 here)
  const float* emb    = (const float*)d_in[2];
  const float* qkv_w  = (const float*)d_in[3];
  const float* ln0_g  = (const float*)d_in[4];
  const float* ln0_b  = (const float*)d_in[5];
  const float* fc_w   = (const float*)d_in[6];
  const float* fc_b   = (const float*)d_in[7];
  const float* sln_g  = (const float*)d_in[8];
  const float* sln_b  = (const float*)d_in[9];
  const float* ln1_g  = (const float*)d_in[10];
  const float* ln1_b  = (const float*)d_in[11];
  const float* ffln_g = (const float*)d_in[16];
  const float* ffln_b = (const float*)d_in[17];
  const float* ln2_g  = (const float*)d_in[18];
  const float* ln2_b  = (const float*)d_in[19];

  float* ws = (float*)d_ws;
  float* pos = ws;                                   // 16384 f32
  float* posmean = pos + 16384;                      // 256 f32
  float* x2t = posmean + 256;                        // 8192*256 f32
  unsigned short* qkvt = (unsigned short*)(x2t + (size_t)8192 * 256); // 8192*3072 bf16
  float* attn_out = (float*)(qkvt + (size_t)8192 * 3072);             // 1024*1024 f32

  pos_kernel<<<64, 256, 0, stream>>>(pos);
  posmean_kernel<<<1, 256, 0, stream>>>(pos, posmean);
  x2t_kernel<<<2048, 256, 0, stream>>>(emb, pos, ln0_g, ln0_b, x2t);
  qkvt_kernel<<<dim3(48, 128), 256, 0, stream>>>(x2t, qkv_w, qkvt);
  attn_kernel<<<4096, 256, 0, stream>>>(char_code, qkvt, attn_out);
  final_kernel<<<1024, 256, 0, stream>>>(char_code, x2t, posmean, attn_out,
                                         fc_w, fc_b, sln_g, sln_b, ln1_g, ln1_b,
                                         ffln_g, ffln_b, ln2_g, ln2_b, (float*)d_out);
}

// Round 2
// 326.958 us; speedup vs baseline: 1.6514x; 1.6514x over previous
//
#include <hip/hip_runtime.h>

// Problem constants: V=128, E=256, H=4, B=1024, L=64
// Workspace layout:
//   pos[16384] f32 | posmean[256] f32 | x2t[8192*256] f32 (8MB)
//   | qkvt[8192*3072] bf16 (50.3MB)
//   | x2tb[8192*256] bf16 (4MB)  -- ALIASED: attn_out[1024*1024] f32 (4MB) after qkvt GEMM
//   | wb[3072*256] bf16 (1.5MB)

typedef __attribute__((ext_vector_type(8))) short bf16x8;
typedef __attribute__((ext_vector_type(4))) float f32x4;

__device__ __forceinline__ float wred_sum(float v) {
#pragma unroll
  for (int off = 32; off > 0; off >>= 1) v += __shfl_xor(v, off, 64);
  return v;
}
__device__ __forceinline__ float wred_max(float v) {
#pragma unroll
  for (int off = 32; off > 0; off >>= 1) v = fmaxf(v, __shfl_xor(v, off, 64));
  return v;
}
__device__ __forceinline__ float bf2f(unsigned short u) {
  union { unsigned int i; float f; } x; x.i = ((unsigned int)u) << 16; return x.f;
}
__device__ __forceinline__ unsigned short f2bf(float f) {
  union { float f; unsigned int i; } x; x.f = f;
  unsigned int r = x.i + 0x7FFFu + ((x.i >> 16) & 1u);
  return (unsigned short)(r >> 16);
}

// ---------------- pos table ----------------
__global__ __launch_bounds__(256) void pos_kernel(float* pos) {
  int idx = blockIdx.x * 256 + threadIdx.x;   // 0..16383
  int l = idx >> 8, e = idx & 255;
  int i = e >> 1;
  float freq = powf(10000.0f, -(float)i * (1.0f / 128.0f));
  float ph = (float)l * freq;
  pos[idx] = (e & 1) ? cosf(ph) : sinf(ph);
}

__global__ __launch_bounds__(256) void posmean_kernel(const float* pos, float* posmean) {
  int e = threadIdx.x;
  float s = 0.f;
#pragma unroll 8
  for (int l = 0; l < 64; l++) s += pos[l * 256 + e];
  posmean[e] = s * (1.0f / 64.0f);
}

// ---------------- convert qkv_w to bf16 ----------------
__global__ __launch_bounds__(256) void cvt_w_kernel(const float* w, unsigned short* wb) {
  int i = (blockIdx.x * 256 + threadIdx.x) * 4;
  float4 v = *(const float4*)(w + i);
  ushort4 o = make_ushort4(f2bf(v.x), f2bf(v.y), f2bf(v.z), f2bf(v.w));
  *(ushort4*)(wb + i) = o;
}

// ---------------- x2 table: LN0(emb[c]+pos[l]) + pos[l], 8192 rows; f32 + bf16 ----------------
__global__ __launch_bounds__(256) void x2t_kernel(const float* emb, const float* pos,
                                                  const float* g, const float* b,
                                                  float* x2t, unsigned short* x2tb) {
  int w = threadIdx.x >> 6, lane = threadIdx.x & 63;
  int row = blockIdx.x * 4 + w;               // 0..8191
  int c = row >> 6, l = row & 63;
  int e0 = lane * 4;
  float4 ev = *(const float4*)(emb + c * 256 + e0);
  float4 pv = *(const float4*)(pos + l * 256 + e0);
  float v0 = ev.x + pv.x, v1 = ev.y + pv.y, v2 = ev.z + pv.z, v3 = ev.w + pv.w;
  float s = wred_sum(v0 + v1 + v2 + v3);
  float q = wred_sum(v0 * v0 + v1 * v1 + v2 * v2 + v3 * v3);
  float mean = s * (1.0f / 256.0f);
  float var = q * (1.0f / 256.0f) - mean * mean;
  float rstd = rsqrtf(var + 1e-5f);
  float4 gv = *(const float4*)(g + e0);
  float4 bv = *(const float4*)(b + e0);
  float4 o;
  o.x = (v0 - mean) * rstd * gv.x + bv.x + pv.x;
  o.y = (v1 - mean) * rstd * gv.y + bv.y + pv.y;
  o.z = (v2 - mean) * rstd * gv.z + bv.z + pv.z;
  o.w = (v3 - mean) * rstd * gv.w + bv.w + pv.w;
  *(float4*)(x2t + (size_t)row * 256 + e0) = o;
  ushort4 ob = make_ushort4(f2bf(o.x), f2bf(o.y), f2bf(o.z), f2bf(o.w));
  *(ushort4*)(x2tb + (size_t)row * 256 + e0) = ob;
}

// ---------------- QKV table GEMM via MFMA: (8192x256)@(3072x256)^T -> bf16 ----------------
// 128x128 tile, 4 waves (2x2), BK=64, global_load_lds staging, linear LDS.
__global__ __launch_bounds__(256) void qkvt_mfma_kernel(const unsigned short* x2tb,
                                                        const unsigned short* wb,
                                                        unsigned short* qkvt) {
  __shared__ unsigned short S[2 * 128 * 64];  // As | Bs ; reused as Cs (128x128)
  unsigned short* As = S;
  unsigned short* Bs = S + 128 * 64;
  int t = threadIdx.x, w = t >> 6, lane = t & 63;
  int m0 = blockIdx.y * 128, n0 = blockIdx.x * 128;
  int wr = w >> 1, wc = w & 1;
  f32x4 acc[4][4] = {};
  int r_in = lane >> 3;              // 0..7 row within 8-row block
  int cb = (lane & 7) * 8;           // 0..56 bf16 col (16B granules)
  for (int kt = 0; kt < 4; ++kt) {
#pragma unroll
    for (int it = 0; it < 4; ++it) {
      int rowblk = it * 32 + w * 8;  // wave-uniform
      const unsigned short* ga = x2tb + (size_t)(m0 + rowblk + r_in) * 256 + kt * 64 + cb;
      __builtin_amdgcn_global_load_lds(
          (const __attribute__((address_space(1))) unsigned int*)ga,
          (__attribute__((address_space(3))) unsigned int*)(As + rowblk * 64), 16, 0, 0);
      const unsigned short* gb = wb + (size_t)(n0 + rowblk + r_in) * 256 + kt * 64 + cb;
      __builtin_amdgcn_global_load_lds(
          (const __attribute__((address_space(1))) unsigned int*)gb,
          (__attribute__((address_space(3))) unsigned int*)(Bs + rowblk * 64), 16, 0, 0);
    }
    __syncthreads();
#pragma unroll
    for (int kk = 0; kk < 2; ++kk) {
      bf16x8 af[4], bfr[4];
#pragma unroll
      for (int m = 0; m < 4; ++m)
        af[m] = *(const bf16x8*)(As + (wr * 64 + m * 16 + (lane & 15)) * 64 + kk * 32 + (lane >> 4) * 8);
#pragma unroll
      for (int n = 0; n < 4; ++n)
        bfr[n] = *(const bf16x8*)(Bs + (wc * 64 + n * 16 + (lane & 15)) * 64 + kk * 32 + (lane >> 4) * 8);
#pragma unroll
      for (int m = 0; m < 4; ++m)
#pragma unroll
        for (int n = 0; n < 4; ++n)
          acc[m][n] = __builtin_amdgcn_mfma_f32_16x16x32_bf16(af[m], bfr[n], acc[m][n], 0, 0, 0);
    }
    __syncthreads();
  }
  // C repack through LDS (Cs aliases S) for coalesced 16B global stores
  unsigned short* Cs = S;
#pragma unroll
  for (int m = 0; m < 4; ++m)
#pragma unroll
    for (int n = 0; n < 4; ++n) {
      int row = wr * 64 + m * 16 + (lane >> 4) * 4;
      int col = wc * 64 + n * 16 + (lane & 15);
#pragma unroll
      for (int j = 0; j < 4; ++j)
        Cs[(row + j) * 128 + col] = f2bf(acc[m][n][j]);
    }
  __syncthreads();
#pragma unroll
  for (int it = 0; it < 8; ++it) {
    int row = it * 16 + (t >> 4);
    int ce = (t & 15) * 8;
    *(bf16x8*)(qkvt + (size_t)(m0 + row) * 3072 + n0 + ce) =
        *(const bf16x8*)(Cs + row * 128 + ce);
  }
}

// ---------------- attention per (b,h) ----------------
__device__ __forceinline__ void stage_rows(float dst[64][65], const unsigned short* qkvt,
                                           const int* s_cc, int h, int sel, int ec, int t) {
  int half = t >> 5;            // 0..7 : half-wave handles one row (32 lanes x ushort2)
  int el = (t & 31) * 2;        // 0..62
#pragma unroll
  for (int it = 0; it < 8; it++) {
    int r = it * 8 + half;
    int g = s_cc[r] * 64 + r;   // row in table
    const unsigned short* p = qkvt + (size_t)g * 3072 + h * 768 + sel + ec * 64 + el;
    ushort2 u = *(const ushort2*)p;
    dst[r][el] = bf2f(u.x);
    dst[r][el + 1] = bf2f(u.y);
  }
}

__global__ __launch_bounds__(256) void attn_kernel(const int* cc, const unsigned short* qkvt,
                                                   float* attn_out) {
  __shared__ float Qs[64][65];   // also reused as Vs
  __shared__ float Ks[64][65];
  __shared__ float Ss[64][65];
  __shared__ float s_sp[4][64];
  __shared__ float s_score[64];
  __shared__ float s_nm[64];
  __shared__ int s_cc[64];
  __shared__ float s_nwinv;
  int b = blockIdx.x >> 2, h = blockIdx.x & 3;
  int t = threadIdx.x, w = t >> 6, lane = t & 63;
  int tx = t & 15, ty = t >> 4;

  if (t < 64) {
    int c = cc[b * 64 + t];
    s_cc[t] = c;
    s_nm[t] = (c != 0) ? 1.0f : 0.0f;
  }
  __syncthreads();
  if (t < 64) {
    float s = wred_sum(s_nm[t]);
    if (t == 0) s_nwinv = 1.0f / s;
  }

  // ---- qk = Q @ K^T, E chunked by 64 ----
  float acc[4][4] = {};
  for (int ec = 0; ec < 4; ec++) {
    stage_rows(Qs, qkvt, s_cc, h, 0, ec, t);
    stage_rows(Ks, qkvt, s_cc, h, 256, ec, t);
    __syncthreads();
#pragma unroll 4
    for (int e = 0; e < 64; e++) {
      float a0 = Qs[ty * 4 + 0][e], a1 = Qs[ty * 4 + 1][e];
      float a2 = Qs[ty * 4 + 2][e], a3 = Qs[ty * 4 + 3][e];
      float b0 = Ks[tx * 4 + 0][e], b1 = Ks[tx * 4 + 1][e];
      float b2 = Ks[tx * 4 + 2][e], b3 = Ks[tx * 4 + 3][e];
      acc[0][0] = fmaf(a0, b0, acc[0][0]); acc[0][1] = fmaf(a0, b1, acc[0][1]);
      acc[0][2] = fmaf(a0, b2, acc[0][2]); acc[0][3] = fmaf(a0, b3, acc[0][3]);
      acc[1][0] = fmaf(a1, b0, acc[1][0]); acc[1][1] = fmaf(a1, b1, acc[1][1]);
      acc[1][2] = fmaf(a1, b2, acc[1][2]); acc[1][3] = fmaf(a1, b3, acc[1][3]);
      acc[2][0] = fmaf(a2, b0, acc[2][0]); acc[2][1] = fmaf(a2, b1, acc[2][1]);
      acc[2][2] = fmaf(a2, b2, acc[2][2]); acc[2][3] = fmaf(a2, b3, acc[2][3]);
      acc[3][0] = fmaf(a3, b0, acc[3][0]); acc[3][1] = fmaf(a3, b1, acc[3][1]);
      acc[3][2] = fmaf(a3, b2, acc[3][2]); acc[3][3] = fmaf(a3, b3, acc[3][3]);
    }
    __syncthreads();
  }
#pragma unroll
  for (int i = 0; i < 4; i++)
#pragma unroll
    for (int j = 0; j < 4; j++)
      Ss[ty * 4 + i][tx * 4 + j] = acc[i][j];
  __syncthreads();

  // ---- masked softmax (wave-parallel: lane = key) + query-averaged score ----
  float sp = 0.f;
#pragma unroll 2
  for (int i = 0; i < 16; i++) {
    int q = w * 16 + i;
    float v = Ss[q][lane] * 0.0625f;          // / sqrt(256)
    bool kmask = (s_cc[lane] == 0);
    if (kmask) v = -1e30f;
    float m = wred_max(v);
    float p = kmask ? 0.f : __expf(v - m);
    float ssum = wred_sum(p);
    sp += s_nm[q] * (p / ssum);
  }
  s_sp[w][lane] = sp;
  __syncthreads();
  if (t < 64) {
    s_score[t] = (s_sp[0][t] + s_sp[1][t] + s_sp[2][t] + s_sp[3][t]) * s_nwinv;
  }
  __syncthreads();

  // ---- out_h[e] = sum_k score[k] * V[k][e], E chunked by 64 (V aliases Qs) ----
  for (int ec = 0; ec < 4; ec++) {
    stage_rows(Qs, qkvt, s_cc, h, 512, ec, t);
    __syncthreads();
    if (t < 64) {
      float a = 0.f;
#pragma unroll 8
      for (int k = 0; k < 64; k++) a += s_score[k] * Qs[k][t];
      attn_out[b * 1024 + h * 256 + ec * 64 + t] = a;
    }
    __syncthreads();
  }
}

// ---------------- final: xmean gather + fc + LN chain ----------------
__device__ __forceinline__ float block_ln(float v, int t, float eps, const float* g,
                                          const float* b, float* s_part) {
  int w = t >> 6, lane = t & 63;
  __syncthreads();
  float s = wred_sum(v), q = wred_sum(v * v);
  if (lane == 0) { s_part[w] = s; s_part[4 + w] = q; }
  __syncthreads();
  float sum = s_part[0] + s_part[1] + s_part[2] + s_part[3];
  float sq = s_part[4] + s_part[5] + s_part[6] + s_part[7];
  float mean = sum * (1.0f / 256.0f);
  float var = sq * (1.0f / 256.0f) - mean * mean;
  float rstd = rsqrtf(var + eps);
  return (v - mean) * rstd * g[t] + b[t];
}

__global__ __launch_bounds__(256) void final_kernel(
    const int* cc, const float* x2t, const float* posmean, const float* ao,
    const float* fc_w, const float* fc_b,
    const float* sln_g, const float* sln_b, const float* ln1_g, const float* ln1_b,
    const float* ffln_g, const float* ffln_b, const float* ln2_g, const float* ln2_b,
    float* out) {
  __shared__ int s_cc[64];
  __shared__ float s_ao[1024];
  __shared__ float s_out[256];
  __shared__ float s_part[8];
  int b = blockIdx.x, t = threadIdx.x, w = t >> 6, lane = t & 63;
  if (t < 64) s_cc[t] = cc[b * 64 + t];
  *(float4*)(s_ao + t * 4) = *(const float4*)(ao + b * 1024 + t * 4);
  __syncthreads();

  // x.mean(1)[e] = mean_l x2t_row - posmean (x2t stores x+pos)
  float xa = 0.f;
#pragma unroll 8
  for (int l = 0; l < 64; l++) xa += x2t[(size_t)(s_cc[l] * 64 + l) * 256 + t];
  float xm = xa * (1.0f / 64.0f) - posmean[t];

  // fc: out[i] = fc_w[i,:] . ao[:]  (wave computes 64 rows, lanes j-parallel)
  for (int ii = 0; ii < 64; ii++) {
    int i = w * 64 + ii;
    const float4* wr = (const float4*)(fc_w + (size_t)i * 1024);
    float p = 0.f;
#pragma unroll
    for (int c4 = 0; c4 < 4; c4++) {
      float4 wv = wr[c4 * 64 + lane];
      float4 av = *(const float4*)(s_ao + c4 * 256 + lane * 4);
      p = fmaf(wv.x, av.x, p); p = fmaf(wv.y, av.y, p);
      p = fmaf(wv.z, av.z, p); p = fmaf(wv.w, av.w, p);
    }
    p = wred_sum(p);
    if (lane == 0) s_out[i] = p + fc_b[i];
  }
  __syncthreads();

  float v = s_out[t];
  v = block_ln(v, t, 1e-5f, sln_g, sln_b, s_part);        // sln
  v = v + xm;
  v = block_ln(v, t, 1e-5f, ln1_g, ln1_b, s_part);        // ln1 -> word
  float ff = block_ln(v, t, 1e-6f, ffln_g, ffln_b, s_part); // ffln
  float w2 = ff + v;
  float fin = block_ln(w2, t, 1e-5f, ln2_g, ln2_b, s_part); // ln2
  out[b * 256 + t] = fin;
}

extern "C" void kernel_launch(void* const* d_in, const int* in_sizes, int n_in,
                              void* d_out, int out_size, void* d_ws, size_t ws_size,
                              hipStream_t stream) {
  const int* char_code = (const int*)d_in[0];
  const float* emb    = (const float*)d_in[2];
  const float* qkv_w  = (const float*)d_in[3];
  const float* ln0_g  = (const float*)d_in[4];
  const float* ln0_b  = (const float*)d_in[5];
  const float* fc_w   = (const float*)d_in[6];
  const float* fc_b   = (const float*)d_in[7];
  const float* sln_g  = (const float*)d_in[8];
  const float* sln_b  = (const float*)d_in[9];
  const float* ln1_g  = (const float*)d_in[10];
  const float* ln1_b  = (const float*)d_in[11];
  const float* ffln_g = (const float*)d_in[16];
  const float* ffln_b = (const float*)d_in[17];
  const float* ln2_g  = (const float*)d_in[18];
  const float* ln2_b  = (const float*)d_in[19];

  float* ws = (float*)d_ws;
  float* pos = ws;                                        // 16384 f32
  float* posmean = pos + 16384;                           // 256 f32
  float* x2t = posmean + 256;                             // 8192*256 f32 (8MB)
  unsigned short* qkvt = (unsigned short*)(x2t + (size_t)8192 * 256);  // 50.3MB bf16
  unsigned short* x2tb = qkvt + (size_t)8192 * 3072;      // 4MB bf16
  float* attn_out = (float*)x2tb;                         // ALIAS: 4MB f32, written after GEMM
  unsigned short* wb = x2tb + (size_t)8192 * 256;         // 1.5MB bf16

  pos_kernel<<<64, 256, 0, stream>>>(pos);
  posmean_kernel<<<1, 256, 0, stream>>>(pos, posmean);
  cvt_w_kernel<<<768, 256, 0, stream>>>(qkv_w, wb);
  x2t_kernel<<<2048, 256, 0, stream>>>(emb, pos, ln0_g, ln0_b, x2t, x2tb);
  qkvt_mfma_kernel<<<dim3(24, 64), 256, 0, stream>>>(x2tb, wb, qkvt);
  attn_kernel<<<4096, 256, 0, stream>>>(char_code, qkvt, attn_out);
  final_kernel<<<1024, 256, 0, stream>>>(char_code, x2t, posmean, attn_out,
                                         fc_w, fc_b, sln_g, sln_b, ln1_g, ln1_b,
                                         ffln_g, ffln_b, ln2_g, ln2_b, (float*)d_out);
}

// Round 3
// 141.496 us; speedup vs baseline: 3.8159x; 2.3107x over previous
//
#include <hip/hip_runtime.h>

// Problem constants: V=128, E=256, H=4, B=1024, L=64
// Workspace layout:
//   pos[16384] f32 | posmean[256] f32 | x2t[8192*256] f32 (8MB)
//   | qkvt[8192*3072] bf16 (50.3MB)
//   | x2tb[8192*256] bf16 (4MB)  -- ALIASED: attn_out[1024*1024] f32 (4MB) after qkvt GEMM
//   | wb[3072*256] bf16 (1.5MB)

typedef __attribute__((ext_vector_type(8))) short bf16x8;
typedef __attribute__((ext_vector_type(4))) float f32x4;

__device__ __forceinline__ float wred_sum(float v) {
#pragma unroll
  for (int off = 32; off > 0; off >>= 1) v += __shfl_xor(v, off, 64);
  return v;
}
__device__ __forceinline__ float bf2f(unsigned short u) {
  union { unsigned int i; float f; } x; x.i = ((unsigned int)u) << 16; return x.f;
}
__device__ __forceinline__ unsigned short f2bf(float f) {
  union { float f; unsigned int i; } x; x.f = f;
  unsigned int r = x.i + 0x7FFFu + ((x.i >> 16) & 1u);
  return (unsigned short)(r >> 16);
}

// ---------------- pos table ----------------
__global__ __launch_bounds__(256) void pos_kernel(float* pos) {
  int idx = blockIdx.x * 256 + threadIdx.x;   // 0..16383
  int l = idx >> 8, e = idx & 255;
  int i = e >> 1;
  float freq = powf(10000.0f, -(float)i * (1.0f / 128.0f));
  float ph = (float)l * freq;
  pos[idx] = (e & 1) ? cosf(ph) : sinf(ph);
}

__global__ __launch_bounds__(256) void posmean_kernel(const float* pos, float* posmean) {
  int e = threadIdx.x;
  float s = 0.f;
#pragma unroll 8
  for (int l = 0; l < 64; l++) s += pos[l * 256 + e];
  posmean[e] = s * (1.0f / 64.0f);
}

// ---------------- convert qkv_w to bf16 ----------------
__global__ __launch_bounds__(256) void cvt_w_kernel(const float* w, unsigned short* wb) {
  int i = (blockIdx.x * 256 + threadIdx.x) * 4;
  float4 v = *(const float4*)(w + i);
  ushort4 o = make_ushort4(f2bf(v.x), f2bf(v.y), f2bf(v.z), f2bf(v.w));
  *(ushort4*)(wb + i) = o;
}

// ---------------- x2 table: LN0(emb[c]+pos[l]) + pos[l], 8192 rows; f32 + bf16 ----------------
__global__ __launch_bounds__(256) void x2t_kernel(const float* emb, const float* pos,
                                                  const float* g, const float* b,
                                                  float* x2t, unsigned short* x2tb) {
  int w = threadIdx.x >> 6, lane = threadIdx.x & 63;
  int row = blockIdx.x * 4 + w;               // 0..8191
  int c = row >> 6, l = row & 63;
  int e0 = lane * 4;
  float4 ev = *(const float4*)(emb + c * 256 + e0);
  float4 pv = *(const float4*)(pos + l * 256 + e0);
  float v0 = ev.x + pv.x, v1 = ev.y + pv.y, v2 = ev.z + pv.z, v3 = ev.w + pv.w;
  float s = wred_sum(v0 + v1 + v2 + v3);
  float q = wred_sum(v0 * v0 + v1 * v1 + v2 * v2 + v3 * v3);
  float mean = s * (1.0f / 256.0f);
  float var = q * (1.0f / 256.0f) - mean * mean;
  float rstd = rsqrtf(var + 1e-5f);
  float4 gv = *(const float4*)(g + e0);
  float4 bv = *(const float4*)(b + e0);
  float4 o;
  o.x = (v0 - mean) * rstd * gv.x + bv.x + pv.x;
  o.y = (v1 - mean) * rstd * gv.y + bv.y + pv.y;
  o.z = (v2 - mean) * rstd * gv.z + bv.z + pv.z;
  o.w = (v3 - mean) * rstd * gv.w + bv.w + pv.w;
  *(float4*)(x2t + (size_t)row * 256 + e0) = o;
  ushort4 ob = make_ushort4(f2bf(o.x), f2bf(o.y), f2bf(o.z), f2bf(o.w));
  *(ushort4*)(x2tb + (size_t)row * 256 + e0) = ob;
}

// ---------------- QKV table GEMM via MFMA: (8192x256)@(3072x256)^T -> bf16 ----------------
__global__ __launch_bounds__(256) void qkvt_mfma_kernel(const unsigned short* x2tb,
                                                        const unsigned short* wb,
                                                        unsigned short* qkvt) {
  __shared__ unsigned short S[2 * 128 * 64];  // As | Bs ; reused as Cs (128x128)
  unsigned short* As = S;
  unsigned short* Bs = S + 128 * 64;
  int t = threadIdx.x, w = t >> 6, lane = t & 63;
  int m0 = blockIdx.y * 128, n0 = blockIdx.x * 128;
  int wr = w >> 1, wc = w & 1;
  f32x4 acc[4][4] = {};
  int r_in = lane >> 3;              // 0..7 row within 8-row block
  int cb = (lane & 7) * 8;           // 0..56 bf16 col (16B granules)
  for (int kt = 0; kt < 4; ++kt) {
#pragma unroll
    for (int it = 0; it < 4; ++it) {
      int rowblk = it * 32 + w * 8;  // wave-uniform
      const unsigned short* ga = x2tb + (size_t)(m0 + rowblk + r_in) * 256 + kt * 64 + cb;
      __builtin_amdgcn_global_load_lds(
          (const __attribute__((address_space(1))) unsigned int*)ga,
          (__attribute__((address_space(3))) unsigned int*)(As + rowblk * 64), 16, 0, 0);
      const unsigned short* gb = wb + (size_t)(n0 + rowblk + r_in) * 256 + kt * 64 + cb;
      __builtin_amdgcn_global_load_lds(
          (const __attribute__((address_space(1))) unsigned int*)gb,
          (__attribute__((address_space(3))) unsigned int*)(Bs + rowblk * 64), 16, 0, 0);
    }
    __syncthreads();
#pragma unroll
    for (int kk = 0; kk < 2; ++kk) {
      bf16x8 af[4], bfr[4];
#pragma unroll
      for (int m = 0; m < 4; ++m)
        af[m] = *(const bf16x8*)(As + (wr * 64 + m * 16 + (lane & 15)) * 64 + kk * 32 + (lane >> 4) * 8);
#pragma unroll
      for (int n = 0; n < 4; ++n)
        bfr[n] = *(const bf16x8*)(Bs + (wc * 64 + n * 16 + (lane & 15)) * 64 + kk * 32 + (lane >> 4) * 8);
#pragma unroll
      for (int m = 0; m < 4; ++m)
#pragma unroll
        for (int n = 0; n < 4; ++n)
          acc[m][n] = __builtin_amdgcn_mfma_f32_16x16x32_bf16(af[m], bfr[n], acc[m][n], 0, 0, 0);
    }
    __syncthreads();
  }
  unsigned short* Cs = S;
#pragma unroll
  for (int m = 0; m < 4; ++m)
#pragma unroll
    for (int n = 0; n < 4; ++n) {
      int row = wr * 64 + m * 16 + (lane >> 4) * 4;
      int col = wc * 64 + n * 16 + (lane & 15);
#pragma unroll
      for (int j = 0; j < 4; ++j)
        Cs[(row + j) * 128 + col] = f2bf(acc[m][n][j]);
    }
  __syncthreads();
#pragma unroll
  for (int it = 0; it < 8; ++it) {
    int row = it * 16 + (t >> 4);
    int ce = (t & 15) * 8;
    *(bf16x8*)(qkvt + (size_t)(m0 + row) * 3072 + n0 + ce) =
        *(const bf16x8*)(Cs + row * 128 + ce);
  }
}

// ---------------- attention per (b,h): MFMA QK^T + in-register softmax + PV ----------------
// LDS: S 32KB. QK phase: Qs=S[0:4096], Ks=S[4096:8192] (ushort idx), one 64-col chunk each.
// V phase: S = V[64][256] bf16 (aliased after last QK read).
__global__ __launch_bounds__(256) void attn_kernel(const int* cc, const unsigned short* qkvt,
                                                   float* attn_out) {
  __shared__ unsigned short S[16384];
  __shared__ float s_sp[4][64];
  __shared__ float s_score[64];
  __shared__ float s_nm[64];
  __shared__ int s_cc[64];
  __shared__ float s_nwinv;
  int b = blockIdx.x >> 2, h = blockIdx.x & 3;
  int t = threadIdx.x, w = t >> 6, lane = t & 63;
  int li = lane & 15, hi = lane >> 4;
  unsigned short* Qs = S;
  unsigned short* Ks = S + 4096;

  if (t < 64) {
    int c = cc[b * 64 + t];
    s_cc[t] = c;
    s_nm[t] = (c != 0) ? 1.0f : 0.0f;
  }
  __syncthreads();
  if (w == 0) {
    float s = wred_sum(s_nm[lane]);
    if (lane == 0) s_nwinv = 1.0f / s;
  }
  // per-lane masks (LDS reads, after barrier)
  float nmv[4], nmr[4];
#pragma unroll
  for (int n = 0; n < 4; ++n) nmv[n] = s_nm[n * 16 + li];
#pragma unroll
  for (int j = 0; j < 4; ++j) nmr[j] = s_nm[w * 16 + hi * 4 + j];

  // staging lane constants (both-sides swizzle: source granule = lds granule ^ (row&7))
  int sr = lane >> 3;                 // row within 8-row group
  int sg = (lane & 7) ^ sr;           // inverse-swizzled source granule
  const unsigned short* base = qkvt + h * 768;

  // ---- QK^T: 4 chunks of K=64, MFMA accumulate ----
  f32x4 acc[4] = {};
  for (int ec = 0; ec < 4; ++ec) {
#pragma unroll
    for (int i = 0; i < 2; ++i) {
      int it = w * 2 + i;             // wave-uniform
      int idx = it * 8 + sr;          // q/k index 0..63
      size_t tr = (size_t)(s_cc[idx] * 64 + idx) * 3072;
      const unsigned short* pq = base + tr + ec * 64 + sg * 8;
      __builtin_amdgcn_global_load_lds(
          (const __attribute__((address_space(1))) unsigned int*)pq,
          (__attribute__((address_space(3))) unsigned int*)(Qs + it * 512), 16, 0, 0);
      const unsigned short* pk = pq + 256;
      __builtin_amdgcn_global_load_lds(
          (const __attribute__((address_space(1))) unsigned int*)pk,
          (__attribute__((address_space(3))) unsigned int*)(Ks + it * 512), 16, 0, 0);
    }
    __syncthreads();
#pragma unroll
    for (int kk = 0; kk < 2; ++kk) {
      int rq = w * 16 + li;
      bf16x8 af = *(const bf16x8*)(Qs + rq * 64 + (((kk * 4 + hi) ^ (rq & 7)) * 8));
#pragma unroll
      for (int n = 0; n < 4; ++n) {
        int rk = n * 16 + li;
        bf16x8 bf = *(const bf16x8*)(Ks + rk * 64 + (((kk * 4 + hi) ^ (rk & 7)) * 8));
        acc[n] = __builtin_amdgcn_mfma_f32_16x16x32_bf16(af, bf, acc[n], 0, 0, 0);
      }
    }
    __syncthreads();
  }

  // ---- V stage (issue early; latency hides under softmax; drained by syncthreads) ----
  {
    int vr = lane >> 5;               // 0..1 row within inst
    int vg = lane & 31;               // 16B granule within 512B row
#pragma unroll
    for (int i = 0; i < 8; ++i) {
      int it = w * 8 + i;             // wave-uniform
      int idx = it * 2 + vr;
      size_t tr = (size_t)(s_cc[idx] * 64 + idx) * 3072;
      const unsigned short* pv = base + tr + 512 + vg * 8;
      __builtin_amdgcn_global_load_lds(
          (const __attribute__((address_space(1))) unsigned int*)pv,
          (__attribute__((address_space(3))) unsigned int*)(S + it * 512), 16, 0, 0);
    }
  }

  // ---- in-register masked softmax + query-averaged score ----
  // acc[n][j]: row q = w*16 + hi*4 + j, col k = n*16 + li
  float sc[4] = {0.f, 0.f, 0.f, 0.f};
#pragma unroll
  for (int j = 0; j < 4; ++j) {
    float v[4];
#pragma unroll
    for (int n = 0; n < 4; ++n)
      v[n] = (nmv[n] != 0.f) ? acc[n][j] * 0.0625f : -1e30f;
    float m = fmaxf(fmaxf(v[0], v[1]), fmaxf(v[2], v[3]));
    m = fmaxf(m, __shfl_xor(m, 1, 64));
    m = fmaxf(m, __shfl_xor(m, 2, 64));
    m = fmaxf(m, __shfl_xor(m, 4, 64));
    m = fmaxf(m, __shfl_xor(m, 8, 64));
    float p[4];
#pragma unroll
    for (int n = 0; n < 4; ++n) p[n] = nmv[n] * __expf(v[n] - m);
    float s = (p[0] + p[1]) + (p[2] + p[3]);
    s += __shfl_xor(s, 1, 64);
    s += __shfl_xor(s, 2, 64);
    s += __shfl_xor(s, 4, 64);
    s += __shfl_xor(s, 8, 64);
    float f = nmr[j] / s;
#pragma unroll
    for (int n = 0; n < 4; ++n) sc[n] += p[n] * f;
  }
#pragma unroll
  for (int n = 0; n < 4; ++n) {
    sc[n] += __shfl_xor(sc[n], 16, 64);
    sc[n] += __shfl_xor(sc[n], 32, 64);
  }
  if (hi == 0) {
#pragma unroll
    for (int n = 0; n < 4; ++n) s_sp[w][n * 16 + li] = sc[n];
  }
  __syncthreads();
  if (t < 64)
    s_score[t] = (s_sp[0][t] + s_sp[1][t] + s_sp[2][t] + s_sp[3][t]) * s_nwinv;
  __syncthreads();   // also drains V stage (vmcnt) + publishes s_score

  // ---- PV: out[e] = sum_k score[k] * V[k][e]; thread t = col e ----
  float o = 0.f;
#pragma unroll
  for (int k4 = 0; k4 < 16; ++k4) {
    float4 sv = *(const float4*)(s_score + k4 * 4);
    o += sv.x * bf2f(S[(k4 * 4 + 0) * 256 + t]);
    o += sv.y * bf2f(S[(k4 * 4 + 1) * 256 + t]);
    o += sv.z * bf2f(S[(k4 * 4 + 2) * 256 + t]);
    o += sv.w * bf2f(S[(k4 * 4 + 3) * 256 + t]);
  }
  attn_out[b * 1024 + h * 256 + t] = o;
}

// ---------------- final: xmean gather + fc + LN chain ----------------
__device__ __forceinline__ float block_ln(float v, int t, float eps, const float* g,
                                          const float* b, float* s_part) {
  int w = t >> 6, lane = t & 63;
  __syncthreads();
  float s = wred_sum(v), q = wred_sum(v * v);
  if (lane == 0) { s_part[w] = s; s_part[4 + w] = q; }
  __syncthreads();
  float sum = s_part[0] + s_part[1] + s_part[2] + s_part[3];
  float sq = s_part[4] + s_part[5] + s_part[6] + s_part[7];
  float mean = sum * (1.0f / 256.0f);
  float var = sq * (1.0f / 256.0f) - mean * mean;
  float rstd = rsqrtf(var + eps);
  return (v - mean) * rstd * g[t] + b[t];
}

__global__ __launch_bounds__(256) void final_kernel(
    const int* cc, const float* x2t, const float* posmean, const float* ao,
    const float* fc_w, const float* fc_b,
    const float* sln_g, const float* sln_b, const float* ln1_g, const float* ln1_b,
    const float* ffln_g, const float* ffln_b, const float* ln2_g, const float* ln2_b,
    float* out) {
  __shared__ int s_cc[64];
  __shared__ float s_ao[1024];
  __shared__ float s_out[256];
  __shared__ float s_part[8];
  int b = blockIdx.x, t = threadIdx.x, w = t >> 6, lane = t & 63;
  if (t < 64) s_cc[t] = cc[b * 64 + t];
  *(float4*)(s_ao + t * 4) = *(const float4*)(ao + b * 1024 + t * 4);
  __syncthreads();

  float xa = 0.f;
#pragma unroll 8
  for (int l = 0; l < 64; l++) xa += x2t[(size_t)(s_cc[l] * 64 + l) * 256 + t];
  float xm = xa * (1.0f / 64.0f) - posmean[t];

  for (int ii = 0; ii < 64; ii++) {
    int i = w * 64 + ii;
    const float4* wr = (const float4*)(fc_w + (size_t)i * 1024);
    float p = 0.f;
#pragma unroll
    for (int c4 = 0; c4 < 4; c4++) {
      float4 wv = wr[c4 * 64 + lane];
      float4 av = *(const float4*)(s_ao + c4 * 256 + lane * 4);
      p = fmaf(wv.x, av.x, p); p = fmaf(wv.y, av.y, p);
      p = fmaf(wv.z, av.z, p); p = fmaf(wv.w, av.w, p);
    }
    p = wred_sum(p);
    if (lane == 0) s_out[i] = p + fc_b[i];
  }
  __syncthreads();

  float v = s_out[t];
  v = block_ln(v, t, 1e-5f, sln_g, sln_b, s_part);
  v = v + xm;
  v = block_ln(v, t, 1e-5f, ln1_g, ln1_b, s_part);
  float ff = block_ln(v, t, 1e-6f, ffln_g, ffln_b, s_part);
  float w2 = ff + v;
  float fin = block_ln(w2, t, 1e-5f, ln2_g, ln2_b, s_part);
  out[b * 256 + t] = fin;
}

extern "C" void kernel_launch(void* const* d_in, const int* in_sizes, int n_in,
                              void* d_out, int out_size, void* d_ws, size_t ws_size,
                              hipStream_t stream) {
  const int* char_code = (const int*)d_in[0];
  const float* emb    = (const float*)d_in[2];
  const float* qkv_w  = (const float*)d_in[3];
  const float* ln0_g  = (const float*)d_in[4];
  const float* ln0_b  = (const float*)d_in[5];
  const float* fc_w   = (const float*)d_in[6];
  const float* fc_b   = (const float*)d_in[7];
  const float* sln_g  = (const float*)d_in[8];
  const float* sln_b  = (const float*)d_in[9];
  const float* ln1_g  = (const float*)d_in[10];
  const float* ln1_b  = (const float*)d_in[11];
  const float* ffln_g = (const float*)d_in[16];
  const float* ffln_b = (const float*)d_in[17];
  const float* ln2_g  = (const float*)d_in[18];
  const float* ln2_b  = (const float*)d_in[19];

  float* ws = (float*)d_ws;
  float* pos = ws;                                        // 16384 f32
  float* posmean = pos + 16384;                           // 256 f32
  float* x2t = posmean + 256;                             // 8192*256 f32 (8MB)
  unsigned short* qkvt = (unsigned short*)(x2t + (size_t)8192 * 256);  // 50.3MB bf16
  unsigned short* x2tb = qkvt + (size_t)8192 * 3072;      // 4MB bf16
  float* attn_out = (float*)x2tb;                         // ALIAS: written after GEMM consumed x2tb
  unsigned short* wb = x2tb + (size_t)8192 * 256;         // 1.5MB bf16

  pos_kernel<<<64, 256, 0, stream>>>(pos);
  posmean_kernel<<<1, 256, 0, stream>>>(pos, posmean);
  cvt_w_kernel<<<768, 256, 0, stream>>>(qkv_w, wb);
  x2t_kernel<<<2048, 256, 0, stream>>>(emb, pos, ln0_g, ln0_b, x2t, x2tb);
  qkvt_mfma_kernel<<<dim3(24, 64), 256, 0, stream>>>(x2tb, wb, qkvt);
  attn_kernel<<<4096, 256, 0, stream>>>(char_code, qkvt, attn_out);
  final_kernel<<<1024, 256, 0, stream>>>(char_code, x2t, posmean, attn_out,
                                         fc_w, fc_b, sln_g, sln_b, ln1_g, ln1_b,
                                         ffln_g, ffln_b, ln2_g, ln2_b, (float*)d_out);
}

// Round 4
// 116.803 us; speedup vs baseline: 4.6226x; 1.2114x over previous
//
#include <hip/hip_runtime.h>

// Problem constants: V=128, E=256, H=4, B=1024, L=64
// Workspace layout:
//   pos[16384] f32 | posmean[256] f32 | x2t[8192*256] f32 (8MB)
//   | qkvt[8192*3072] bf16 (50.3MB)
//   | x2tb[8192*256] bf16 (4MB) -- ALIASED: aob[1024*1024] bf16 (2MB) after qkvt GEMM
//   | wb[3072*256] bf16 (1.5MB) | fc_wb[256*1024] bf16 (0.5MB) | fco[1024*256] f32 (1MB)

typedef __attribute__((ext_vector_type(8))) short bf16x8;
typedef __attribute__((ext_vector_type(4))) float f32x4;

__device__ __forceinline__ float wred_sum(float v) {
#pragma unroll
  for (int off = 32; off > 0; off >>= 1) v += __shfl_xor(v, off, 64);
  return v;
}
__device__ __forceinline__ float bf2f(unsigned short u) {
  union { unsigned int i; float f; } x; x.i = ((unsigned int)u) << 16; return x.f;
}
__device__ __forceinline__ unsigned short f2bf(float f) {
  union { float f; unsigned int i; } x; x.f = f;
  unsigned int r = x.i + 0x7FFFu + ((x.i >> 16) & 1u);
  return (unsigned short)(r >> 16);
}

// ---------------- pos table ----------------
__global__ __launch_bounds__(256) void pos_kernel(float* pos) {
  int idx = blockIdx.x * 256 + threadIdx.x;   // 0..16383
  int l = idx >> 8, e = idx & 255;
  int i = e >> 1;
  float freq = powf(10000.0f, -(float)i * (1.0f / 128.0f));
  float ph = (float)l * freq;
  pos[idx] = (e & 1) ? cosf(ph) : sinf(ph);
}

__global__ __launch_bounds__(256) void posmean_kernel(const float* pos, float* posmean) {
  int e = threadIdx.x;
  float s = 0.f;
#pragma unroll 8
  for (int l = 0; l < 64; l++) s += pos[l * 256 + e];
  posmean[e] = s * (1.0f / 64.0f);
}

// ---------------- convert f32 -> bf16 (4 elems/thread) ----------------
__global__ __launch_bounds__(256) void cvt_w_kernel(const float* w, unsigned short* wb) {
  int i = (blockIdx.x * 256 + threadIdx.x) * 4;
  float4 v = *(const float4*)(w + i);
  ushort4 o = make_ushort4(f2bf(v.x), f2bf(v.y), f2bf(v.z), f2bf(v.w));
  *(ushort4*)(wb + i) = o;
}

// ---------------- x2 table: LN0(emb[c]+pos[l]) + pos[l], 8192 rows; f32 + bf16 ----------------
__global__ __launch_bounds__(256) void x2t_kernel(const float* emb, const float* pos,
                                                  const float* g, const float* b,
                                                  float* x2t, unsigned short* x2tb) {
  int w = threadIdx.x >> 6, lane = threadIdx.x & 63;
  int row = blockIdx.x * 4 + w;               // 0..8191
  int c = row >> 6, l = row & 63;
  int e0 = lane * 4;
  float4 ev = *(const float4*)(emb + c * 256 + e0);
  float4 pv = *(const float4*)(pos + l * 256 + e0);
  float v0 = ev.x + pv.x, v1 = ev.y + pv.y, v2 = ev.z + pv.z, v3 = ev.w + pv.w;
  float s = wred_sum(v0 + v1 + v2 + v3);
  float q = wred_sum(v0 * v0 + v1 * v1 + v2 * v2 + v3 * v3);
  float mean = s * (1.0f / 256.0f);
  float var = q * (1.0f / 256.0f) - mean * mean;
  float rstd = rsqrtf(var + 1e-5f);
  float4 gv = *(const float4*)(g + e0);
  float4 bv = *(const float4*)(b + e0);
  float4 o;
  o.x = (v0 - mean) * rstd * gv.x + bv.x + pv.x;
  o.y = (v1 - mean) * rstd * gv.y + bv.y + pv.y;
  o.z = (v2 - mean) * rstd * gv.z + bv.z + pv.z;
  o.w = (v3 - mean) * rstd * gv.w + bv.w + pv.w;
  *(float4*)(x2t + (size_t)row * 256 + e0) = o;
  ushort4 ob = make_ushort4(f2bf(o.x), f2bf(o.y), f2bf(o.z), f2bf(o.w));
  *(ushort4*)(x2tb + (size_t)row * 256 + e0) = ob;
}

// ---------------- QKV table GEMM via MFMA: (8192x256)@(3072x256)^T -> bf16 ----------------
__global__ __launch_bounds__(256) void qkvt_mfma_kernel(const unsigned short* x2tb,
                                                        const unsigned short* wb,
                                                        unsigned short* qkvt) {
  __shared__ unsigned short S[2 * 128 * 64];  // As | Bs ; reused as Cs (128x128)
  unsigned short* As = S;
  unsigned short* Bs = S + 128 * 64;
  int t = threadIdx.x, w = t >> 6, lane = t & 63;
  int m0 = blockIdx.y * 128, n0 = blockIdx.x * 128;
  int wr = w >> 1, wc = w & 1;
  f32x4 acc[4][4] = {};
  int r_in = lane >> 3;              // 0..7 row within 8-row block
  int cb = (lane & 7) * 8;           // 0..56 bf16 col (16B granules)
  for (int kt = 0; kt < 4; ++kt) {
#pragma unroll
    for (int it = 0; it < 4; ++it) {
      int rowblk = it * 32 + w * 8;  // wave-uniform
      const unsigned short* ga = x2tb + (size_t)(m0 + rowblk + r_in) * 256 + kt * 64 + cb;
      __builtin_amdgcn_global_load_lds(
          (const __attribute__((address_space(1))) unsigned int*)ga,
          (__attribute__((address_space(3))) unsigned int*)(As + rowblk * 64), 16, 0, 0);
      const unsigned short* gb = wb + (size_t)(n0 + rowblk + r_in) * 256 + kt * 64 + cb;
      __builtin_amdgcn_global_load_lds(
          (const __attribute__((address_space(1))) unsigned int*)gb,
          (__attribute__((address_space(3))) unsigned int*)(Bs + rowblk * 64), 16, 0, 0);
    }
    __syncthreads();
#pragma unroll
    for (int kk = 0; kk < 2; ++kk) {
      bf16x8 af[4], bfr[4];
#pragma unroll
      for (int m = 0; m < 4; ++m)
        af[m] = *(const bf16x8*)(As + (wr * 64 + m * 16 + (lane & 15)) * 64 + kk * 32 + (lane >> 4) * 8);
#pragma unroll
      for (int n = 0; n < 4; ++n)
        bfr[n] = *(const bf16x8*)(Bs + (wc * 64 + n * 16 + (lane & 15)) * 64 + kk * 32 + (lane >> 4) * 8);
#pragma unroll
      for (int m = 0; m < 4; ++m)
#pragma unroll
        for (int n = 0; n < 4; ++n)
          acc[m][n] = __builtin_amdgcn_mfma_f32_16x16x32_bf16(af[m], bfr[n], acc[m][n], 0, 0, 0);
    }
    __syncthreads();
  }
  unsigned short* Cs = S;
#pragma unroll
  for (int m = 0; m < 4; ++m)
#pragma unroll
    for (int n = 0; n < 4; ++n) {
      int row = wr * 64 + m * 16 + (lane >> 4) * 4;
      int col = wc * 64 + n * 16 + (lane & 15);
#pragma unroll
      for (int j = 0; j < 4; ++j)
        Cs[(row + j) * 128 + col] = f2bf(acc[m][n][j]);
    }
  __syncthreads();
#pragma unroll
  for (int it = 0; it < 8; ++it) {
    int row = it * 16 + (t >> 4);
    int ce = (t & 15) * 8;
    *(bf16x8*)(qkvt + (size_t)(m0 + row) * 3072 + n0 + ce) =
        *(const bf16x8*)(Cs + row * 128 + ce);
  }
}

// ---------------- attention per (b,h): MFMA QK^T + in-register softmax + PV -> bf16 ----------------
__global__ __launch_bounds__(256) void attn_kernel(const int* cc, const unsigned short* qkvt,
                                                   unsigned short* aob) {
  __shared__ unsigned short S[16384];
  __shared__ float s_sp[4][64];
  __shared__ float s_score[64];
  __shared__ float s_nm[64];
  __shared__ int s_cc[64];
  __shared__ float s_nwinv;
  int b = blockIdx.x >> 2, h = blockIdx.x & 3;
  int t = threadIdx.x, w = t >> 6, lane = t & 63;
  int li = lane & 15, hi = lane >> 4;
  unsigned short* Qs = S;
  unsigned short* Ks = S + 4096;

  if (t < 64) {
    int c = cc[b * 64 + t];
    s_cc[t] = c;
    s_nm[t] = (c != 0) ? 1.0f : 0.0f;
  }
  __syncthreads();
  if (w == 0) {
    float s = wred_sum(s_nm[lane]);
    if (lane == 0) s_nwinv = 1.0f / s;
  }
  float nmv[4], nmr[4];
#pragma unroll
  for (int n = 0; n < 4; ++n) nmv[n] = s_nm[n * 16 + li];
#pragma unroll
  for (int j = 0; j < 4; ++j) nmr[j] = s_nm[w * 16 + hi * 4 + j];

  int sr = lane >> 3;                 // row within 8-row group
  int sg = (lane & 7) ^ sr;           // inverse-swizzled source granule
  const unsigned short* base = qkvt + h * 768;

  // ---- QK^T: 4 chunks of K=64, MFMA accumulate ----
  f32x4 acc[4] = {};
  for (int ec = 0; ec < 4; ++ec) {
#pragma unroll
    for (int i = 0; i < 2; ++i) {
      int it = w * 2 + i;             // wave-uniform
      int idx = it * 8 + sr;          // q/k index 0..63
      size_t tr = (size_t)(s_cc[idx] * 64 + idx) * 3072;
      const unsigned short* pq = base + tr + ec * 64 + sg * 8;
      __builtin_amdgcn_global_load_lds(
          (const __attribute__((address_space(1))) unsigned int*)pq,
          (__attribute__((address_space(3))) unsigned int*)(Qs + it * 512), 16, 0, 0);
      const unsigned short* pk = pq + 256;
      __builtin_amdgcn_global_load_lds(
          (const __attribute__((address_space(1))) unsigned int*)pk,
          (__attribute__((address_space(3))) unsigned int*)(Ks + it * 512), 16, 0, 0);
    }
    __syncthreads();
#pragma unroll
    for (int kk = 0; kk < 2; ++kk) {
      int rq = w * 16 + li;
      bf16x8 af = *(const bf16x8*)(Qs + rq * 64 + (((kk * 4 + hi) ^ (rq & 7)) * 8));
#pragma unroll
      for (int n = 0; n < 4; ++n) {
        int rk = n * 16 + li;
        bf16x8 bf = *(const bf16x8*)(Ks + rk * 64 + (((kk * 4 + hi) ^ (rk & 7)) * 8));
        acc[n] = __builtin_amdgcn_mfma_f32_16x16x32_bf16(af, bf, acc[n], 0, 0, 0);
      }
    }
    __syncthreads();
  }

  // ---- V stage (issue early; drained by syncthreads before PV) ----
  {
    int vr = lane >> 5;
    int vg = lane & 31;
#pragma unroll
    for (int i = 0; i < 8; ++i) {
      int it = w * 8 + i;
      int idx = it * 2 + vr;
      size_t tr = (size_t)(s_cc[idx] * 64 + idx) * 3072;
      const unsigned short* pv = base + tr + 512 + vg * 8;
      __builtin_amdgcn_global_load_lds(
          (const __attribute__((address_space(1))) unsigned int*)pv,
          (__attribute__((address_space(3))) unsigned int*)(S + it * 512), 16, 0, 0);
    }
  }

  // ---- in-register masked softmax + query-averaged score ----
  float sc[4] = {0.f, 0.f, 0.f, 0.f};
#pragma unroll
  for (int j = 0; j < 4; ++j) {
    float v[4];
#pragma unroll
    for (int n = 0; n < 4; ++n)
      v[n] = (nmv[n] != 0.f) ? acc[n][j] * 0.0625f : -1e30f;
    float m = fmaxf(fmaxf(v[0], v[1]), fmaxf(v[2], v[3]));
    m = fmaxf(m, __shfl_xor(m, 1, 64));
    m = fmaxf(m, __shfl_xor(m, 2, 64));
    m = fmaxf(m, __shfl_xor(m, 4, 64));
    m = fmaxf(m, __shfl_xor(m, 8, 64));
    float p[4];
#pragma unroll
    for (int n = 0; n < 4; ++n) p[n] = nmv[n] * __expf(v[n] - m);
    float s = (p[0] + p[1]) + (p[2] + p[3]);
    s += __shfl_xor(s, 1, 64);
    s += __shfl_xor(s, 2, 64);
    s += __shfl_xor(s, 4, 64);
    s += __shfl_xor(s, 8, 64);
    float f = nmr[j] / s;
#pragma unroll
    for (int n = 0; n < 4; ++n) sc[n] += p[n] * f;
  }
#pragma unroll
  for (int n = 0; n < 4; ++n) {
    sc[n] += __shfl_xor(sc[n], 16, 64);
    sc[n] += __shfl_xor(sc[n], 32, 64);
  }
  if (hi == 0) {
#pragma unroll
    for (int n = 0; n < 4; ++n) s_sp[w][n * 16 + li] = sc[n];
  }
  __syncthreads();
  if (t < 64)
    s_score[t] = (s_sp[0][t] + s_sp[1][t] + s_sp[2][t] + s_sp[3][t]) * s_nwinv;
  __syncthreads();   // drains V stage + publishes s_score

  // ---- PV: out[e] = sum_k score[k] * V[k][e]; thread t = col e; bf16 out ----
  float o = 0.f;
#pragma unroll
  for (int k4 = 0; k4 < 16; ++k4) {
    float4 sv = *(const float4*)(s_score + k4 * 4);
    o += sv.x * bf2f(S[(k4 * 4 + 0) * 256 + t]);
    o += sv.y * bf2f(S[(k4 * 4 + 1) * 256 + t]);
    o += sv.z * bf2f(S[(k4 * 4 + 2) * 256 + t]);
    o += sv.w * bf2f(S[(k4 * 4 + 3) * 256 + t]);
  }
  aob[b * 1024 + h * 256 + t] = f2bf(o);
}

// ---------------- fc GEMM: fco(1024x256) = aob(1024x1024) @ fc_wb(256x1024)^T + fc_b ----------------
// 64x64 tile, 4 waves (wave = 16 output cols), BK=64, K=1024.
__global__ __launch_bounds__(256) void fc_mfma_kernel(const unsigned short* aob,
                                                      const unsigned short* fc_wb,
                                                      const float* fc_b, float* fco) {
  __shared__ unsigned short As[64 * 64];
  __shared__ unsigned short Bs[64 * 64];
  int t = threadIdx.x, w = t >> 6, lane = t & 63;
  int li = lane & 15, hi = lane >> 4;
  int n0 = blockIdx.x * 64;           // 0..255 (4 tiles)
  int m0 = blockIdx.y * 64;           // 0..1023 (16 tiles)
  int r_in = lane >> 3;
  int cb = (lane & 7) * 8;
  f32x4 acc[4] = {};
  for (int kt = 0; kt < 16; ++kt) {
#pragma unroll
    for (int it = 0; it < 2; ++it) {
      int rowblk = it * 32 + w * 8;   // wave-uniform
      const unsigned short* ga = aob + (size_t)(m0 + rowblk + r_in) * 1024 + kt * 64 + cb;
      __builtin_amdgcn_global_load_lds(
          (const __attribute__((address_space(1))) unsigned int*)ga,
          (__attribute__((address_space(3))) unsigned int*)(As + rowblk * 64), 16, 0, 0);
      const unsigned short* gb = fc_wb + (size_t)(n0 + rowblk + r_in) * 1024 + kt * 64 + cb;
      __builtin_amdgcn_global_load_lds(
          (const __attribute__((address_space(1))) unsigned int*)gb,
          (__attribute__((address_space(3))) unsigned int*)(Bs + rowblk * 64), 16, 0, 0);
    }
    __syncthreads();
#pragma unroll
    for (int kk = 0; kk < 2; ++kk) {
      bf16x8 bf = *(const bf16x8*)(Bs + (w * 16 + li) * 64 + kk * 32 + hi * 8);
#pragma unroll
      for (int m = 0; m < 4; ++m) {
        bf16x8 af = *(const bf16x8*)(As + (m * 16 + li) * 64 + kk * 32 + hi * 8);
        acc[m] = __builtin_amdgcn_mfma_f32_16x16x32_bf16(af, bf, acc[m], 0, 0, 0);
      }
    }
    __syncthreads();
  }
  int col = n0 + w * 16 + li;
  float bias = fc_b[col];
#pragma unroll
  for (int m = 0; m < 4; ++m)
#pragma unroll
    for (int j = 0; j < 4; ++j)
      fco[(size_t)(m0 + m * 16 + hi * 4 + j) * 256 + col] = acc[m][j] + bias;
}

// ---------------- final: xmean gather + LN chain ----------------
__device__ __forceinline__ float block_ln(float v, int t, float eps, const float* g,
                                          const float* b, float* s_part) {
  int w = t >> 6, lane = t & 63;
  __syncthreads();
  float s = wred_sum(v), q = wred_sum(v * v);
  if (lane == 0) { s_part[w] = s; s_part[4 + w] = q; }
  __syncthreads();
  float sum = s_part[0] + s_part[1] + s_part[2] + s_part[3];
  float sq = s_part[4] + s_part[5] + s_part[6] + s_part[7];
  float mean = sum * (1.0f / 256.0f);
  float var = sq * (1.0f / 256.0f) - mean * mean;
  float rstd = rsqrtf(var + eps);
  return (v - mean) * rstd * g[t] + b[t];
}

__global__ __launch_bounds__(256) void final_kernel(
    const int* cc, const float* x2t, const float* posmean, const float* fco,
    const float* sln_g, const float* sln_b, const float* ln1_g, const float* ln1_b,
    const float* ffln_g, const float* ffln_b, const float* ln2_g, const float* ln2_b,
    float* out) {
  __shared__ int s_cc[64];
  __shared__ float s_part[8];
  int b = blockIdx.x, t = threadIdx.x;
  if (t < 64) s_cc[t] = cc[b * 64 + t];
  __syncthreads();

  float xa = 0.f;
#pragma unroll 8
  for (int l = 0; l < 64; l++) xa += x2t[(size_t)(s_cc[l] * 64 + l) * 256 + t];
  float xm = xa * (1.0f / 64.0f) - posmean[t];

  float v = fco[(size_t)b * 256 + t];
  v = block_ln(v, t, 1e-5f, sln_g, sln_b, s_part);
  v = v + xm;
  v = block_ln(v, t, 1e-5f, ln1_g, ln1_b, s_part);
  float ff = block_ln(v, t, 1e-6f, ffln_g, ffln_b, s_part);
  float w2 = ff + v;
  float fin = block_ln(w2, t, 1e-5f, ln2_g, ln2_b, s_part);
  out[b * 256 + t] = fin;
}

extern "C" void kernel_launch(void* const* d_in, const int* in_sizes, int n_in,
                              void* d_out, int out_size, void* d_ws, size_t ws_size,
                              hipStream_t stream) {
  const int* char_code = (const int*)d_in[0];
  const float* emb    = (const float*)d_in[2];
  const float* qkv_w  = (const float*)d_in[3];
  const float* ln0_g  = (const float*)d_in[4];
  const float* ln0_b  = (const float*)d_in[5];
  const float* fc_w   = (const float*)d_in[6];
  const float* fc_b   = (const float*)d_in[7];
  const float* sln_g  = (const float*)d_in[8];
  const float* sln_b  = (const float*)d_in[9];
  const float* ln1_g  = (const float*)d_in[10];
  const float* ln1_b  = (const float*)d_in[11];
  const float* ffln_g = (const float*)d_in[16];
  const float* ffln_b = (const float*)d_in[17];
  const float* ln2_g  = (const float*)d_in[18];
  const float* ln2_b  = (const float*)d_in[19];

  float* ws = (float*)d_ws;
  float* pos = ws;                                        // 16384 f32
  float* posmean = pos + 16384;                           // 256 f32
  float* x2t = posmean + 256;                             // 8192*256 f32 (8MB)
  unsigned short* qkvt = (unsigned short*)(x2t + (size_t)8192 * 256);  // 50.3MB bf16
  unsigned short* x2tb = qkvt + (size_t)8192 * 3072;      // 4MB bf16
  unsigned short* aob = x2tb;                             // ALIAS: 2MB bf16, written after qkvt GEMM
  unsigned short* wb = x2tb + (size_t)8192 * 256;         // 1.5MB bf16
  unsigned short* fc_wb = wb + (size_t)3072 * 256;        // 0.5MB bf16
  float* fco = (float*)(fc_wb + (size_t)256 * 1024);      // 1MB f32

  pos_kernel<<<64, 256, 0, stream>>>(pos);
  posmean_kernel<<<1, 256, 0, stream>>>(pos, posmean);
  cvt_w_kernel<<<768, 256, 0, stream>>>(qkv_w, wb);
  cvt_w_kernel<<<256, 256, 0, stream>>>(fc_w, fc_wb);
  x2t_kernel<<<2048, 256, 0, stream>>>(emb, pos, ln0_g, ln0_b, x2t, x2tb);
  qkvt_mfma_kernel<<<dim3(24, 64), 256, 0, stream>>>(x2tb, wb, qkvt);
  attn_kernel<<<4096, 256, 0, stream>>>(char_code, qkvt, aob);
  fc_mfma_kernel<<<dim3(4, 16), 256, 0, stream>>>(aob, fc_wb, fc_b, fco);
  final_kernel<<<1024, 256, 0, stream>>>(char_code, x2t, posmean, fco,
                                         sln_g, sln_b, ln1_g, ln1_b,
                                         ffln_g, ffln_b, ln2_g, ln2_b, (float*)d_out);
}

// Round 5
// 112.497 us; speedup vs baseline: 4.7995x; 1.0383x over previous
//
#include <hip/hip_runtime.h>

// Problem constants: V=128, E=256, H=4, B=1024, L=64
// Algebra: attn out folds V away: out = sv @ Wv^T, Wv folded into fc (W').
//          QK^T = Y @ x2^T with Y = X2 @ (Wq^T Wk) (NT precomputed, per head).
// Workspace: pos | posmean | x2tb(4MB) | yt(16MB) | wqTb|wkTb|wvTb|fc_wb|NTb|wfoldb (0.5MB ea)
//            | svb(2MB bf16) | fco(1MB f32)

typedef __attribute__((ext_vector_type(8))) short bf16x8;
typedef __attribute__((ext_vector_type(4))) float f32x4;

__device__ __forceinline__ float wred_sum(float v) {
#pragma unroll
  for (int off = 32; off > 0; off >>= 1) v += __shfl_xor(v, off, 64);
  return v;
}
__device__ __forceinline__ float bf2f(unsigned short u) {
  union { unsigned int i; float f; } x; x.i = ((unsigned int)u) << 16; return x.f;
}
__device__ __forceinline__ unsigned short f2bf(float f) {
  union { float f; unsigned int i; } x; x.f = f;
  unsigned int r = x.i + 0x7FFFu + ((x.i >> 16) & 1u);
  return (unsigned short)(r >> 16);
}
__device__ __forceinline__ void gld16(const unsigned short* g, unsigned short* l) {
  __builtin_amdgcn_global_load_lds(
      (const __attribute__((address_space(1))) unsigned int*)g,
      (__attribute__((address_space(3))) unsigned int*)l, 16, 0, 0);
}

// ---------------- pos table ----------------
__global__ __launch_bounds__(256) void pos_kernel(float* pos) {
  int idx = blockIdx.x * 256 + threadIdx.x;
  int l = idx >> 8, e = idx & 255;
  int i = e >> 1;
  float freq = powf(10000.0f, -(float)i * (1.0f / 128.0f));
  float ph = (float)l * freq;
  pos[idx] = (e & 1) ? cosf(ph) : sinf(ph);
}

__global__ __launch_bounds__(256) void posmean_kernel(const float* pos, float* posmean) {
  int e = threadIdx.x;
  float s = 0.f;
#pragma unroll 8
  for (int l = 0; l < 64; l++) s += pos[l * 256 + e];
  posmean[e] = s * (1.0f / 64.0f);
}

// ---------------- convert f32 -> bf16 ----------------
__global__ __launch_bounds__(256) void cvt_w_kernel(const float* w, unsigned short* wb) {
  int i = (blockIdx.x * 256 + threadIdx.x) * 4;
  float4 v = *(const float4*)(w + i);
  *(ushort4*)(wb + i) = make_ushort4(f2bf(v.x), f2bf(v.y), f2bf(v.z), f2bf(v.w));
}

// ---------------- transpose+cvt weight slice: wT[h][e][i] = qkv_w[h*768+sel+i][e] ----------------
__global__ __launch_bounds__(256) void transpose_cvt_kernel(const float* qkv_w,
                                                            unsigned short* wT, int sel) {
  __shared__ float T[64][65];
  int h = blockIdx.y;
  int ti = (blockIdx.x & 3) * 64;
  int te = (blockIdx.x >> 2) * 64;
  int t = threadIdx.x, r = t >> 4, c4 = (t & 15) * 4;
#pragma unroll
  for (int rep = 0; rep < 4; ++rep) {
    int il = rep * 16 + r;
    float4 v = *(const float4*)(qkv_w + (size_t)(h * 768 + sel + ti + il) * 256 + te + c4);
    T[il][c4] = v.x; T[il][c4 + 1] = v.y; T[il][c4 + 2] = v.z; T[il][c4 + 3] = v.w;
  }
  __syncthreads();
#pragma unroll
  for (int rep = 0; rep < 4; ++rep) {
    int el = rep * 16 + r;
    ushort4 o = make_ushort4(f2bf(T[c4 + 0][el]), f2bf(T[c4 + 1][el]),
                             f2bf(T[c4 + 2][el]), f2bf(T[c4 + 3][el]));
    *(ushort4*)(wT + (size_t)h * 65536 + (size_t)(te + el) * 256 + ti + c4) = o;
  }
}

// ---------------- x2 table: bf16(LN0(emb[c]+pos[l]) + pos[l]), 8192 rows ----------------
__global__ __launch_bounds__(256) void x2t_kernel(const float* emb, const float* pos,
                                                  const float* g, const float* b,
                                                  unsigned short* x2tb) {
  int w = threadIdx.x >> 6, lane = threadIdx.x & 63;
  int row = blockIdx.x * 4 + w;
  int c = row >> 6, l = row & 63;
  int e0 = lane * 4;
  float4 ev = *(const float4*)(emb + c * 256 + e0);
  float4 pv = *(const float4*)(pos + l * 256 + e0);
  float v0 = ev.x + pv.x, v1 = ev.y + pv.y, v2 = ev.z + pv.z, v3 = ev.w + pv.w;
  float s = wred_sum(v0 + v1 + v2 + v3);
  float q = wred_sum(v0 * v0 + v1 * v1 + v2 * v2 + v3 * v3);
  float mean = s * (1.0f / 256.0f);
  float var = q * (1.0f / 256.0f) - mean * mean;
  float rstd = rsqrtf(var + 1e-5f);
  float4 gv = *(const float4*)(g + e0);
  float4 bv = *(const float4*)(b + e0);
  *(ushort4*)(x2tb + (size_t)row * 256 + e0) = make_ushort4(
      f2bf((v0 - mean) * rstd * gv.x + bv.x + pv.x),
      f2bf((v1 - mean) * rstd * gv.y + bv.y + pv.y),
      f2bf((v2 - mean) * rstd * gv.z + bv.z + pv.z),
      f2bf((v3 - mean) * rstd * gv.w + bv.w + pv.w));
}

// ---------------- generic 64x64-tile GEMM, K=256, bf16 out: C = A @ B^T ----------------
__global__ __launch_bounds__(256) void gemm64_kernel(
    const unsigned short* A, int lda, int offA,
    const unsigned short* B, int ldb, int offB,
    unsigned short* C, int ldc, int offC) {
  __shared__ unsigned short As[64 * 64];
  __shared__ unsigned short Bs[64 * 64];
  int t = threadIdx.x, w = t >> 6, lane = t & 63;
  int li = lane & 15, hi = lane >> 4;
  int n0 = blockIdx.x * 64, m0 = blockIdx.y * 64, z = blockIdx.z;
  A += (size_t)z * offA; B += (size_t)z * offB; C += (size_t)z * offC;
  int r_in = lane >> 3, cb = (lane & 7) * 8;
  f32x4 acc[4] = {};
  for (int kt = 0; kt < 4; ++kt) {
#pragma unroll
    for (int it = 0; it < 2; ++it) {
      int rowblk = it * 32 + w * 8;
      gld16(A + (size_t)(m0 + rowblk + r_in) * lda + kt * 64 + cb, As + rowblk * 64);
      gld16(B + (size_t)(n0 + rowblk + r_in) * ldb + kt * 64 + cb, Bs + rowblk * 64);
    }
    __syncthreads();
#pragma unroll
    for (int kk = 0; kk < 2; ++kk) {
      bf16x8 bf = *(const bf16x8*)(Bs + (w * 16 + li) * 64 + kk * 32 + hi * 8);
#pragma unroll
      for (int m = 0; m < 4; ++m) {
        bf16x8 af = *(const bf16x8*)(As + (m * 16 + li) * 64 + kk * 32 + hi * 8);
        acc[m] = __builtin_amdgcn_mfma_f32_16x16x32_bf16(af, bf, acc[m], 0, 0, 0);
      }
    }
    __syncthreads();
  }
  int col = n0 + w * 16 + li;
#pragma unroll
  for (int m = 0; m < 4; ++m)
#pragma unroll
    for (int j = 0; j < 4; ++j)
      C[(size_t)(m0 + m * 16 + hi * 4 + j) * ldc + col] = f2bf(acc[m][j]);
}

// ---------------- Y GEMM: yt[r][h*256+e2] = sum_e1 x2tb[r][e1] * NT[h][e2][e1] ----------------
// 128x128 tile; grid (2, 64, 4).
__global__ __launch_bounds__(256) void gemm128_kernel(const unsigned short* A,
                                                      const unsigned short* B,
                                                      unsigned short* C) {
  __shared__ unsigned short S[2 * 128 * 64];
  unsigned short* As = S;
  unsigned short* Bs = S + 128 * 64;
  int t = threadIdx.x, w = t >> 6, lane = t & 63;
  int m0 = blockIdx.y * 128, n0 = blockIdx.x * 128, z = blockIdx.z;
  B += (size_t)z * 65536; 
  int wr = w >> 1, wc = w & 1;
  f32x4 acc[4][4] = {};
  int r_in = lane >> 3, cb = (lane & 7) * 8;
  for (int kt = 0; kt < 4; ++kt) {
#pragma unroll
    for (int it = 0; it < 4; ++it) {
      int rowblk = it * 32 + w * 8;
      gld16(A + (size_t)(m0 + rowblk + r_in) * 256 + kt * 64 + cb, As + rowblk * 64);
      gld16(B + (size_t)(n0 + rowblk + r_in) * 256 + kt * 64 + cb, Bs + rowblk * 64);
    }
    __syncthreads();
#pragma unroll
    for (int kk = 0; kk < 2; ++kk) {
      bf16x8 af[4], bfr[4];
#pragma unroll
      for (int m = 0; m < 4; ++m)
        af[m] = *(const bf16x8*)(As + (wr * 64 + m * 16 + (lane & 15)) * 64 + kk * 32 + (lane >> 4) * 8);
#pragma unroll
      for (int n = 0; n < 4; ++n)
        bfr[n] = *(const bf16x8*)(Bs + (wc * 64 + n * 16 + (lane & 15)) * 64 + kk * 32 + (lane >> 4) * 8);
#pragma unroll
      for (int m = 0; m < 4; ++m)
#pragma unroll
        for (int n = 0; n < 4; ++n)
          acc[m][n] = __builtin_amdgcn_mfma_f32_16x16x32_bf16(af[m], bfr[n], acc[m][n], 0, 0, 0);
    }
    __syncthreads();
  }
  unsigned short* Cs = S;
#pragma unroll
  for (int m = 0; m < 4; ++m)
#pragma unroll
    for (int n = 0; n < 4; ++n) {
      int row = wr * 64 + m * 16 + ((lane >> 4)) * 4;
      int col = wc * 64 + n * 16 + (lane & 15);
#pragma unroll
      for (int j = 0; j < 4; ++j)
        Cs[(row + j) * 128 + col] = f2bf(acc[m][n][j]);
    }
  __syncthreads();
#pragma unroll
  for (int it = 0; it < 8; ++it) {
    int row = it * 16 + (t >> 4);
    int ce = (t & 15) * 8;
    *(bf16x8*)(C + (size_t)(m0 + row) * 1024 + z * 256 + n0 + ce) =
        *(const bf16x8*)(Cs + row * 128 + ce);
  }
}

// ---------------- attention per (b,h): QK = Y @ x2^T, softmax, sv = score @ x2 ----------------
__global__ __launch_bounds__(256) void attn_kernel(const int* cc, const unsigned short* yt,
                                                   const unsigned short* x2tb,
                                                   unsigned short* svb) {
  __shared__ unsigned short X2s[16384];   // [4 chunk][64 row][64 col] swizzled
  __shared__ unsigned short Ys[2][4096];  // double-buffered 64x64 chunk
  __shared__ float s_sp[4][64];
  __shared__ float s_score[64];
  __shared__ float s_nm[64];
  __shared__ int s_cc[64];
  __shared__ float s_nwinv;
  int b = blockIdx.x & 1023, h = blockIdx.x >> 10;  // same-b blocks share XCD (1024%8==0)
  int t = threadIdx.x, w = t >> 6, lane = t & 63;
  int li = lane & 15, hi = lane >> 4;

  if (t < 64) {
    int c = cc[b * 64 + t];
    s_cc[t] = c;
    s_nm[t] = (c != 0) ? 1.0f : 0.0f;
  }
  __syncthreads();
  if (w == 0) {
    float s = wred_sum(s_nm[lane]);
    if (lane == 0) s_nwinv = 1.0f / s;
  }
  float nmv[4], nmr[4];
#pragma unroll
  for (int n = 0; n < 4; ++n) nmv[n] = s_nm[n * 16 + li];
#pragma unroll
  for (int j = 0; j < 4; ++j) nmr[j] = s_nm[w * 16 + hi * 4 + j];

  int sr = lane >> 3;                 // row within 8-row group
  int sg = (lane & 7) ^ sr;           // inverse-swizzled source granule
  const unsigned short* ybase = yt + h * 256;

  // stage full x2 (4 chunks of 64 cols, each 64x64 swizzled)
#pragma unroll
  for (int ecc = 0; ecc < 4; ++ecc)
#pragma unroll
    for (int i = 0; i < 2; ++i) {
      int it = w * 2 + i, idx = it * 8 + sr;
      const unsigned short* p = x2tb + (size_t)(s_cc[idx] * 64 + idx) * 256 + ecc * 64 + sg * 8;
      gld16(p, X2s + ecc * 4096 + it * 512);
    }
  // stage Y chunk 0
#pragma unroll
  for (int i = 0; i < 2; ++i) {
    int it = w * 2 + i, idx = it * 8 + sr;
    gld16(ybase + (size_t)(s_cc[idx] * 64 + idx) * 1024 + sg * 8, Ys[0] + it * 512);
  }

  // ---- QK^T: 4 chunks of K=64, MFMA accumulate; prefetch next Y chunk ----
  f32x4 acc[4] = {};
  int cur = 0;
  for (int ec = 0; ec < 4; ++ec) {
    __syncthreads();                  // Ys[cur] (+X2s on first iter) ready
    if (ec < 3) {
#pragma unroll
      for (int i = 0; i < 2; ++i) {
        int it = w * 2 + i, idx = it * 8 + sr;
        gld16(ybase + (size_t)(s_cc[idx] * 64 + idx) * 1024 + (ec + 1) * 64 + sg * 8,
              Ys[cur ^ 1] + it * 512);
      }
    }
#pragma unroll
    for (int kk = 0; kk < 2; ++kk) {
      int rq = w * 16 + li;
      bf16x8 af = *(const bf16x8*)(Ys[cur] + rq * 64 + (((kk * 4 + hi) ^ (rq & 7)) * 8));
#pragma unroll
      for (int n = 0; n < 4; ++n) {
        int rk = n * 16 + li;
        bf16x8 bf = *(const bf16x8*)(X2s + ec * 4096 + rk * 64 + (((kk * 4 + hi) ^ (rk & 7)) * 8));
        acc[n] = __builtin_amdgcn_mfma_f32_16x16x32_bf16(af, bf, acc[n], 0, 0, 0);
      }
    }
    cur ^= 1;
  }

  // ---- in-register masked softmax + query-averaged score ----
  float sc[4] = {0.f, 0.f, 0.f, 0.f};
#pragma unroll
  for (int j = 0; j < 4; ++j) {
    float v[4];
#pragma unroll
    for (int n = 0; n < 4; ++n)
      v[n] = (nmv[n] != 0.f) ? acc[n][j] * 0.0625f : -1e30f;
    float m = fmaxf(fmaxf(v[0], v[1]), fmaxf(v[2], v[3]));
    m = fmaxf(m, __shfl_xor(m, 1, 64));
    m = fmaxf(m, __shfl_xor(m, 2, 64));
    m = fmaxf(m, __shfl_xor(m, 4, 64));
    m = fmaxf(m, __shfl_xor(m, 8, 64));
    float p[4];
#pragma unroll
    for (int n = 0; n < 4; ++n) p[n] = nmv[n] * __expf(v[n] - m);
    float s = (p[0] + p[1]) + (p[2] + p[3]);
    s += __shfl_xor(s, 1, 64);
    s += __shfl_xor(s, 2, 64);
    s += __shfl_xor(s, 4, 64);
    s += __shfl_xor(s, 8, 64);
    float f = nmr[j] / s;
#pragma unroll
    for (int n = 0; n < 4; ++n) sc[n] += p[n] * f;
  }
#pragma unroll
  for (int n = 0; n < 4; ++n) {
    sc[n] += __shfl_xor(sc[n], 16, 64);
    sc[n] += __shfl_xor(sc[n], 32, 64);
  }
  if (hi == 0) {
#pragma unroll
    for (int n = 0; n < 4; ++n) s_sp[w][n * 16 + li] = sc[n];
  }
  __syncthreads();
  if (t < 64)
    s_score[t] = (s_sp[0][t] + s_sp[1][t] + s_sp[2][t] + s_sp[3][t]) * s_nwinv;
  __syncthreads();

  // ---- sv[e] = sum_k score[k] * x2[row_k][e]; wave w owns chunk w, lane = col ----
  const unsigned short* Xw = X2s + w * 4096;
  float o = 0.f;
#pragma unroll
  for (int k4 = 0; k4 < 16; ++k4) {
    float4 sv4 = *(const float4*)(s_score + k4 * 4);
    o += sv4.x * bf2f(Xw[(k4 * 4 + 0) * 64 + ((((lane >> 3) ^ ((k4 * 4 + 0) & 7)) << 3) | (lane & 7))]);
    o += sv4.y * bf2f(Xw[(k4 * 4 + 1) * 64 + ((((lane >> 3) ^ ((k4 * 4 + 1) & 7)) << 3) | (lane & 7))]);
    o += sv4.z * bf2f(Xw[(k4 * 4 + 2) * 64 + ((((lane >> 3) ^ ((k4 * 4 + 2) & 7)) << 3) | (lane & 7))]);
    o += sv4.w * bf2f(Xw[(k4 * 4 + 3) * 64 + ((((lane >> 3) ^ ((k4 * 4 + 3) & 7)) << 3) | (lane & 7))]);
  }
  svb[b * 1024 + h * 256 + t] = f2bf(o);
}

// ---------------- fc GEMM: fco(1024x256) = svb(1024x1024) @ wfold(256x1024)^T + fc_b ----------------
__global__ __launch_bounds__(256) void fc_mfma_kernel(const unsigned short* aob,
                                                      const unsigned short* fc_wb,
                                                      const float* fc_b, float* fco) {
  __shared__ unsigned short As[64 * 64];
  __shared__ unsigned short Bs[64 * 64];
  int t = threadIdx.x, w = t >> 6, lane = t & 63;
  int li = lane & 15, hi = lane >> 4;
  int n0 = blockIdx.x * 64;
  int m0 = blockIdx.y * 64;
  int r_in = lane >> 3, cb = (lane & 7) * 8;
  f32x4 acc[4] = {};
  for (int kt = 0; kt < 16; ++kt) {
#pragma unroll
    for (int it = 0; it < 2; ++it) {
      int rowblk = it * 32 + w * 8;
      gld16(aob + (size_t)(m0 + rowblk + r_in) * 1024 + kt * 64 + cb, As + rowblk * 64);
      gld16(fc_wb + (size_t)(n0 + rowblk + r_in) * 1024 + kt * 64 + cb, Bs + rowblk * 64);
    }
    __syncthreads();
#pragma unroll
    for (int kk = 0; kk < 2; ++kk) {
      bf16x8 bf = *(const bf16x8*)(Bs + (w * 16 + li) * 64 + kk * 32 + hi * 8);
#pragma unroll
      for (int m = 0; m < 4; ++m) {
        bf16x8 af = *(const bf16x8*)(As + (m * 16 + li) * 64 + kk * 32 + hi * 8);
        acc[m] = __builtin_amdgcn_mfma_f32_16x16x32_bf16(af, bf, acc[m], 0, 0, 0);
      }
    }
    __syncthreads();
  }
  int col = n0 + w * 16 + li;
  float bias = fc_b[col];
#pragma unroll
  for (int m = 0; m < 4; ++m)
#pragma unroll
    for (int j = 0; j < 4; ++j)
      fco[(size_t)(m0 + m * 16 + hi * 4 + j) * 256 + col] = acc[m][j] + bias;
}

// ---------------- final: xmean gather (bf16 table) + LN chain ----------------
__device__ __forceinline__ float block_ln(float v, int t, float eps, const float* g,
                                          const float* b, float* s_part) {
  int w = t >> 6, lane = t & 63;
  __syncthreads();
  float s = wred_sum(v), q = wred_sum(v * v);
  if (lane == 0) { s_part[w] = s; s_part[4 + w] = q; }
  __syncthreads();
  float sum = s_part[0] + s_part[1] + s_part[2] + s_part[3];
  float sq = s_part[4] + s_part[5] + s_part[6] + s_part[7];
  float mean = sum * (1.0f / 256.0f);
  float var = sq * (1.0f / 256.0f) - mean * mean;
  float rstd = rsqrtf(var + eps);
  return (v - mean) * rstd * g[t] + b[t];
}

__global__ __launch_bounds__(256) void final_kernel(
    const int* cc, const unsigned short* x2tb, const float* posmean, const float* fco,
    const float* sln_g, const float* sln_b, const float* ln1_g, const float* ln1_b,
    const float* ffln_g, const float* ffln_b, const float* ln2_g, const float* ln2_b,
    float* out) {
  __shared__ int s_cc[64];
  __shared__ float s_part[8];
  int b = blockIdx.x, t = threadIdx.x;
  if (t < 64) s_cc[t] = cc[b * 64 + t];
  __syncthreads();

  float xa = 0.f;
#pragma unroll 8
  for (int l = 0; l < 64; l++) xa += bf2f(x2tb[(size_t)(s_cc[l] * 64 + l) * 256 + t]);
  float xm = xa * (1.0f / 64.0f) - posmean[t];

  float v = fco[(size_t)b * 256 + t];
  v = block_ln(v, t, 1e-5f, sln_g, sln_b, s_part);
  v = v + xm;
  v = block_ln(v, t, 1e-5f, ln1_g, ln1_b, s_part);
  float ff = block_ln(v, t, 1e-6f, ffln_g, ffln_b, s_part);
  float w2 = ff + v;
  float fin = block_ln(w2, t, 1e-5f, ln2_g, ln2_b, s_part);
  out[b * 256 + t] = fin;
}

extern "C" void kernel_launch(void* const* d_in, const int* in_sizes, int n_in,
                              void* d_out, int out_size, void* d_ws, size_t ws_size,
                              hipStream_t stream) {
  const int* char_code = (const int*)d_in[0];
  const float* emb    = (const float*)d_in[2];
  const float* qkv_w  = (const float*)d_in[3];
  const float* ln0_g  = (const float*)d_in[4];
  const float* ln0_b  = (const float*)d_in[5];
  const float* fc_w   = (const float*)d_in[6];
  const float* fc_b   = (const float*)d_in[7];
  const float* sln_g  = (const float*)d_in[8];
  const float* sln_b  = (const float*)d_in[9];
  const float* ln1_g  = (const float*)d_in[10];
  const float* ln1_b  = (const float*)d_in[11];
  const float* ffln_g = (const float*)d_in[16];
  const float* ffln_b = (const float*)d_in[17];
  const float* ln2_g  = (const float*)d_in[18];
  const float* ln2_b  = (const float*)d_in[19];

  float* ws = (float*)d_ws;
  float* pos = ws;                                          // 16384 f32
  float* posmean = pos + 16384;                             // 256 f32
  unsigned short* x2tb  = (unsigned short*)(posmean + 256); // 8192*256
  unsigned short* yt    = x2tb + (size_t)8192 * 256;        // 8192*1024
  unsigned short* wqTb  = yt + (size_t)8192 * 1024;         // 4*256*256
  unsigned short* wkTb  = wqTb + 262144;
  unsigned short* wvTb  = wkTb + 262144;
  unsigned short* fc_wb = wvTb + 262144;                    // 256*1024
  unsigned short* NTb   = fc_wb + 262144;                   // 4*256*256
  unsigned short* wfoldb= NTb + 262144;                     // 256*1024
  unsigned short* svb   = wfoldb + 262144;                  // 1024*1024
  float* fco = (float*)(svb + (size_t)1024 * 1024);         // 1024*256 f32

  pos_kernel<<<64, 256, 0, stream>>>(pos);
  posmean_kernel<<<1, 256, 0, stream>>>(pos, posmean);
  cvt_w_kernel<<<256, 256, 0, stream>>>(fc_w, fc_wb);
  transpose_cvt_kernel<<<dim3(16, 4), 256, 0, stream>>>(qkv_w, wqTb, 0);
  transpose_cvt_kernel<<<dim3(16, 4), 256, 0, stream>>>(qkv_w, wkTb, 256);
  transpose_cvt_kernel<<<dim3(16, 4), 256, 0, stream>>>(qkv_w, wvTb, 512);
  x2t_kernel<<<2048, 256, 0, stream>>>(emb, pos, ln0_g, ln0_b, x2tb);
  // NT[h][e2][e1] = sum_i Wk[i,e2] Wq[i,e1]
  gemm64_kernel<<<dim3(4, 4, 4), 256, 0, stream>>>(wkTb, 256, 65536, wqTb, 256, 65536,
                                                   NTb, 256, 65536);
  // wfold[o][h*256+e] = sum_e' fc_w[o,h*256+e'] Wv_h[e',e]
  gemm64_kernel<<<dim3(4, 4, 4), 256, 0, stream>>>(fc_wb, 1024, 256, wvTb, 256, 65536,
                                                   wfoldb, 1024, 256);
  // yt = x2tb @ NT^T (per head)
  gemm128_kernel<<<dim3(2, 64, 4), 256, 0, stream>>>(x2tb, NTb, yt);
  attn_kernel<<<4096, 256, 0, stream>>>(char_code, yt, x2tb, svb);
  fc_mfma_kernel<<<dim3(4, 16), 256, 0, stream>>>(svb, wfoldb, fc_b, fco);
  final_kernel<<<1024, 256, 0, stream>>>(char_code, x2tb, posmean, fco,
                                         sln_g, sln_b, ln1_g, ln1_b,
                                         ffln_g, ffln_b, ln2_g, ln2_b, (float*)d_out);
}

// Round 6
// 104.972 us; speedup vs baseline: 5.1436x; 1.0717x over previous
//
#include <hip/hip_runtime.h>

// Problem constants: V=128, E=256, H=4, B=1024, L=64
// Algebra: attn out folds V away: out = sv @ Wv^T, Wv folded into fc (W').
//          QK^T = Y @ x2^T with Y = X2 @ (Wq^T Wk) (NT precomputed, per head).
// attn: one block per batch b; wave w = head h; X2 staged once; Y direct global->reg.

typedef __attribute__((ext_vector_type(8))) short bf16x8;
typedef __attribute__((ext_vector_type(4))) float f32x4;

__device__ __forceinline__ float wred_sum(float v) {
#pragma unroll
  for (int off = 32; off > 0; off >>= 1) v += __shfl_xor(v, off, 64);
  return v;
}
__device__ __forceinline__ float bf2f(unsigned short u) {
  union { unsigned int i; float f; } x; x.i = ((unsigned int)u) << 16; return x.f;
}
__device__ __forceinline__ unsigned short f2bf(float f) {
  union { float f; unsigned int i; } x; x.f = f;
  unsigned int r = x.i + 0x7FFFu + ((x.i >> 16) & 1u);
  return (unsigned short)(r >> 16);
}
__device__ __forceinline__ void gld16(const unsigned short* g, unsigned short* l) {
  __builtin_amdgcn_global_load_lds(
      (const __attribute__((address_space(1))) unsigned int*)g,
      (__attribute__((address_space(3))) unsigned int*)l, 16, 0, 0);
}

// ---------------- pos table ----------------
__global__ __launch_bounds__(256) void pos_kernel(float* pos) {
  int idx = blockIdx.x * 256 + threadIdx.x;
  int l = idx >> 8, e = idx & 255;
  int i = e >> 1;
  float freq = powf(10000.0f, -(float)i * (1.0f / 128.0f));
  float ph = (float)l * freq;
  pos[idx] = (e & 1) ? cosf(ph) : sinf(ph);
}

__global__ __launch_bounds__(256) void posmean_kernel(const float* pos, float* posmean) {
  int e = threadIdx.x;
  float s = 0.f;
#pragma unroll 8
  for (int l = 0; l < 64; l++) s += pos[l * 256 + e];
  posmean[e] = s * (1.0f / 64.0f);
}

// ---------------- convert f32 -> bf16 ----------------
__global__ __launch_bounds__(256) void cvt_w_kernel(const float* w, unsigned short* wb) {
  int i = (blockIdx.x * 256 + threadIdx.x) * 4;
  float4 v = *(const float4*)(w + i);
  *(ushort4*)(wb + i) = make_ushort4(f2bf(v.x), f2bf(v.y), f2bf(v.z), f2bf(v.w));
}

// ---------------- transpose+cvt weight slice: wT[h][e][i] = qkv_w[h*768+sel+i][e] ----------------
__global__ __launch_bounds__(256) void transpose_cvt_kernel(const float* qkv_w,
                                                            unsigned short* wT, int sel) {
  __shared__ float T[64][65];
  int h = blockIdx.y;
  int ti = (blockIdx.x & 3) * 64;
  int te = (blockIdx.x >> 2) * 64;
  int t = threadIdx.x, r = t >> 4, c4 = (t & 15) * 4;
#pragma unroll
  for (int rep = 0; rep < 4; ++rep) {
    int il = rep * 16 + r;
    float4 v = *(const float4*)(qkv_w + (size_t)(h * 768 + sel + ti + il) * 256 + te + c4);
    T[il][c4] = v.x; T[il][c4 + 1] = v.y; T[il][c4 + 2] = v.z; T[il][c4 + 3] = v.w;
  }
  __syncthreads();
#pragma unroll
  for (int rep = 0; rep < 4; ++rep) {
    int el = rep * 16 + r;
    ushort4 o = make_ushort4(f2bf(T[c4 + 0][el]), f2bf(T[c4 + 1][el]),
                             f2bf(T[c4 + 2][el]), f2bf(T[c4 + 3][el]));
    *(ushort4*)(wT + (size_t)h * 65536 + (size_t)(te + el) * 256 + ti + c4) = o;
  }
}

// ---------------- x2 table: bf16(LN0(emb[c]+pos[l]) + pos[l]), 8192 rows ----------------
__global__ __launch_bounds__(256) void x2t_kernel(const float* emb, const float* pos,
                                                  const float* g, const float* b,
                                                  unsigned short* x2tb) {
  int w = threadIdx.x >> 6, lane = threadIdx.x & 63;
  int row = blockIdx.x * 4 + w;
  int c = row >> 6, l = row & 63;
  int e0 = lane * 4;
  float4 ev = *(const float4*)(emb + c * 256 + e0);
  float4 pv = *(const float4*)(pos + l * 256 + e0);
  float v0 = ev.x + pv.x, v1 = ev.y + pv.y, v2 = ev.z + pv.z, v3 = ev.w + pv.w;
  float s = wred_sum(v0 + v1 + v2 + v3);
  float q = wred_sum(v0 * v0 + v1 * v1 + v2 * v2 + v3 * v3);
  float mean = s * (1.0f / 256.0f);
  float var = q * (1.0f / 256.0f) - mean * mean;
  float rstd = rsqrtf(var + 1e-5f);
  float4 gv = *(const float4*)(g + e0);
  float4 bv = *(const float4*)(b + e0);
  *(ushort4*)(x2tb + (size_t)row * 256 + e0) = make_ushort4(
      f2bf((v0 - mean) * rstd * gv.x + bv.x + pv.x),
      f2bf((v1 - mean) * rstd * gv.y + bv.y + pv.y),
      f2bf((v2 - mean) * rstd * gv.z + bv.z + pv.z),
      f2bf((v3 - mean) * rstd * gv.w + bv.w + pv.w));
}

// ---------------- generic 64x64-tile GEMM, K=256, bf16 out: C = A @ B^T ----------------
__global__ __launch_bounds__(256) void gemm64_kernel(
    const unsigned short* A, int lda, int offA,
    const unsigned short* B, int ldb, int offB,
    unsigned short* C, int ldc, int offC) {
  __shared__ unsigned short As[64 * 64];
  __shared__ unsigned short Bs[64 * 64];
  int t = threadIdx.x, w = t >> 6, lane = t & 63;
  int li = lane & 15, hi = lane >> 4;
  int n0 = blockIdx.x * 64, m0 = blockIdx.y * 64, z = blockIdx.z;
  A += (size_t)z * offA; B += (size_t)z * offB; C += (size_t)z * offC;
  int r_in = lane >> 3, cb = (lane & 7) * 8;
  f32x4 acc[4] = {};
  for (int kt = 0; kt < 4; ++kt) {
#pragma unroll
    for (int it = 0; it < 2; ++it) {
      int rowblk = it * 32 + w * 8;
      gld16(A + (size_t)(m0 + rowblk + r_in) * lda + kt * 64 + cb, As + rowblk * 64);
      gld16(B + (size_t)(n0 + rowblk + r_in) * ldb + kt * 64 + cb, Bs + rowblk * 64);
    }
    __syncthreads();
#pragma unroll
    for (int kk = 0; kk < 2; ++kk) {
      bf16x8 bf = *(const bf16x8*)(Bs + (w * 16 + li) * 64 + kk * 32 + hi * 8);
#pragma unroll
      for (int m = 0; m < 4; ++m) {
        bf16x8 af = *(const bf16x8*)(As + (m * 16 + li) * 64 + kk * 32 + hi * 8);
        acc[m] = __builtin_amdgcn_mfma_f32_16x16x32_bf16(af, bf, acc[m], 0, 0, 0);
      }
    }
    __syncthreads();
  }
  int col = n0 + w * 16 + li;
#pragma unroll
  for (int m = 0; m < 4; ++m)
#pragma unroll
    for (int j = 0; j < 4; ++j)
      C[(size_t)(m0 + m * 16 + hi * 4 + j) * ldc + col] = f2bf(acc[m][j]);
}

// ---------------- Y GEMM: yt[r][h*256+e2] = sum_e1 x2tb[r][e1] * NT[h][e2][e1] ----------------
__global__ __launch_bounds__(256) void gemm128_kernel(const unsigned short* A,
                                                      const unsigned short* B,
                                                      unsigned short* C) {
  __shared__ unsigned short S[2 * 128 * 64];
  unsigned short* As = S;
  unsigned short* Bs = S + 128 * 64;
  int t = threadIdx.x, w = t >> 6, lane = t & 63;
  int m0 = blockIdx.y * 128, n0 = blockIdx.x * 128, z = blockIdx.z;
  B += (size_t)z * 65536;
  int wr = w >> 1, wc = w & 1;
  f32x4 acc[4][4] = {};
  int r_in = lane >> 3, cb = (lane & 7) * 8;
  for (int kt = 0; kt < 4; ++kt) {
#pragma unroll
    for (int it = 0; it < 4; ++it) {
      int rowblk = it * 32 + w * 8;
      gld16(A + (size_t)(m0 + rowblk + r_in) * 256 + kt * 64 + cb, As + rowblk * 64);
      gld16(B + (size_t)(n0 + rowblk + r_in) * 256 + kt * 64 + cb, Bs + rowblk * 64);
    }
    __syncthreads();
#pragma unroll
    for (int kk = 0; kk < 2; ++kk) {
      bf16x8 af[4], bfr[4];
#pragma unroll
      for (int m = 0; m < 4; ++m)
        af[m] = *(const bf16x8*)(As + (wr * 64 + m * 16 + (lane & 15)) * 64 + kk * 32 + (lane >> 4) * 8);
#pragma unroll
      for (int n = 0; n < 4; ++n)
        bfr[n] = *(const bf16x8*)(Bs + (wc * 64 + n * 16 + (lane & 15)) * 64 + kk * 32 + (lane >> 4) * 8);
#pragma unroll
      for (int m = 0; m < 4; ++m)
#pragma unroll
        for (int n = 0; n < 4; ++n)
          acc[m][n] = __builtin_amdgcn_mfma_f32_16x16x32_bf16(af[m], bfr[n], acc[m][n], 0, 0, 0);
    }
    __syncthreads();
  }
  unsigned short* Cs = S;
#pragma unroll
  for (int m = 0; m < 4; ++m)
#pragma unroll
    for (int n = 0; n < 4; ++n) {
      int row = wr * 64 + m * 16 + ((lane >> 4)) * 4;
      int col = wc * 64 + n * 16 + (lane & 15);
#pragma unroll
      for (int j = 0; j < 4; ++j)
        Cs[(row + j) * 128 + col] = f2bf(acc[m][n][j]);
    }
  __syncthreads();
#pragma unroll
  for (int it = 0; it < 8; ++it) {
    int row = it * 16 + (t >> 4);
    int ce = (t & 15) * 8;
    *(bf16x8*)(C + (size_t)(m0 + row) * 1024 + z * 256 + n0 + ce) =
        *(const bf16x8*)(Cs + row * 128 + ce);
  }
}

// ---------------- attention: one block per b, wave = head ----------------
// X2s: 4 chunks x (64 rows x 64 cols) swizzled; chunk stride 4112 ushorts (+32B pad
// so PV's cross-chunk read pattern is 2-way/free). Y fragments: global->reg, dbuf.
// Barriers: 2 total.
__global__ __launch_bounds__(256) void attn_kernel(const int* cc, const unsigned short* yt,
                                                   const unsigned short* x2tb,
                                                   unsigned short* svb) {
  __shared__ unsigned short X2s[4 * 4112];
  __shared__ float s_nm[64];
  __shared__ int s_cc[64];
  int b = blockIdx.x;
  int t = threadIdx.x, w = t >> 6, lane = t & 63;
  int li = lane & 15, hi = lane >> 4;

  if (t < 64) {
    int c = cc[b * 64 + t];
    s_cc[t] = c;
    s_nm[t] = (c != 0) ? 1.0f : 0.0f;
  }
  __syncthreads();

  int sr = lane >> 3;                 // row within 8-row group
  int sg = (lane & 7) ^ sr;           // inverse-swizzled source granule
  // ---- stage X2 once (32KB, 8 issues/thread) ----
#pragma unroll
  for (int ecc = 0; ecc < 4; ++ecc)
#pragma unroll
    for (int i = 0; i < 2; ++i) {
      int it = w * 2 + i, idx = it * 8 + sr;
      gld16(x2tb + (size_t)(s_cc[idx] * 64 + idx) * 256 + ecc * 64 + sg * 8,
            X2s + ecc * 4112 + it * 512);
    }

  // per-lane Y row pointers (head = wave w); A-frag lane li = q-row m*16+li
  const unsigned short* rowp[4];
#pragma unroll
  for (int m = 0; m < 4; ++m) {
    int idx = m * 16 + li;
    rowp[m] = yt + (size_t)(s_cc[idx] * 64 + idx) * 1024 + w * 256;
  }
  float nmv[4];
#pragma unroll
  for (int n = 0; n < 4; ++n) nmv[n] = s_nm[n * 16 + li];
  float nwinv = 1.0f / wred_sum(s_nm[lane]);

  // preload Y chunk 0 to regs (overlaps X2 stage drain)
  bf16x8 yA[8], yB[8];
#pragma unroll
  for (int kk = 0; kk < 2; ++kk)
#pragma unroll
    for (int m = 0; m < 4; ++m)
      yA[kk * 4 + m] = *(const bf16x8*)(rowp[m] + kk * 32 + hi * 8);

  __syncthreads();   // X2s staged (also drains yA)

  // ---- QK^T: 4 chunks, no barriers; register-dbuf Y prefetch ----
  f32x4 acc[4][4] = {};
#pragma unroll
  for (int ec = 0; ec < 4; ++ec) {
    const bf16x8* cur = (ec & 1) ? yB : yA;
    bf16x8* nxt = (ec & 1) ? yA : yB;
    if (ec < 3) {
#pragma unroll
      for (int kk = 0; kk < 2; ++kk)
#pragma unroll
        for (int m = 0; m < 4; ++m)
          nxt[kk * 4 + m] = *(const bf16x8*)(rowp[m] + (ec + 1) * 64 + kk * 32 + hi * 8);
    }
#pragma unroll
    for (int kk = 0; kk < 2; ++kk)
#pragma unroll
      for (int n = 0; n < 4; ++n) {
        int rk = n * 16 + li;
        bf16x8 bf = *(const bf16x8*)(X2s + ec * 4112 + rk * 64 + (((kk * 4 + hi) ^ (rk & 7)) * 8));
#pragma unroll
        for (int m = 0; m < 4; ++m)
          acc[m][n] = __builtin_amdgcn_mfma_f32_16x16x32_bf16(cur[kk * 4 + m], bf, acc[m][n], 0, 0, 0);
      }
  }

  // ---- wave-local masked softmax + query-averaged score ----
  // acc[m][n][j]: q = m*16 + hi*4 + j, k = n*16 + li
  float sc[4] = {0.f, 0.f, 0.f, 0.f};
#pragma unroll
  for (int m = 0; m < 4; ++m)
#pragma unroll
    for (int j = 0; j < 4; ++j) {
      float nmq = s_nm[m * 16 + hi * 4 + j];
      float v[4];
#pragma unroll
      for (int n = 0; n < 4; ++n)
        v[n] = (nmv[n] != 0.f) ? acc[m][n][j] * 0.0625f : -1e30f;
      float mx = fmaxf(fmaxf(v[0], v[1]), fmaxf(v[2], v[3]));
      mx = fmaxf(mx, __shfl_xor(mx, 1, 64));
      mx = fmaxf(mx, __shfl_xor(mx, 2, 64));
      mx = fmaxf(mx, __shfl_xor(mx, 4, 64));
      mx = fmaxf(mx, __shfl_xor(mx, 8, 64));
      float p[4];
#pragma unroll
      for (int n = 0; n < 4; ++n) p[n] = nmv[n] * __expf(v[n] - mx);
      float s = (p[0] + p[1]) + (p[2] + p[3]);
      s += __shfl_xor(s, 1, 64);
      s += __shfl_xor(s, 2, 64);
      s += __shfl_xor(s, 4, 64);
      s += __shfl_xor(s, 8, 64);
      float f = nmq / s;
#pragma unroll
      for (int n = 0; n < 4; ++n) sc[n] += p[n] * f;
    }
#pragma unroll
  for (int n = 0; n < 4; ++n) {
    sc[n] += __shfl_xor(sc[n], 16, 64);
    sc[n] += __shfl_xor(sc[n], 32, 64);
    sc[n] *= nwinv;                 // lane holds score[n*16 + li]
  }

  // ---- PV: sv[e] = sum_k score[k]*x2[k][e]; lane owns cols lane*4..+3 of its head ----
  int cg = li >> 1;                  // granule of cols (li*4)
  int sub = (lane & 1) * 4;          // ushort offset within granule
  const unsigned short* Xc = X2s + (lane >> 4) * 4112;
  float o0 = 0.f, o1 = 0.f, o2 = 0.f, o3 = 0.f;
#pragma unroll
  for (int k = 0; k < 64; ++k) {
    float sk = __shfl(sc[k >> 4], k & 15, 64);
    ushort4 xv = *(const ushort4*)(Xc + k * 64 + ((cg ^ (k & 7)) * 8) + sub);
    o0 = fmaf(sk, bf2f(xv.x), o0);
    o1 = fmaf(sk, bf2f(xv.y), o1);
    o2 = fmaf(sk, bf2f(xv.z), o2);
    o3 = fmaf(sk, bf2f(xv.w), o3);
  }
  *(ushort4*)(svb + (size_t)b * 1024 + w * 256 + lane * 4) =
      make_ushort4(f2bf(o0), f2bf(o1), f2bf(o2), f2bf(o3));
}

// ---------------- fc GEMM: fco(1024x256) = svb(1024x1024) @ wfold(256x1024)^T + fc_b ----------------
__global__ __launch_bounds__(256) void fc_mfma_kernel(const unsigned short* aob,
                                                      const unsigned short* fc_wb,
                                                      const float* fc_b, float* fco) {
  __shared__ unsigned short As[64 * 64];
  __shared__ unsigned short Bs[64 * 64];
  int t = threadIdx.x, w = t >> 6, lane = t & 63;
  int li = lane & 15, hi = lane >> 4;
  int n0 = blockIdx.x * 64;
  int m0 = blockIdx.y * 64;
  int r_in = lane >> 3, cb = (lane & 7) * 8;
  f32x4 acc[4] = {};
  for (int kt = 0; kt < 16; ++kt) {
#pragma unroll
    for (int it = 0; it < 2; ++it) {
      int rowblk = it * 32 + w * 8;
      gld16(aob + (size_t)(m0 + rowblk + r_in) * 1024 + kt * 64 + cb, As + rowblk * 64);
      gld16(fc_wb + (size_t)(n0 + rowblk + r_in) * 1024 + kt * 64 + cb, Bs + rowblk * 64);
    }
    __syncthreads();
#pragma unroll
    for (int kk = 0; kk < 2; ++kk) {
      bf16x8 bf = *(const bf16x8*)(Bs + (w * 16 + li) * 64 + kk * 32 + hi * 8);
#pragma unroll
      for (int m = 0; m < 4; ++m) {
        bf16x8 af = *(const bf16x8*)(As + (m * 16 + li) * 64 + kk * 32 + hi * 8);
        acc[m] = __builtin_amdgcn_mfma_f32_16x16x32_bf16(af, bf, acc[m], 0, 0, 0);
      }
    }
    __syncthreads();
  }
  int col = n0 + w * 16 + li;
  float bias = fc_b[col];
#pragma unroll
  for (int m = 0; m < 4; ++m)
#pragma unroll
    for (int j = 0; j < 4; ++j)
      fco[(size_t)(m0 + m * 16 + hi * 4 + j) * 256 + col] = acc[m][j] + bias;
}

// ---------------- final: xmean gather (bf16 table) + LN chain ----------------
__device__ __forceinline__ float block_ln(float v, int t, float eps, const float* g,
                                          const float* b, float* s_part) {
  int w = t >> 6, lane = t & 63;
  __syncthreads();
  float s = wred_sum(v), q = wred_sum(v * v);
  if (lane == 0) { s_part[w] = s; s_part[4 + w] = q; }
  __syncthreads();
  float sum = s_part[0] + s_part[1] + s_part[2] + s_part[3];
  float sq = s_part[4] + s_part[5] + s_part[6] + s_part[7];
  float mean = sum * (1.0f / 256.0f);
  float var = sq * (1.0f / 256.0f) - mean * mean;
  float rstd = rsqrtf(var + eps);
  return (v - mean) * rstd * g[t] + b[t];
}

__global__ __launch_bounds__(256) void final_kernel(
    const int* cc, const unsigned short* x2tb, const float* posmean, const float* fco,
    const float* sln_g, const float* sln_b, const float* ln1_g, const float* ln1_b,
    const float* ffln_g, const float* ffln_b, const float* ln2_g, const float* ln2_b,
    float* out) {
  __shared__ int s_cc[64];
  __shared__ float s_part[8];
  int b = blockIdx.x, t = threadIdx.x;
  if (t < 64) s_cc[t] = cc[b * 64 + t];
  __syncthreads();

  float xa = 0.f;
#pragma unroll 8
  for (int l = 0; l < 64; l++) xa += bf2f(x2tb[(size_t)(s_cc[l] * 64 + l) * 256 + t]);
  float xm = xa * (1.0f / 64.0f) - posmean[t];

  float v = fco[(size_t)b * 256 + t];
  v = block_ln(v, t, 1e-5f, sln_g, sln_b, s_part);
  v = v + xm;
  v = block_ln(v, t, 1e-5f, ln1_g, ln1_b, s_part);
  float ff = block_ln(v, t, 1e-6f, ffln_g, ffln_b, s_part);
  float w2 = ff + v;
  float fin = block_ln(w2, t, 1e-5f, ln2_g, ln2_b, s_part);
  out[b * 256 + t] = fin;
}

extern "C" void kernel_launch(void* const* d_in, const int* in_sizes, int n_in,
                              void* d_out, int out_size, void* d_ws, size_t ws_size,
                              hipStream_t stream) {
  const int* char_code = (const int*)d_in[0];
  const float* emb    = (const float*)d_in[2];
  const float* qkv_w  = (const float*)d_in[3];
  const float* ln0_g  = (const float*)d_in[4];
  const float* ln0_b  = (const float*)d_in[5];
  const float* fc_w   = (const float*)d_in[6];
  const float* fc_b   = (const float*)d_in[7];
  const float* sln_g  = (const float*)d_in[8];
  const float* sln_b  = (const float*)d_in[9];
  const float* ln1_g  = (const float*)d_in[10];
  const float* ln1_b  = (const float*)d_in[11];
  const float* ffln_g = (const float*)d_in[16];
  const float* ffln_b = (const float*)d_in[17];
  const float* ln2_g  = (const float*)d_in[18];
  const float* ln2_b  = (const float*)d_in[19];

  float* ws = (float*)d_ws;
  float* pos = ws;                                          // 16384 f32
  float* posmean = pos + 16384;                             // 256 f32
  unsigned short* x2tb  = (unsigned short*)(posmean + 256); // 8192*256
  unsigned short* yt    = x2tb + (size_t)8192 * 256;        // 8192*1024
  unsigned short* wqTb  = yt + (size_t)8192 * 1024;         // 4*256*256
  unsigned short* wkTb  = wqTb + 262144;
  unsigned short* wvTb  = wkTb + 262144;
  unsigned short* fc_wb = wvTb + 262144;                    // 256*1024
  unsigned short* NTb   = fc_wb + 262144;                   // 4*256*256
  unsigned short* wfoldb= NTb + 262144;                     // 256*1024
  unsigned short* svb   = wfoldb + 262144;                  // 1024*1024
  float* fco = (float*)(svb + (size_t)1024 * 1024);         // 1024*256 f32

  pos_kernel<<<64, 256, 0, stream>>>(pos);
  posmean_kernel<<<1, 256, 0, stream>>>(pos, posmean);
  cvt_w_kernel<<<256, 256, 0, stream>>>(fc_w, fc_wb);
  transpose_cvt_kernel<<<dim3(16, 4), 256, 0, stream>>>(qkv_w, wqTb, 0);
  transpose_cvt_kernel<<<dim3(16, 4), 256, 0, stream>>>(qkv_w, wkTb, 256);
  transpose_cvt_kernel<<<dim3(16, 4), 256, 0, stream>>>(qkv_w, wvTb, 512);
  x2t_kernel<<<2048, 256, 0, stream>>>(emb, pos, ln0_g, ln0_b, x2tb);
  // NT[h][e2][e1] = sum_i Wk[i,e2] Wq[i,e1]
  gemm64_kernel<<<dim3(4, 4, 4), 256, 0, stream>>>(wkTb, 256, 65536, wqTb, 256, 65536,
                                                   NTb, 256, 65536);
  // wfold[o][h*256+e] = sum_e' fc_w[o,h*256+e'] Wv_h[e',e]
  gemm64_kernel<<<dim3(4, 4, 4), 256, 0, stream>>>(fc_wb, 1024, 256, wvTb, 256, 65536,
                                                   wfoldb, 1024, 256);
  // yt = x2tb @ NT^T (per head)
  gemm128_kernel<<<dim3(2, 64, 4), 256, 0, stream>>>(x2tb, NTb, yt);
  attn_kernel<<<1024, 256, 0, stream>>>(char_code, yt, x2tb, svb);
  fc_mfma_kernel<<<dim3(4, 16), 256, 0, stream>>>(svb, wfoldb, fc_b, fco);
  final_kernel<<<1024, 256, 0, stream>>>(char_code, x2tb, posmean, fco,
                                         sln_g, sln_b, ln1_g, ln1_b,
                                         ffln_g, ffln_b, ln2_g, ln2_b, (float*)d_out);
}

// Round 7
// 95.877 us; speedup vs baseline: 5.6315x; 1.0949x over previous
//
#include <hip/hip_runtime.h>

// Problem constants: V=128, E=256, H=4, B=1024, L=64
// Algebra: attn out folds V away: out = sv @ Wv^T, Wv folded into fc (W').
//          QK^T = Y @ x2^T with Y = X2 @ (Wq^T Wk) (NT precomputed, per head).
// attn: one block per batch b; wave w = head h; X2 staged once in LDS;
//       ALL Y fragments loaded global->reg upfront (32 outstanding loads/wave).

typedef __attribute__((ext_vector_type(8))) short bf16x8;
typedef __attribute__((ext_vector_type(4))) float f32x4;

__device__ __forceinline__ float wred_sum(float v) {
#pragma unroll
  for (int off = 32; off > 0; off >>= 1) v += __shfl_xor(v, off, 64);
  return v;
}
__device__ __forceinline__ float bf2f(unsigned short u) {
  union { unsigned int i; float f; } x; x.i = ((unsigned int)u) << 16; return x.f;
}
__device__ __forceinline__ unsigned short f2bf(float f) {
  union { float f; unsigned int i; } x; x.f = f;
  unsigned int r = x.i + 0x7FFFu + ((x.i >> 16) & 1u);
  return (unsigned short)(r >> 16);
}
__device__ __forceinline__ void gld16(const unsigned short* g, unsigned short* l) {
  __builtin_amdgcn_global_load_lds(
      (const __attribute__((address_space(1))) unsigned int*)g,
      (__attribute__((address_space(3))) unsigned int*)l, 16, 0, 0);
}

// ---------------- prep: pos | posmean | fc_w cvt | qkv_w transpose x3 (one launch) ----------------
// blocks 0..191: transpose (sel3 = bid>>6, h = (bid&63)>>4, xx = bid&15)
// blocks 192..447: fc_w f32->bf16
// blocks 448..511: pos table
// block 512: posmean (self-computes pos values)
__global__ __launch_bounds__(256) void prep_kernel(const float* qkv_w, const float* fc_w,
                                                   float* pos, float* posmean,
                                                   unsigned short* fc_wb,
                                                   unsigned short* wT) {
  __shared__ float T[64][65];
  int bid = blockIdx.x, t = threadIdx.x;
  if (bid < 192) {
    int sel3 = bid >> 6;              // 0=wq,1=wk,2=wv
    int sub = bid & 63;
    int h = sub >> 4;
    int xx = sub & 15;
    int ti = (xx & 3) * 64, te = (xx >> 2) * 64;
    int sel = sel3 * 256;
    unsigned short* wTo = wT + (size_t)sel3 * 262144 + (size_t)h * 65536;
    int r = t >> 4, c4 = (t & 15) * 4;
#pragma unroll
    for (int rep = 0; rep < 4; ++rep) {
      int il = rep * 16 + r;
      float4 v = *(const float4*)(qkv_w + (size_t)(h * 768 + sel + ti + il) * 256 + te + c4);
      T[il][c4] = v.x; T[il][c4 + 1] = v.y; T[il][c4 + 2] = v.z; T[il][c4 + 3] = v.w;
    }
    __syncthreads();
#pragma unroll
    for (int rep = 0; rep < 4; ++rep) {
      int el = rep * 16 + r;
      ushort4 o = make_ushort4(f2bf(T[c4 + 0][el]), f2bf(T[c4 + 1][el]),
                               f2bf(T[c4 + 2][el]), f2bf(T[c4 + 3][el]));
      *(ushort4*)(wTo + (size_t)(te + el) * 256 + ti + c4) = o;
    }
  } else if (bid < 448) {
    int i = ((bid - 192) * 256 + t) * 4;
    float4 v = *(const float4*)(fc_w + i);
    *(ushort4*)(fc_wb + i) = make_ushort4(f2bf(v.x), f2bf(v.y), f2bf(v.z), f2bf(v.w));
  } else if (bid < 512) {
    int idx = (bid - 448) * 256 + t;
    int l = idx >> 8, e = idx & 255;
    int i = e >> 1;
    float freq = powf(10000.0f, -(float)i * (1.0f / 128.0f));
    float ph = (float)l * freq;
    pos[idx] = (e & 1) ? cosf(ph) : sinf(ph);
  } else {
    int e = t, i = e >> 1;
    float freq = powf(10000.0f, -(float)i * (1.0f / 128.0f));
    float s = 0.f;
    for (int l = 0; l < 64; ++l) {
      float ph = (float)l * freq;
      s += (e & 1) ? cosf(ph) : sinf(ph);
    }
    posmean[e] = s * (1.0f / 64.0f);
  }
}

// ---------------- x2 table: bf16(LN0(emb[c]+pos[l]) + pos[l]), 8192 rows ----------------
__global__ __launch_bounds__(256) void x2t_kernel(const float* emb, const float* pos,
                                                  const float* g, const float* b,
                                                  unsigned short* x2tb) {
  int w = threadIdx.x >> 6, lane = threadIdx.x & 63;
  int row = blockIdx.x * 4 + w;
  int c = row >> 6, l = row & 63;
  int e0 = lane * 4;
  float4 ev = *(const float4*)(emb + c * 256 + e0);
  float4 pv = *(const float4*)(pos + l * 256 + e0);
  float v0 = ev.x + pv.x, v1 = ev.y + pv.y, v2 = ev.z + pv.z, v3 = ev.w + pv.w;
  float s = wred_sum(v0 + v1 + v2 + v3);
  float q = wred_sum(v0 * v0 + v1 * v1 + v2 * v2 + v3 * v3);
  float mean = s * (1.0f / 256.0f);
  float var = q * (1.0f / 256.0f) - mean * mean;
  float rstd = rsqrtf(var + 1e-5f);
  float4 gv = *(const float4*)(g + e0);
  float4 bv = *(const float4*)(b + e0);
  *(ushort4*)(x2tb + (size_t)row * 256 + e0) = make_ushort4(
      f2bf((v0 - mean) * rstd * gv.x + bv.x + pv.x),
      f2bf((v1 - mean) * rstd * gv.y + bv.y + pv.y),
      f2bf((v2 - mean) * rstd * gv.z + bv.z + pv.z),
      f2bf((v3 - mean) * rstd * gv.w + bv.w + pv.w));
}

// ---------------- combined 64x64-tile GEMMs, K=256, bf16 out: C = A @ B^T ----------------
// z 0..3: NT[h] = Wk_h^T-rows @ Wq_h^T-rows   (256x256 each)
// z 4..7: wfold head quadrants: fc_w cols x Wv
__global__ __launch_bounds__(256) void gemm64x2_kernel(
    const unsigned short* wkTb, const unsigned short* wqTb, unsigned short* NTb,
    const unsigned short* fc_wb, const unsigned short* wvTb, unsigned short* wfoldb) {
  __shared__ unsigned short As[64 * 64];
  __shared__ unsigned short Bs[64 * 64];
  int t = threadIdx.x, w = t >> 6, lane = t & 63;
  int li = lane & 15, hi = lane >> 4;
  int n0 = blockIdx.x * 64, m0 = blockIdx.y * 64, z = blockIdx.z;
  const unsigned short* A; const unsigned short* B; unsigned short* C;
  int lda, ldb, ldc;
  if (z < 4) {
    A = wkTb + (size_t)z * 65536; lda = 256;
    B = wqTb + (size_t)z * 65536; ldb = 256;
    C = NTb + (size_t)z * 65536; ldc = 256;
  } else {
    int zz = z - 4;
    A = fc_wb + (size_t)zz * 256; lda = 1024;
    B = wvTb + (size_t)zz * 65536; ldb = 256;
    C = wfoldb + (size_t)zz * 256; ldc = 1024;
  }
  int r_in = lane >> 3, cb = (lane & 7) * 8;
  f32x4 acc[4] = {};
  for (int kt = 0; kt < 4; ++kt) {
#pragma unroll
    for (int it = 0; it < 2; ++it) {
      int rowblk = it * 32 + w * 8;
      gld16(A + (size_t)(m0 + rowblk + r_in) * lda + kt * 64 + cb, As + rowblk * 64);
      gld16(B + (size_t)(n0 + rowblk + r_in) * ldb + kt * 64 + cb, Bs + rowblk * 64);
    }
    __syncthreads();
#pragma unroll
    for (int kk = 0; kk < 2; ++kk) {
      bf16x8 bf = *(const bf16x8*)(Bs + (w * 16 + li) * 64 + kk * 32 + hi * 8);
#pragma unroll
      for (int m = 0; m < 4; ++m) {
        bf16x8 af = *(const bf16x8*)(As + (m * 16 + li) * 64 + kk * 32 + hi * 8);
        acc[m] = __builtin_amdgcn_mfma_f32_16x16x32_bf16(af, bf, acc[m], 0, 0, 0);
      }
    }
    __syncthreads();
  }
  int col = n0 + w * 16 + li;
#pragma unroll
  for (int m = 0; m < 4; ++m)
#pragma unroll
    for (int j = 0; j < 4; ++j)
      C[(size_t)(m0 + m * 16 + hi * 4 + j) * ldc + col] = f2bf(acc[m][j]);
}

// ---------------- Y GEMM: yt[r][h*256+e2] = sum_e1 x2tb[r][e1] * NT[h][e2][e1] ----------------
__global__ __launch_bounds__(256) void gemm128_kernel(const unsigned short* A,
                                                      const unsigned short* B,
                                                      unsigned short* C) {
  __shared__ unsigned short S[2 * 128 * 64];
  unsigned short* As = S;
  unsigned short* Bs = S + 128 * 64;
  int t = threadIdx.x, w = t >> 6, lane = t & 63;
  int m0 = blockIdx.y * 128, n0 = blockIdx.x * 128, z = blockIdx.z;
  B += (size_t)z * 65536;
  int wr = w >> 1, wc = w & 1;
  f32x4 acc[4][4] = {};
  int r_in = lane >> 3, cb = (lane & 7) * 8;
  for (int kt = 0; kt < 4; ++kt) {
#pragma unroll
    for (int it = 0; it < 4; ++it) {
      int rowblk = it * 32 + w * 8;
      gld16(A + (size_t)(m0 + rowblk + r_in) * 256 + kt * 64 + cb, As + rowblk * 64);
      gld16(B + (size_t)(n0 + rowblk + r_in) * 256 + kt * 64 + cb, Bs + rowblk * 64);
    }
    __syncthreads();
#pragma unroll
    for (int kk = 0; kk < 2; ++kk) {
      bf16x8 af[4], bfr[4];
#pragma unroll
      for (int m = 0; m < 4; ++m)
        af[m] = *(const bf16x8*)(As + (wr * 64 + m * 16 + (lane & 15)) * 64 + kk * 32 + (lane >> 4) * 8);
#pragma unroll
      for (int n = 0; n < 4; ++n)
        bfr[n] = *(const bf16x8*)(Bs + (wc * 64 + n * 16 + (lane & 15)) * 64 + kk * 32 + (lane >> 4) * 8);
#pragma unroll
      for (int m = 0; m < 4; ++m)
#pragma unroll
        for (int n = 0; n < 4; ++n)
          acc[m][n] = __builtin_amdgcn_mfma_f32_16x16x32_bf16(af[m], bfr[n], acc[m][n], 0, 0, 0);
    }
    __syncthreads();
  }
  unsigned short* Cs = S;
#pragma unroll
  for (int m = 0; m < 4; ++m)
#pragma unroll
    for (int n = 0; n < 4; ++n) {
      int row = wr * 64 + m * 16 + ((lane >> 4)) * 4;
      int col = wc * 64 + n * 16 + (lane & 15);
#pragma unroll
      for (int j = 0; j < 4; ++j)
        Cs[(row + j) * 128 + col] = f2bf(acc[m][n][j]);
    }
  __syncthreads();
#pragma unroll
  for (int it = 0; it < 8; ++it) {
    int row = it * 16 + (t >> 4);
    int ce = (t & 15) * 8;
    *(bf16x8*)(C + (size_t)(m0 + row) * 1024 + z * 256 + n0 + ce) =
        *(const bf16x8*)(Cs + row * 128 + ce);
  }
}

// ---------------- attention: one block per b, wave = head; all-Y-upfront ----------------
__global__ __launch_bounds__(256, 2) void attn_kernel(const int* cc, const unsigned short* yt,
                                                      const unsigned short* x2tb,
                                                      unsigned short* svb) {
  __shared__ unsigned short X2s[4 * 4112];
  __shared__ float s_nm[64];
  __shared__ int s_cc[64];
  int b = blockIdx.x;
  int t = threadIdx.x, w = t >> 6, lane = t & 63;
  int li = lane & 15, hi = lane >> 4;

  if (t < 64) {
    int c = cc[b * 64 + t];
    s_cc[t] = c;
    s_nm[t] = (c != 0) ? 1.0f : 0.0f;
  }
  __syncthreads();

  int sr = lane >> 3;                 // row within 8-row group
  int sg = (lane & 7) ^ sr;           // inverse-swizzled source granule
  // ---- stage X2 once (32KB, 8 issues/thread) ----
#pragma unroll
  for (int ecc = 0; ecc < 4; ++ecc)
#pragma unroll
    for (int i = 0; i < 2; ++i) {
      int it = w * 2 + i, idx = it * 8 + sr;
      gld16(x2tb + (size_t)(s_cc[idx] * 64 + idx) * 256 + ecc * 64 + sg * 8,
            X2s + ecc * 4112 + it * 512);
    }

  // per-lane Y row pointers (head = wave w); A-frag lane li = q-row m*16+li
  const unsigned short* rowp[4];
#pragma unroll
  for (int m = 0; m < 4; ++m) {
    int idx = m * 16 + li;
    rowp[m] = yt + (size_t)(s_cc[idx] * 64 + idx) * 1024 + w * 256;
  }
  float nmv[4];
#pragma unroll
  for (int n = 0; n < 4; ++n) nmv[n] = s_nm[n * 16 + li];
  float nwinv = 1.0f / wred_sum(s_nm[lane]);

  // ---- load ALL Y fragments upfront: 32 outstanding 16B loads/lane ----
  bf16x8 y[4][8];
#pragma unroll
  for (int ec = 0; ec < 4; ++ec)
#pragma unroll
    for (int kk = 0; kk < 2; ++kk)
#pragma unroll
      for (int m = 0; m < 4; ++m)
        y[ec][kk * 4 + m] = *(const bf16x8*)(rowp[m] + ec * 64 + kk * 32 + hi * 8);

  __syncthreads();   // X2s staged

  // ---- QK^T: 4 chunks, no barriers ----
  f32x4 acc[4][4] = {};
#pragma unroll
  for (int ec = 0; ec < 4; ++ec)
#pragma unroll
    for (int kk = 0; kk < 2; ++kk)
#pragma unroll
      for (int n = 0; n < 4; ++n) {
        int rk = n * 16 + li;
        bf16x8 bf = *(const bf16x8*)(X2s + ec * 4112 + rk * 64 + (((kk * 4 + hi) ^ (rk & 7)) * 8));
#pragma unroll
        for (int m = 0; m < 4; ++m)
          acc[m][n] = __builtin_amdgcn_mfma_f32_16x16x32_bf16(y[ec][kk * 4 + m], bf, acc[m][n], 0, 0, 0);
      }

  // ---- wave-local masked softmax + query-averaged score ----
  // acc[m][n][j]: q = m*16 + hi*4 + j, k = n*16 + li
  float sc[4] = {0.f, 0.f, 0.f, 0.f};
#pragma unroll
  for (int m = 0; m < 4; ++m)
#pragma unroll
    for (int j = 0; j < 4; ++j) {
      float nmq = s_nm[m * 16 + hi * 4 + j];
      float v[4];
#pragma unroll
      for (int n = 0; n < 4; ++n)
        v[n] = (nmv[n] != 0.f) ? acc[m][n][j] * 0.0625f : -1e30f;
      float mx = fmaxf(fmaxf(v[0], v[1]), fmaxf(v[2], v[3]));
      mx = fmaxf(mx, __shfl_xor(mx, 1, 64));
      mx = fmaxf(mx, __shfl_xor(mx, 2, 64));
      mx = fmaxf(mx, __shfl_xor(mx, 4, 64));
      mx = fmaxf(mx, __shfl_xor(mx, 8, 64));
      float p[4];
#pragma unroll
      for (int n = 0; n < 4; ++n) p[n] = nmv[n] * __expf(v[n] - mx);
      float s = (p[0] + p[1]) + (p[2] + p[3]);
      s += __shfl_xor(s, 1, 64);
      s += __shfl_xor(s, 2, 64);
      s += __shfl_xor(s, 4, 64);
      s += __shfl_xor(s, 8, 64);
      float f = nmq / s;
#pragma unroll
      for (int n = 0; n < 4; ++n) sc[n] += p[n] * f;
    }
#pragma unroll
  for (int n = 0; n < 4; ++n) {
    sc[n] += __shfl_xor(sc[n], 16, 64);
    sc[n] += __shfl_xor(sc[n], 32, 64);
    sc[n] *= nwinv;                 // lane holds score[n*16 + li]
  }

  // ---- PV: sv[e] = sum_k score[k]*x2[k][e]; lane owns cols lane*4..+3 of its head ----
  int cg = li >> 1;
  int sub = (lane & 1) * 4;
  const unsigned short* Xc = X2s + (lane >> 4) * 4112;
  float o0 = 0.f, o1 = 0.f, o2 = 0.f, o3 = 0.f;
#pragma unroll
  for (int k = 0; k < 64; ++k) {
    float sk = __shfl(sc[k >> 4], k & 15, 64);
    ushort4 xv = *(const ushort4*)(Xc + k * 64 + ((cg ^ (k & 7)) * 8) + sub);
    o0 = fmaf(sk, bf2f(xv.x), o0);
    o1 = fmaf(sk, bf2f(xv.y), o1);
    o2 = fmaf(sk, bf2f(xv.z), o2);
    o3 = fmaf(sk, bf2f(xv.w), o3);
  }
  *(ushort4*)(svb + (size_t)b * 1024 + w * 256 + lane * 4) =
      make_ushort4(f2bf(o0), f2bf(o1), f2bf(o2), f2bf(o3));
}

// ---------------- fc GEMM: fco(1024x256) = svb(1024x1024) @ wfold(256x1024)^T + fc_b ----------------
__global__ __launch_bounds__(256) void fc_mfma_kernel(const unsigned short* aob,
                                                      const unsigned short* fc_wb,
                                                      const float* fc_b, float* fco) {
  __shared__ unsigned short As[64 * 64];
  __shared__ unsigned short Bs[64 * 64];
  int t = threadIdx.x, w = t >> 6, lane = t & 63;
  int li = lane & 15, hi = lane >> 4;
  int n0 = blockIdx.x * 64;
  int m0 = blockIdx.y * 64;
  int r_in = lane >> 3, cb = (lane & 7) * 8;
  f32x4 acc[4] = {};
  for (int kt = 0; kt < 16; ++kt) {
#pragma unroll
    for (int it = 0; it < 2; ++it) {
      int rowblk = it * 32 + w * 8;
      gld16(aob + (size_t)(m0 + rowblk + r_in) * 1024 + kt * 64 + cb, As + rowblk * 64);
      gld16(fc_wb + (size_t)(n0 + rowblk + r_in) * 1024 + kt * 64 + cb, Bs + rowblk * 64);
    }
    __syncthreads();
#pragma unroll
    for (int kk = 0; kk < 2; ++kk) {
      bf16x8 bf = *(const bf16x8*)(Bs + (w * 16 + li) * 64 + kk * 32 + hi * 8);
#pragma unroll
      for (int m = 0; m < 4; ++m) {
        bf16x8 af = *(const bf16x8*)(As + (m * 16 + li) * 64 + kk * 32 + hi * 8);
        acc[m] = __builtin_amdgcn_mfma_f32_16x16x32_bf16(af, bf, acc[m], 0, 0, 0);
      }
    }
    __syncthreads();
  }
  int col = n0 + w * 16 + li;
  float bias = fc_b[col];
#pragma unroll
  for (int m = 0; m < 4; ++m)
#pragma unroll
    for (int j = 0; j < 4; ++j)
      fco[(size_t)(m0 + m * 16 + hi * 4 + j) * 256 + col] = acc[m][j] + bias;
}

// ---------------- final: xmean gather (bf16 table) + LN chain ----------------
__device__ __forceinline__ float block_ln(float v, int t, float eps, const float* g,
                                          const float* b, float* s_part) {
  int w = t >> 6, lane = t & 63;
  __syncthreads();
  float s = wred_sum(v), q = wred_sum(v * v);
  if (lane == 0) { s_part[w] = s; s_part[4 + w] = q; }
  __syncthreads();
  float sum = s_part[0] + s_part[1] + s_part[2] + s_part[3];
  float sq = s_part[4] + s_part[5] + s_part[6] + s_part[7];
  float mean = sum * (1.0f / 256.0f);
  float var = sq * (1.0f / 256.0f) - mean * mean;
  float rstd = rsqrtf(var + eps);
  return (v - mean) * rstd * g[t] + b[t];
}

__global__ __launch_bounds__(256) void final_kernel(
    const int* cc, const unsigned short* x2tb, const float* posmean, const float* fco,
    const float* sln_g, const float* sln_b, const float* ln1_g, const float* ln1_b,
    const float* ffln_g, const float* ffln_b, const float* ln2_g, const float* ln2_b,
    float* out) {
  __shared__ int s_cc[64];
  __shared__ float s_part[8];
  int b = blockIdx.x, t = threadIdx.x;
  if (t < 64) s_cc[t] = cc[b * 64 + t];
  __syncthreads();

  float xa = 0.f;
#pragma unroll 8
  for (int l = 0; l < 64; l++) xa += bf2f(x2tb[(size_t)(s_cc[l] * 64 + l) * 256 + t]);
  float xm = xa * (1.0f / 64.0f) - posmean[t];

  float v = fco[(size_t)b * 256 + t];
  v = block_ln(v, t, 1e-5f, sln_g, sln_b, s_part);
  v = v + xm;
  v = block_ln(v, t, 1e-5f, ln1_g, ln1_b, s_part);
  float ff = block_ln(v, t, 1e-6f, ffln_g, ffln_b, s_part);
  float w2 = ff + v;
  float fin = block_ln(w2, t, 1e-5f, ln2_g, ln2_b, s_part);
  out[b * 256 + t] = fin;
}

extern "C" void kernel_launch(void* const* d_in, const int* in_sizes, int n_in,
                              void* d_out, int out_size, void* d_ws, size_t ws_size,
                              hipStream_t stream) {
  const int* char_code = (const int*)d_in[0];
  const float* emb    = (const float*)d_in[2];
  const float* qkv_w  = (const float*)d_in[3];
  const float* ln0_g  = (const float*)d_in[4];
  const float* ln0_b  = (const float*)d_in[5];
  const float* fc_w   = (const float*)d_in[6];
  const float* fc_b   = (const float*)d_in[7];
  const float* sln_g  = (const float*)d_in[8];
  const float* sln_b  = (const float*)d_in[9];
  const float* ln1_g  = (const float*)d_in[10];
  const float* ln1_b  = (const float*)d_in[11];
  const float* ffln_g = (const float*)d_in[16];
  const float* ffln_b = (const float*)d_in[17];
  const float* ln2_g  = (const float*)d_in[18];
  const float* ln2_b  = (const float*)d_in[19];

  float* ws = (float*)d_ws;
  float* pos = ws;                                          // 16384 f32
  float* posmean = pos + 16384;                             // 256 f32
  unsigned short* x2tb  = (unsigned short*)(posmean + 256); // 8192*256
  unsigned short* yt    = x2tb + (size_t)8192 * 256;        // 8192*1024
  unsigned short* wqTb  = yt + (size_t)8192 * 1024;         // 4*256*256 (wq|wk|wv contiguous)
  unsigned short* wkTb  = wqTb + 262144;
  unsigned short* wvTb  = wkTb + 262144;
  unsigned short* fc_wb = wvTb + 262144;                    // 256*1024
  unsigned short* NTb   = fc_wb + 262144;                   // 4*256*256
  unsigned short* wfoldb= NTb + 262144;                     // 256*1024
  unsigned short* svb   = wfoldb + 262144;                  // 1024*1024
  float* fco = (float*)(svb + (size_t)1024 * 1024);         // 1024*256 f32

  prep_kernel<<<513, 256, 0, stream>>>(qkv_w, fc_w, pos, posmean, fc_wb, wqTb);
  x2t_kernel<<<2048, 256, 0, stream>>>(emb, pos, ln0_g, ln0_b, x2tb);
  gemm64x2_kernel<<<dim3(4, 4, 8), 256, 0, stream>>>(wkTb, wqTb, NTb, fc_wb, wvTb, wfoldb);
  gemm128_kernel<<<dim3(2, 64, 4), 256, 0, stream>>>(x2tb, NTb, yt);
  attn_kernel<<<1024, 256, 0, stream>>>(char_code, yt, x2tb, svb);
  fc_mfma_kernel<<<dim3(4, 16), 256, 0, stream>>>(svb, wfoldb, fc_b, fco);
  final_kernel<<<1024, 256, 0, stream>>>(char_code, x2tb, posmean, fco,
                                         sln_g, sln_b, ln1_g, ln1_b,
                                         ffln_g, ffln_b, ln2_g, ln2_b, (float*)d_out);
}

// Round 8
// 77.408 us; speedup vs baseline: 6.9751x; 1.2386x over previous
//
#include <hip/hip_runtime.h>

// Problem constants: V=128, E=256, H=4, B=1024, L=64
// Algebra: attn out folds V away: out = sv @ Wv^T, Wv folded into fc (W').
//          QK^T = Y @ x2^T with Y = X2 @ (Wq^T Wk) (NT precomputed, per head).
// attn: one block per batch b; 8 waves: wave = (head, q-half); X2 staged once in LDS;
//       Y global->reg with 2-chunk-ahead register pipeline; ~110 VGPR -> 4 waves/SIMD.

typedef __attribute__((ext_vector_type(8))) short bf16x8;
typedef __attribute__((ext_vector_type(4))) float f32x4;

__device__ __forceinline__ float wred_sum(float v) {
#pragma unroll
  for (int off = 32; off > 0; off >>= 1) v += __shfl_xor(v, off, 64);
  return v;
}
__device__ __forceinline__ float bf2f(unsigned short u) {
  union { unsigned int i; float f; } x; x.i = ((unsigned int)u) << 16; return x.f;
}
__device__ __forceinline__ unsigned short f2bf(float f) {
  union { float f; unsigned int i; } x; x.f = f;
  unsigned int r = x.i + 0x7FFFu + ((x.i >> 16) & 1u);
  return (unsigned short)(r >> 16);
}
__device__ __forceinline__ void gld16(const unsigned short* g, unsigned short* l) {
  __builtin_amdgcn_global_load_lds(
      (const __attribute__((address_space(1))) unsigned int*)g,
      (__attribute__((address_space(3))) unsigned int*)l, 16, 0, 0);
}

// ---------------- prep: transposes | fc cvt | posmean | x2t (one launch) ----------------
// blocks 0..191: qkv_w transpose x3 ; 192..447: fc_w cvt ; 448: posmean ; 449..2496: x2t
__global__ __launch_bounds__(256) void prep_kernel(const float* qkv_w, const float* fc_w,
                                                   const float* emb, const float* ln0_g,
                                                   const float* ln0_b, float* posmean,
                                                   unsigned short* fc_wb, unsigned short* wT,
                                                   unsigned short* x2tb) {
  __shared__ float T[64][65];
  int bid = blockIdx.x, t = threadIdx.x;
  if (bid < 192) {
    int sel3 = bid >> 6;              // 0=wq,1=wk,2=wv
    int sub = bid & 63;
    int h = sub >> 4;
    int xx = sub & 15;
    int ti = (xx & 3) * 64, te = (xx >> 2) * 64;
    int sel = sel3 * 256;
    unsigned short* wTo = wT + (size_t)sel3 * 262144 + (size_t)h * 65536;
    int r = t >> 4, c4 = (t & 15) * 4;
#pragma unroll
    for (int rep = 0; rep < 4; ++rep) {
      int il = rep * 16 + r;
      float4 v = *(const float4*)(qkv_w + (size_t)(h * 768 + sel + ti + il) * 256 + te + c4);
      T[il][c4] = v.x; T[il][c4 + 1] = v.y; T[il][c4 + 2] = v.z; T[il][c4 + 3] = v.w;
    }
    __syncthreads();
#pragma unroll
    for (int rep = 0; rep < 4; ++rep) {
      int el = rep * 16 + r;
      ushort4 o = make_ushort4(f2bf(T[c4 + 0][el]), f2bf(T[c4 + 1][el]),
                               f2bf(T[c4 + 2][el]), f2bf(T[c4 + 3][el]));
      *(ushort4*)(wTo + (size_t)(te + el) * 256 + ti + c4) = o;
    }
  } else if (bid < 448) {
    int i = ((bid - 192) * 256 + t) * 4;
    float4 v = *(const float4*)(fc_w + i);
    *(ushort4*)(fc_wb + i) = make_ushort4(f2bf(v.x), f2bf(v.y), f2bf(v.z), f2bf(v.w));
  } else if (bid == 448) {
    int e = t, i = e >> 1;
    float freq = powf(10000.0f, -(float)i * (1.0f / 128.0f));
    float s = 0.f;
    for (int l = 0; l < 64; ++l) {
      float ph = (float)l * freq;
      s += (e & 1) ? cosf(ph) : sinf(ph);
    }
    posmean[e] = s * (1.0f / 64.0f);
  } else {
    // x2t: bf16(LN0(emb[c]+pos[l]) + pos[l]); pos computed inline
    int w = t >> 6, lane = t & 63;
    int row = (bid - 449) * 4 + w;
    int c = row >> 6, l = row & 63;
    int e0 = lane * 4;
    float i0 = (float)(e0 >> 1);
    float fr0 = powf(10000.0f, -i0 * (1.0f / 128.0f));
    float fr1 = powf(10000.0f, -(i0 + 1.0f) * (1.0f / 128.0f));
    float p0 = (float)l * fr0, p1 = (float)l * fr1;
    float4 pv = make_float4(sinf(p0), cosf(p0), sinf(p1), cosf(p1));
    float4 ev = *(const float4*)(emb + c * 256 + e0);
    float v0 = ev.x + pv.x, v1 = ev.y + pv.y, v2 = ev.z + pv.z, v3 = ev.w + pv.w;
    float s = wred_sum(v0 + v1 + v2 + v3);
    float q = wred_sum(v0 * v0 + v1 * v1 + v2 * v2 + v3 * v3);
    float mean = s * (1.0f / 256.0f);
    float var = q * (1.0f / 256.0f) - mean * mean;
    float rstd = rsqrtf(var + 1e-5f);
    float4 gv = *(const float4*)(ln0_g + e0);
    float4 bv = *(const float4*)(ln0_b + e0);
    *(ushort4*)(x2tb + (size_t)row * 256 + e0) = make_ushort4(
        f2bf((v0 - mean) * rstd * gv.x + bv.x + pv.x),
        f2bf((v1 - mean) * rstd * gv.y + bv.y + pv.y),
        f2bf((v2 - mean) * rstd * gv.z + bv.z + pv.z),
        f2bf((v3 - mean) * rstd * gv.w + bv.w + pv.w));
  }
}

// ---------------- combined 64x64-tile GEMMs, K=256, bf16 out: C = A @ B^T ----------------
__global__ __launch_bounds__(256) void gemm64x2_kernel(
    const unsigned short* wkTb, const unsigned short* wqTb, unsigned short* NTb,
    const unsigned short* fc_wb, const unsigned short* wvTb, unsigned short* wfoldb) {
  __shared__ unsigned short As[64 * 64];
  __shared__ unsigned short Bs[64 * 64];
  int t = threadIdx.x, w = t >> 6, lane = t & 63;
  int li = lane & 15, hi = lane >> 4;
  int n0 = blockIdx.x * 64, m0 = blockIdx.y * 64, z = blockIdx.z;
  const unsigned short* A; const unsigned short* B; unsigned short* C;
  int lda, ldb, ldc;
  if (z < 4) {
    A = wkTb + (size_t)z * 65536; lda = 256;
    B = wqTb + (size_t)z * 65536; ldb = 256;
    C = NTb + (size_t)z * 65536; ldc = 256;
  } else {
    int zz = z - 4;
    A = fc_wb + (size_t)zz * 256; lda = 1024;
    B = wvTb + (size_t)zz * 65536; ldb = 256;
    C = wfoldb + (size_t)zz * 256; ldc = 1024;
  }
  int r_in = lane >> 3, cb = (lane & 7) * 8;
  f32x4 acc[4] = {};
  for (int kt = 0; kt < 4; ++kt) {
#pragma unroll
    for (int it = 0; it < 2; ++it) {
      int rowblk = it * 32 + w * 8;
      gld16(A + (size_t)(m0 + rowblk + r_in) * lda + kt * 64 + cb, As + rowblk * 64);
      gld16(B + (size_t)(n0 + rowblk + r_in) * ldb + kt * 64 + cb, Bs + rowblk * 64);
    }
    __syncthreads();
#pragma unroll
    for (int kk = 0; kk < 2; ++kk) {
      bf16x8 bf = *(const bf16x8*)(Bs + (w * 16 + li) * 64 + kk * 32 + hi * 8);
#pragma unroll
      for (int m = 0; m < 4; ++m) {
        bf16x8 af = *(const bf16x8*)(As + (m * 16 + li) * 64 + kk * 32 + hi * 8);
        acc[m] = __builtin_amdgcn_mfma_f32_16x16x32_bf16(af, bf, acc[m], 0, 0, 0);
      }
    }
    __syncthreads();
  }
  int col = n0 + w * 16 + li;
#pragma unroll
  for (int m = 0; m < 4; ++m)
#pragma unroll
    for (int j = 0; j < 4; ++j)
      C[(size_t)(m0 + m * 16 + hi * 4 + j) * ldc + col] = f2bf(acc[m][j]);
}

// ---------------- Y GEMM: yt[r][h*256+e2] = sum_e1 x2tb[r][e1] * NT[h][e2][e1] ----------------
__global__ __launch_bounds__(256) void gemm128_kernel(const unsigned short* A,
                                                      const unsigned short* B,
                                                      unsigned short* C) {
  __shared__ unsigned short S[2 * 128 * 64];
  unsigned short* As = S;
  unsigned short* Bs = S + 128 * 64;
  int t = threadIdx.x, w = t >> 6, lane = t & 63;
  int m0 = blockIdx.y * 128, n0 = blockIdx.x * 128, z = blockIdx.z;
  B += (size_t)z * 65536;
  int wr = w >> 1, wc = w & 1;
  f32x4 acc[4][4] = {};
  int r_in = lane >> 3, cb = (lane & 7) * 8;
  for (int kt = 0; kt < 4; ++kt) {
#pragma unroll
    for (int it = 0; it < 4; ++it) {
      int rowblk = it * 32 + w * 8;
      gld16(A + (size_t)(m0 + rowblk + r_in) * 256 + kt * 64 + cb, As + rowblk * 64);
      gld16(B + (size_t)(n0 + rowblk + r_in) * 256 + kt * 64 + cb, Bs + rowblk * 64);
    }
    __syncthreads();
#pragma unroll
    for (int kk = 0; kk < 2; ++kk) {
      bf16x8 af[4], bfr[4];
#pragma unroll
      for (int m = 0; m < 4; ++m)
        af[m] = *(const bf16x8*)(As + (wr * 64 + m * 16 + (lane & 15)) * 64 + kk * 32 + (lane >> 4) * 8);
#pragma unroll
      for (int n = 0; n < 4; ++n)
        bfr[n] = *(const bf16x8*)(Bs + (wc * 64 + n * 16 + (lane & 15)) * 64 + kk * 32 + (lane >> 4) * 8);
#pragma unroll
      for (int m = 0; m < 4; ++m)
#pragma unroll
        for (int n = 0; n < 4; ++n)
          acc[m][n] = __builtin_amdgcn_mfma_f32_16x16x32_bf16(af[m], bfr[n], acc[m][n], 0, 0, 0);
    }
    __syncthreads();
  }
  unsigned short* Cs = S;
#pragma unroll
  for (int m = 0; m < 4; ++m)
#pragma unroll
    for (int n = 0; n < 4; ++n) {
      int row = wr * 64 + m * 16 + ((lane >> 4)) * 4;
      int col = wc * 64 + n * 16 + (lane & 15);
#pragma unroll
      for (int j = 0; j < 4; ++j)
        Cs[(row + j) * 128 + col] = f2bf(acc[m][n][j]);
    }
  __syncthreads();
#pragma unroll
  for (int it = 0; it < 8; ++it) {
    int row = it * 16 + (t >> 4);
    int ce = (t & 15) * 8;
    *(bf16x8*)(C + (size_t)(m0 + row) * 1024 + z * 256 + n0 + ce) =
        *(const bf16x8*)(Cs + row * 128 + ce);
  }
}

// ---------------- attention: block = b (512 thr, 8 waves); wave = (head, q-half) ----------------
__global__ __launch_bounds__(512, 4) void attn_kernel(const int* cc, const unsigned short* yt,
                                                      const unsigned short* x2tb,
                                                      unsigned short* svb) {
  __shared__ unsigned short X2s[4 * 4112];
  __shared__ float s_sp[8][64];
  __shared__ float s_score[4][64];
  __shared__ float s_nm[64];
  __shared__ int s_cc[64];
  __shared__ float s_nwinv;
  int b = blockIdx.x;
  int t = threadIdx.x, w = t >> 6, lane = t & 63;
  int li = lane & 15, hi = lane >> 4;
  int h = w >> 1, mh = w & 1;

  if (t < 64) {
    int c = cc[b * 64 + t];
    s_cc[t] = c;
    s_nm[t] = (c != 0) ? 1.0f : 0.0f;
  }
  __syncthreads();
  if (t < 64) {
    float s = wred_sum(s_nm[t]);
    if (t == 0) s_nwinv = 1.0f / s;
  }

  // ---- stage X2 once: wave w stages rows w*8..w*8+7 of each 64-col chunk ----
  int sr = lane >> 3;                 // row within 8-row group
  int sg = (lane & 7) ^ sr;           // inverse-swizzled source granule
  {
    int idx = w * 8 + sr;
    size_t rbase = (size_t)(s_cc[idx] * 64 + idx) * 256;
#pragma unroll
    for (int ecc = 0; ecc < 4; ++ecc)
      gld16(x2tb + rbase + ecc * 64 + sg * 8, X2s + ecc * 4112 + w * 512);
  }

  // per-lane Y row pointers for this wave's q-rows (head h, half mh)
  const unsigned short* rowp[2];
#pragma unroll
  for (int m = 0; m < 2; ++m) {
    int idx = mh * 32 + m * 16 + li;
    rowp[m] = yt + (size_t)(s_cc[idx] * 64 + idx) * 1024 + h * 256;
  }
  float nmv[4];
#pragma unroll
  for (int n = 0; n < 4; ++n) nmv[n] = s_nm[n * 16 + li];

  // preload Y chunks 0,1 (16B/lane each frag)
  bf16x8 ybuf[4][4];
#pragma unroll
  for (int ec = 0; ec < 2; ++ec)
#pragma unroll
    for (int kk = 0; kk < 2; ++kk)
#pragma unroll
      for (int m = 0; m < 2; ++m)
        ybuf[ec][kk * 2 + m] = *(const bf16x8*)(rowp[m] + ec * 64 + kk * 32 + hi * 8);

  __syncthreads();   // X2s staged

  // ---- QK^T: 4 chunks; 2-chunk-ahead register prefetch, no barriers ----
  f32x4 acc[2][4] = {};
#pragma unroll
  for (int ec = 0; ec < 4; ++ec) {
    if (ec < 2) {
#pragma unroll
      for (int kk = 0; kk < 2; ++kk)
#pragma unroll
        for (int m = 0; m < 2; ++m)
          ybuf[ec + 2][kk * 2 + m] = *(const bf16x8*)(rowp[m] + (ec + 2) * 64 + kk * 32 + hi * 8);
    }
    __builtin_amdgcn_sched_barrier(0);
#pragma unroll
    for (int kk = 0; kk < 2; ++kk)
#pragma unroll
      for (int n = 0; n < 4; ++n) {
        int rk = n * 16 + li;
        bf16x8 bf = *(const bf16x8*)(X2s + ec * 4112 + rk * 64 + (((kk * 4 + hi) ^ (rk & 7)) * 8));
#pragma unroll
        for (int m = 0; m < 2; ++m)
          acc[m][n] = __builtin_amdgcn_mfma_f32_16x16x32_bf16(ybuf[ec][kk * 2 + m], bf, acc[m][n], 0, 0, 0);
      }
  }

  // ---- per-wave masked softmax over its 32 q-rows + partial score ----
  // acc[m][n][j]: q = mh*32 + m*16 + hi*4 + j, k = n*16 + li
  float sc[4] = {0.f, 0.f, 0.f, 0.f};
#pragma unroll
  for (int m = 0; m < 2; ++m)
#pragma unroll
    for (int j = 0; j < 4; ++j) {
      float nmq = s_nm[mh * 32 + m * 16 + hi * 4 + j];
      float v[4];
#pragma unroll
      for (int n = 0; n < 4; ++n)
        v[n] = (nmv[n] != 0.f) ? acc[m][n][j] * 0.0625f : -1e30f;
      float mx = fmaxf(fmaxf(v[0], v[1]), fmaxf(v[2], v[3]));
      mx = fmaxf(mx, __shfl_xor(mx, 1, 64));
      mx = fmaxf(mx, __shfl_xor(mx, 2, 64));
      mx = fmaxf(mx, __shfl_xor(mx, 4, 64));
      mx = fmaxf(mx, __shfl_xor(mx, 8, 64));
      float p[4];
#pragma unroll
      for (int n = 0; n < 4; ++n) p[n] = nmv[n] * __expf(v[n] - mx);
      float s = (p[0] + p[1]) + (p[2] + p[3]);
      s += __shfl_xor(s, 1, 64);
      s += __shfl_xor(s, 2, 64);
      s += __shfl_xor(s, 4, 64);
      s += __shfl_xor(s, 8, 64);
      float f = nmq / s;
#pragma unroll
      for (int n = 0; n < 4; ++n) sc[n] += p[n] * f;
    }
#pragma unroll
  for (int n = 0; n < 4; ++n) {
    sc[n] += __shfl_xor(sc[n], 16, 64);
    sc[n] += __shfl_xor(sc[n], 32, 64);
  }
  if (hi == 0) {
#pragma unroll
    for (int n = 0; n < 4; ++n) s_sp[w][n * 16 + li] = sc[n];
  }
  __syncthreads();
  if (t < 256) {
    int hh = t >> 6, k = t & 63;
    s_score[hh][k] = (s_sp[hh * 2][k] + s_sp[hh * 2 + 1][k]) * s_nwinv;
  }
  __syncthreads();

  // ---- PV: wave w covers cols mh*128 + lane*2 (+1) of head h ----
  int c0 = mh * 128 + lane * 2;
  int chunk = c0 >> 6;
  int cin = c0 & 63;
  int cg = cin >> 3, ce = cin & 7;
  const unsigned short* Xc = X2s + chunk * 4112;
  const float* sco = s_score[h];
  float o0 = 0.f, o1 = 0.f;
#pragma unroll
  for (int k = 0; k < 64; ++k) {
    float sk = sco[k];
    const unsigned short* p = Xc + k * 64 + ((cg ^ (k & 7)) * 8) + ce;
    o0 = fmaf(sk, bf2f(p[0]), o0);
    o1 = fmaf(sk, bf2f(p[1]), o1);
  }
  ushort2 ov; ov.x = f2bf(o0); ov.y = f2bf(o1);
  *(ushort2*)(svb + (size_t)b * 1024 + h * 256 + c0) = ov;
}

// ---------------- fc GEMM (K-split x4): fco_part[z] = svb @ wfold^T over K-quarter z ----------------
__global__ __launch_bounds__(256) void fc_mfma_kernel(const unsigned short* aob,
                                                      const unsigned short* fc_wb,
                                                      float* fco) {
  __shared__ unsigned short As[64 * 64];
  __shared__ unsigned short Bs[64 * 64];
  int t = threadIdx.x, w = t >> 6, lane = t & 63;
  int li = lane & 15, hi = lane >> 4;
  int n0 = blockIdx.x * 64;
  int m0 = blockIdx.y * 64;
  int z = blockIdx.z;
  int r_in = lane >> 3, cb = (lane & 7) * 8;
  f32x4 acc[4] = {};
  for (int kt = z * 4; kt < z * 4 + 4; ++kt) {
#pragma unroll
    for (int it = 0; it < 2; ++it) {
      int rowblk = it * 32 + w * 8;
      gld16(aob + (size_t)(m0 + rowblk + r_in) * 1024 + kt * 64 + cb, As + rowblk * 64);
      gld16(fc_wb + (size_t)(n0 + rowblk + r_in) * 1024 + kt * 64 + cb, Bs + rowblk * 64);
    }
    __syncthreads();
#pragma unroll
    for (int kk = 0; kk < 2; ++kk) {
      bf16x8 bf = *(const bf16x8*)(Bs + (w * 16 + li) * 64 + kk * 32 + hi * 8);
#pragma unroll
      for (int m = 0; m < 4; ++m) {
        bf16x8 af = *(const bf16x8*)(As + (m * 16 + li) * 64 + kk * 32 + hi * 8);
        acc[m] = __builtin_amdgcn_mfma_f32_16x16x32_bf16(af, bf, acc[m], 0, 0, 0);
      }
    }
    __syncthreads();
  }
  int col = n0 + w * 16 + li;
  float* out = fco + (size_t)z * 262144;
#pragma unroll
  for (int m = 0; m < 4; ++m)
#pragma unroll
    for (int j = 0; j < 4; ++j)
      out[(size_t)(m0 + m * 16 + hi * 4 + j) * 256 + col] = acc[m][j];
}

// ---------------- final: sum fc partials + bias + xmean gather + LN chain ----------------
__device__ __forceinline__ float block_ln(float v, int t, float eps, const float* g,
                                          const float* b, float* s_part) {
  int w = t >> 6, lane = t & 63;
  __syncthreads();
  float s = wred_sum(v), q = wred_sum(v * v);
  if (lane == 0) { s_part[w] = s; s_part[4 + w] = q; }
  __syncthreads();
  float sum = s_part[0] + s_part[1] + s_part[2] + s_part[3];
  float sq = s_part[4] + s_part[5] + s_part[6] + s_part[7];
  float mean = sum * (1.0f / 256.0f);
  float var = sq * (1.0f / 256.0f) - mean * mean;
  float rstd = rsqrtf(var + eps);
  return (v - mean) * rstd * g[t] + b[t];
}

__global__ __launch_bounds__(256) void final_kernel(
    const int* cc, const unsigned short* x2tb, const float* posmean, const float* fco,
    const float* fc_b,
    const float* sln_g, const float* sln_b, const float* ln1_g, const float* ln1_b,
    const float* ffln_g, const float* ffln_b, const float* ln2_g, const float* ln2_b,
    float* out) {
  __shared__ int s_cc[64];
  __shared__ float s_part[8];
  int b = blockIdx.x, t = threadIdx.x;
  if (t < 64) s_cc[t] = cc[b * 64 + t];
  __syncthreads();

  float xa = 0.f;
#pragma unroll 8
  for (int l = 0; l < 64; l++) xa += bf2f(x2tb[(size_t)(s_cc[l] * 64 + l) * 256 + t]);
  float xm = xa * (1.0f / 64.0f) - posmean[t];

  size_t o = (size_t)b * 256 + t;
  float v = fco[o] + fco[262144 + o] + fco[2 * 262144 + o] + fco[3 * 262144 + o] + fc_b[t];
  v = block_ln(v, t, 1e-5f, sln_g, sln_b, s_part);
  v = v + xm;
  v = block_ln(v, t, 1e-5f, ln1_g, ln1_b, s_part);
  float ff = block_ln(v, t, 1e-6f, ffln_g, ffln_b, s_part);
  float w2 = ff + v;
  float fin = block_ln(w2, t, 1e-5f, ln2_g, ln2_b, s_part);
  out[b * 256 + t] = fin;
}

extern "C" void kernel_launch(void* const* d_in, const int* in_sizes, int n_in,
                              void* d_out, int out_size, void* d_ws, size_t ws_size,
                              hipStream_t stream) {
  const int* char_code = (const int*)d_in[0];
  const float* emb    = (const float*)d_in[2];
  const float* qkv_w  = (const float*)d_in[3];
  const float* ln0_g  = (const float*)d_in[4];
  const float* ln0_b  = (const float*)d_in[5];
  const float* fc_w   = (const float*)d_in[6];
  const float* fc_b   = (const float*)d_in[7];
  const float* sln_g  = (const float*)d_in[8];
  const float* sln_b  = (const float*)d_in[9];
  const float* ln1_g  = (const float*)d_in[10];
  const float* ln1_b  = (const float*)d_in[11];
  const float* ffln_g = (const float*)d_in[16];
  const float* ffln_b = (const float*)d_in[17];
  const float* ln2_g  = (const float*)d_in[18];
  const float* ln2_b  = (const float*)d_in[19];

  float* ws = (float*)d_ws;
  float* posmean = ws;                                      // 256 f32
  unsigned short* x2tb  = (unsigned short*)(posmean + 256); // 8192*256
  unsigned short* yt    = x2tb + (size_t)8192 * 256;        // 8192*1024
  unsigned short* wqTb  = yt + (size_t)8192 * 1024;         // 4*256*256 (wq|wk|wv contiguous)
  unsigned short* wkTb  = wqTb + 262144;
  unsigned short* wvTb  = wkTb + 262144;
  unsigned short* fc_wb = wvTb + 262144;                    // 256*1024
  unsigned short* NTb   = fc_wb + 262144;                   // 4*256*256
  unsigned short* wfoldb= NTb + 262144;                     // 256*1024
  unsigned short* svb   = wfoldb + 262144;                  // 1024*1024
  float* fco = (float*)(svb + (size_t)1024 * 1024);         // 4 * 1024*256 f32

  prep_kernel<<<2497, 256, 0, stream>>>(qkv_w, fc_w, emb, ln0_g, ln0_b, posmean,
                                        fc_wb, wqTb, x2tb);
  gemm64x2_kernel<<<dim3(4, 4, 8), 256, 0, stream>>>(wkTb, wqTb, NTb, fc_wb, wvTb, wfoldb);
  gemm128_kernel<<<dim3(2, 64, 4), 256, 0, stream>>>(x2tb, NTb, yt);
  attn_kernel<<<1024, 512, 0, stream>>>(char_code, yt, x2tb, svb);
  fc_mfma_kernel<<<dim3(4, 16, 4), 256, 0, stream>>>(svb, wfoldb, fco);
  final_kernel<<<1024, 256, 0, stream>>>(char_code, x2tb, posmean, fco, fc_b,
                                         sln_g, sln_b, ln1_g, ln1_b,
                                         ffln_g, ffln_b, ln2_g, ln2_b, (float*)d_out);
}

// Round 9
// 66.800 us; speedup vs baseline: 8.0829x; 1.1588x over previous
//
#include <hip/hip_runtime.h>

// Problem constants: V=128, E=256, H=4, B=1024, L=64
// Algebra: attn out folds V away: out = sv @ Wv^T, Wv folded into fc (W').
//          QK^T = Y @ x2^T with Y = X2 @ (Wq^T Wk) (NT precomputed, per head).
// attn: block = batch b (8 waves, wave = (head, q-half)); X2 staged once in LDS;
//       Y global->reg 2-chunk-ahead pipeline; xmean fused (X2 already in LDS).

typedef __attribute__((ext_vector_type(8))) short bf16x8;
typedef __attribute__((ext_vector_type(4))) float f32x4;

__device__ __forceinline__ float wred_sum(float v) {
#pragma unroll
  for (int off = 32; off > 0; off >>= 1) v += __shfl_xor(v, off, 64);
  return v;
}
__device__ __forceinline__ float bf2f(unsigned short u) {
  union { unsigned int i; float f; } x; x.i = ((unsigned int)u) << 16; return x.f;
}
__device__ __forceinline__ unsigned short f2bf(float f) {
  union { float f; unsigned int i; } x; x.f = f;
  unsigned int r = x.i + 0x7FFFu + ((x.i >> 16) & 1u);
  return (unsigned short)(r >> 16);
}
__device__ __forceinline__ void gld16(const unsigned short* g, unsigned short* l) {
  __builtin_amdgcn_global_load_lds(
      (const __attribute__((address_space(1))) unsigned int*)g,
      (__attribute__((address_space(3))) unsigned int*)l, 16, 0, 0);
}
// fast freq = 10000^(-i/128) = exp2(-i * log2(1e4)/128)
__device__ __forceinline__ float fast_freq(float i) {
  return exp2f(i * (-13.287712379549449f / 128.0f));
}

// ---------------- prep: transposes | fc cvt | posmean | x2t (one launch) ----------------
// blocks 0..191: qkv_w transpose x3 ; 192..447: fc_w cvt ; 448: posmean ; 449..2496: x2t
__global__ __launch_bounds__(256) void prep_kernel(const float* qkv_w, const float* fc_w,
                                                   const float* emb, const float* ln0_g,
                                                   const float* ln0_b, float* posmean,
                                                   unsigned short* fc_wb, unsigned short* wT,
                                                   unsigned short* x2tb) {
  __shared__ float T[64][65];
  int bid = blockIdx.x, t = threadIdx.x;
  if (bid < 192) {
    int sel3 = bid >> 6;              // 0=wq,1=wk,2=wv
    int sub = bid & 63;
    int h = sub >> 4;
    int xx = sub & 15;
    int ti = (xx & 3) * 64, te = (xx >> 2) * 64;
    int sel = sel3 * 256;
    unsigned short* wTo = wT + (size_t)sel3 * 262144 + (size_t)h * 65536;
    int r = t >> 4, c4 = (t & 15) * 4;
#pragma unroll
    for (int rep = 0; rep < 4; ++rep) {
      int il = rep * 16 + r;
      float4 v = *(const float4*)(qkv_w + (size_t)(h * 768 + sel + ti + il) * 256 + te + c4);
      T[il][c4] = v.x; T[il][c4 + 1] = v.y; T[il][c4 + 2] = v.z; T[il][c4 + 3] = v.w;
    }
    __syncthreads();
#pragma unroll
    for (int rep = 0; rep < 4; ++rep) {
      int el = rep * 16 + r;
      ushort4 o = make_ushort4(f2bf(T[c4 + 0][el]), f2bf(T[c4 + 1][el]),
                               f2bf(T[c4 + 2][el]), f2bf(T[c4 + 3][el]));
      *(ushort4*)(wTo + (size_t)(te + el) * 256 + ti + c4) = o;
    }
  } else if (bid < 448) {
    int i = ((bid - 192) * 256 + t) * 4;
    float4 v = *(const float4*)(fc_w + i);
    *(ushort4*)(fc_wb + i) = make_ushort4(f2bf(v.x), f2bf(v.y), f2bf(v.z), f2bf(v.w));
  } else if (bid == 448) {
    int e = t;
    float freq = fast_freq((float)(e >> 1));
    float s = 0.f;
    for (int l = 0; l < 64; ++l) {
      float ph = (float)l * freq;
      s += (e & 1) ? __cosf(ph) : __sinf(ph);
    }
    posmean[e] = s * (1.0f / 64.0f);
  } else {
    // x2t: bf16(LN0(emb[c]+pos[l]) + pos[l]); pos computed inline (fast trig)
    int w = t >> 6, lane = t & 63;
    int row = (bid - 449) * 4 + w;
    int c = row >> 6, l = row & 63;
    int e0 = lane * 4;
    float fr0 = fast_freq((float)(e0 >> 1));
    float fr1 = fast_freq((float)(e0 >> 1) + 1.0f);
    float p0 = (float)l * fr0, p1 = (float)l * fr1;
    float4 pv = make_float4(__sinf(p0), __cosf(p0), __sinf(p1), __cosf(p1));
    float4 ev = *(const float4*)(emb + c * 256 + e0);
    float v0 = ev.x + pv.x, v1 = ev.y + pv.y, v2 = ev.z + pv.z, v3 = ev.w + pv.w;
    float s = wred_sum(v0 + v1 + v2 + v3);
    float q = wred_sum(v0 * v0 + v1 * v1 + v2 * v2 + v3 * v3);
    float mean = s * (1.0f / 256.0f);
    float var = q * (1.0f / 256.0f) - mean * mean;
    float rstd = rsqrtf(var + 1e-5f);
    float4 gv = *(const float4*)(ln0_g + e0);
    float4 bv = *(const float4*)(ln0_b + e0);
    *(ushort4*)(x2tb + (size_t)row * 256 + e0) = make_ushort4(
        f2bf((v0 - mean) * rstd * gv.x + bv.x + pv.x),
        f2bf((v1 - mean) * rstd * gv.y + bv.y + pv.y),
        f2bf((v2 - mean) * rstd * gv.z + bv.z + pv.z),
        f2bf((v3 - mean) * rstd * gv.w + bv.w + pv.w));
  }
}

// ---------------- combined 64x64-tile GEMMs, K=256, bf16 out: C = A @ B^T ----------------
__global__ __launch_bounds__(256) void gemm64x2_kernel(
    const unsigned short* wkTb, const unsigned short* wqTb, unsigned short* NTb,
    const unsigned short* fc_wb, const unsigned short* wvTb, unsigned short* wfoldb) {
  __shared__ unsigned short As[64 * 64];
  __shared__ unsigned short Bs[64 * 64];
  int t = threadIdx.x, w = t >> 6, lane = t & 63;
  int li = lane & 15, hi = lane >> 4;
  int n0 = blockIdx.x * 64, m0 = blockIdx.y * 64, z = blockIdx.z;
  const unsigned short* A; const unsigned short* B; unsigned short* C;
  int lda, ldb, ldc;
  if (z < 4) {
    A = wkTb + (size_t)z * 65536; lda = 256;
    B = wqTb + (size_t)z * 65536; ldb = 256;
    C = NTb + (size_t)z * 65536; ldc = 256;
  } else {
    int zz = z - 4;
    A = fc_wb + (size_t)zz * 256; lda = 1024;
    B = wvTb + (size_t)zz * 65536; ldb = 256;
    C = wfoldb + (size_t)zz * 256; ldc = 1024;
  }
  int r_in = lane >> 3, cb = (lane & 7) * 8;
  f32x4 acc[4] = {};
  for (int kt = 0; kt < 4; ++kt) {
#pragma unroll
    for (int it = 0; it < 2; ++it) {
      int rowblk = it * 32 + w * 8;
      gld16(A + (size_t)(m0 + rowblk + r_in) * lda + kt * 64 + cb, As + rowblk * 64);
      gld16(B + (size_t)(n0 + rowblk + r_in) * ldb + kt * 64 + cb, Bs + rowblk * 64);
    }
    __syncthreads();
#pragma unroll
    for (int kk = 0; kk < 2; ++kk) {
      bf16x8 bf = *(const bf16x8*)(Bs + (w * 16 + li) * 64 + kk * 32 + hi * 8);
#pragma unroll
      for (int m = 0; m < 4; ++m) {
        bf16x8 af = *(const bf16x8*)(As + (m * 16 + li) * 64 + kk * 32 + hi * 8);
        acc[m] = __builtin_amdgcn_mfma_f32_16x16x32_bf16(af, bf, acc[m], 0, 0, 0);
      }
    }
    __syncthreads();
  }
  int col = n0 + w * 16 + li;
#pragma unroll
  for (int m = 0; m < 4; ++m)
#pragma unroll
    for (int j = 0; j < 4; ++j)
      C[(size_t)(m0 + m * 16 + hi * 4 + j) * ldc + col] = f2bf(acc[m][j]);
}

// ---------------- Y GEMM: yt[r][h*256+e2] = sum_e1 x2tb[r][e1] * NT[h][e2][e1] ----------------
__global__ __launch_bounds__(256) void gemm128_kernel(const unsigned short* A,
                                                      const unsigned short* B,
                                                      unsigned short* C) {
  __shared__ unsigned short S[2 * 128 * 64];
  unsigned short* As = S;
  unsigned short* Bs = S + 128 * 64;
  int t = threadIdx.x, w = t >> 6, lane = t & 63;
  int m0 = blockIdx.y * 128, n0 = blockIdx.x * 128, z = blockIdx.z;
  B += (size_t)z * 65536;
  int wr = w >> 1, wc = w & 1;
  f32x4 acc[4][4] = {};
  int r_in = lane >> 3, cb = (lane & 7) * 8;
  for (int kt = 0; kt < 4; ++kt) {
#pragma unroll
    for (int it = 0; it < 4; ++it) {
      int rowblk = it * 32 + w * 8;
      gld16(A + (size_t)(m0 + rowblk + r_in) * 256 + kt * 64 + cb, As + rowblk * 64);
      gld16(B + (size_t)(n0 + rowblk + r_in) * 256 + kt * 64 + cb, Bs + rowblk * 64);
    }
    __syncthreads();
#pragma unroll
    for (int kk = 0; kk < 2; ++kk) {
      bf16x8 af[4], bfr[4];
#pragma unroll
      for (int m = 0; m < 4; ++m)
        af[m] = *(const bf16x8*)(As + (wr * 64 + m * 16 + (lane & 15)) * 64 + kk * 32 + (lane >> 4) * 8);
#pragma unroll
      for (int n = 0; n < 4; ++n)
        bfr[n] = *(const bf16x8*)(Bs + (wc * 64 + n * 16 + (lane & 15)) * 64 + kk * 32 + (lane >> 4) * 8);
#pragma unroll
      for (int m = 0; m < 4; ++m)
#pragma unroll
        for (int n = 0; n < 4; ++n)
          acc[m][n] = __builtin_amdgcn_mfma_f32_16x16x32_bf16(af[m], bfr[n], acc[m][n], 0, 0, 0);
    }
    __syncthreads();
  }
  unsigned short* Cs = S;
#pragma unroll
  for (int m = 0; m < 4; ++m)
#pragma unroll
    for (int n = 0; n < 4; ++n) {
      int row = wr * 64 + m * 16 + ((lane >> 4)) * 4;
      int col = wc * 64 + n * 16 + (lane & 15);
#pragma unroll
      for (int j = 0; j < 4; ++j)
        Cs[(row + j) * 128 + col] = f2bf(acc[m][n][j]);
    }
  __syncthreads();
#pragma unroll
  for (int it = 0; it < 8; ++it) {
    int row = it * 16 + (t >> 4);
    int ce = (t & 15) * 8;
    *(bf16x8*)(C + (size_t)(m0 + row) * 1024 + z * 256 + n0 + ce) =
        *(const bf16x8*)(Cs + row * 128 + ce);
  }
}

// ---------------- attention: block = b (512 thr, 8 waves); wave = (head, q-half) ----------------
// Also emits xm[b][e] = mean_l x2[row_l][e] - posmean[e] (X2 already in LDS).
__global__ __launch_bounds__(512, 4) void attn_kernel(const int* cc, const unsigned short* yt,
                                                      const unsigned short* x2tb,
                                                      const float* posmean,
                                                      unsigned short* svb, float* xmb) {
  __shared__ unsigned short X2s[4 * 4112];
  __shared__ float s_sp[8][64];
  __shared__ float s_score[4][64];
  __shared__ float s_nm[64];
  __shared__ int s_cc[64];
  __shared__ float s_nwinv;
  int b = blockIdx.x;
  int t = threadIdx.x, w = t >> 6, lane = t & 63;
  int li = lane & 15, hi = lane >> 4;
  int h = w >> 1, mh = w & 1;

  if (t < 64) {
    int c = cc[b * 64 + t];
    s_cc[t] = c;
    s_nm[t] = (c != 0) ? 1.0f : 0.0f;
  }
  __syncthreads();
  if (t < 64) {
    float s = wred_sum(s_nm[t]);
    if (t == 0) s_nwinv = 1.0f / s;
  }

  // ---- stage X2 once: wave w stages rows w*8..w*8+7 of each 64-col chunk ----
  int sr = lane >> 3;                 // row within 8-row group
  int sg = (lane & 7) ^ sr;           // inverse-swizzled source granule
  {
    int idx = w * 8 + sr;
    size_t rbase = (size_t)(s_cc[idx] * 64 + idx) * 256;
#pragma unroll
    for (int ecc = 0; ecc < 4; ++ecc)
      gld16(x2tb + rbase + ecc * 64 + sg * 8, X2s + ecc * 4112 + w * 512);
  }

  // per-lane Y row pointers for this wave's q-rows (head h, half mh)
  const unsigned short* rowp[2];
#pragma unroll
  for (int m = 0; m < 2; ++m) {
    int idx = mh * 32 + m * 16 + li;
    rowp[m] = yt + (size_t)(s_cc[idx] * 64 + idx) * 1024 + h * 256;
  }
  float nmv[4];
#pragma unroll
  for (int n = 0; n < 4; ++n) nmv[n] = s_nm[n * 16 + li];

  // preload Y chunks 0,1
  bf16x8 ybuf[4][4];
#pragma unroll
  for (int ec = 0; ec < 2; ++ec)
#pragma unroll
    for (int kk = 0; kk < 2; ++kk)
#pragma unroll
      for (int m = 0; m < 2; ++m)
        ybuf[ec][kk * 2 + m] = *(const bf16x8*)(rowp[m] + ec * 64 + kk * 32 + hi * 8);

  __syncthreads();   // X2s staged

  // ---- QK^T: 4 chunks; 2-chunk-ahead register prefetch, no barriers ----
  f32x4 acc[2][4] = {};
#pragma unroll
  for (int ec = 0; ec < 4; ++ec) {
    if (ec < 2) {
#pragma unroll
      for (int kk = 0; kk < 2; ++kk)
#pragma unroll
        for (int m = 0; m < 2; ++m)
          ybuf[ec + 2][kk * 2 + m] = *(const bf16x8*)(rowp[m] + (ec + 2) * 64 + kk * 32 + hi * 8);
    }
    __builtin_amdgcn_sched_barrier(0);
#pragma unroll
    for (int kk = 0; kk < 2; ++kk)
#pragma unroll
      for (int n = 0; n < 4; ++n) {
        int rk = n * 16 + li;
        bf16x8 bf = *(const bf16x8*)(X2s + ec * 4112 + rk * 64 + (((kk * 4 + hi) ^ (rk & 7)) * 8));
#pragma unroll
        for (int m = 0; m < 2; ++m)
          acc[m][n] = __builtin_amdgcn_mfma_f32_16x16x32_bf16(ybuf[ec][kk * 2 + m], bf, acc[m][n], 0, 0, 0);
      }
  }

  // ---- per-wave masked softmax over its 32 q-rows + partial score ----
  float sc[4] = {0.f, 0.f, 0.f, 0.f};
#pragma unroll
  for (int m = 0; m < 2; ++m)
#pragma unroll
    for (int j = 0; j < 4; ++j) {
      float nmq = s_nm[mh * 32 + m * 16 + hi * 4 + j];
      float v[4];
#pragma unroll
      for (int n = 0; n < 4; ++n)
        v[n] = (nmv[n] != 0.f) ? acc[m][n][j] * 0.0625f : -1e30f;
      float mx = fmaxf(fmaxf(v[0], v[1]), fmaxf(v[2], v[3]));
      mx = fmaxf(mx, __shfl_xor(mx, 1, 64));
      mx = fmaxf(mx, __shfl_xor(mx, 2, 64));
      mx = fmaxf(mx, __shfl_xor(mx, 4, 64));
      mx = fmaxf(mx, __shfl_xor(mx, 8, 64));
      float p[4];
#pragma unroll
      for (int n = 0; n < 4; ++n) p[n] = nmv[n] * __expf(v[n] - mx);
      float s = (p[0] + p[1]) + (p[2] + p[3]);
      s += __shfl_xor(s, 1, 64);
      s += __shfl_xor(s, 2, 64);
      s += __shfl_xor(s, 4, 64);
      s += __shfl_xor(s, 8, 64);
      float f = nmq / s;
#pragma unroll
      for (int n = 0; n < 4; ++n) sc[n] += p[n] * f;
    }
#pragma unroll
  for (int n = 0; n < 4; ++n) {
    sc[n] += __shfl_xor(sc[n], 16, 64);
    sc[n] += __shfl_xor(sc[n], 32, 64);
  }
  if (hi == 0) {
#pragma unroll
    for (int n = 0; n < 4; ++n) s_sp[w][n * 16 + li] = sc[n];
  }
  __syncthreads();
  if (t < 256) {
    int hh = t >> 6, k = t & 63;
    s_score[hh][k] = (s_sp[hh * 2][k] + s_sp[hh * 2 + 1][k]) * s_nwinv;
  }
  __syncthreads();

  // ---- PV: wave w covers cols mh*128 + lane*2 (+1) of head h ----
  {
    int c0 = mh * 128 + lane * 2;
    int chunk = c0 >> 6;
    int cin = c0 & 63;
    int cg = cin >> 3, ce = cin & 7;
    const unsigned short* Xc = X2s + chunk * 4112;
    const float* sco = s_score[h];
    float o0 = 0.f, o1 = 0.f;
#pragma unroll
    for (int k = 0; k < 64; ++k) {
      float sk = sco[k];
      const unsigned short* p = Xc + k * 64 + ((cg ^ (k & 7)) * 8) + ce;
      o0 = fmaf(sk, bf2f(p[0]), o0);
      o1 = fmaf(sk, bf2f(p[1]), o1);
    }
    ushort2 ov; ov.x = f2bf(o0); ov.y = f2bf(o1);
    *(ushort2*)(svb + (size_t)b * 1024 + h * 256 + c0) = ov;
  }

  // ---- xmean: wave w sums cols [w*32, w*32+32); lane parity splits rows ----
  {
    int cidx = w * 32 + (lane & 31);
    int chunk = cidx >> 6, cin = cidx & 63;
    int cg = cin >> 3, ce = cin & 7;
    const unsigned short* Xc = X2s + chunk * 4112;
    int r0 = lane >> 5;               // 0 or 1
    float s = 0.f;
#pragma unroll
    for (int kk = 0; kk < 32; ++kk) {
      int k = r0 + kk * 2;
      s += bf2f(Xc[k * 64 + ((cg ^ (k & 7)) * 8) + ce]);
    }
    s += __shfl_xor(s, 32, 64);
    if (lane < 32)
      xmb[(size_t)b * 256 + cidx] = s * (1.0f / 64.0f) - posmean[cidx];
  }
}

// ---------------- fc GEMM (K-split x4): fco_part[z] = svb @ wfold^T over K-quarter z ----------------
__global__ __launch_bounds__(256) void fc_mfma_kernel(const unsigned short* aob,
                                                      const unsigned short* fc_wb,
                                                      float* fco) {
  __shared__ unsigned short As[64 * 64];
  __shared__ unsigned short Bs[64 * 64];
  int t = threadIdx.x, w = t >> 6, lane = t & 63;
  int li = lane & 15, hi = lane >> 4;
  int n0 = blockIdx.x * 64;
  int m0 = blockIdx.y * 64;
  int z = blockIdx.z;
  int r_in = lane >> 3, cb = (lane & 7) * 8;
  f32x4 acc[4] = {};
  for (int kt = z * 4; kt < z * 4 + 4; ++kt) {
#pragma unroll
    for (int it = 0; it < 2; ++it) {
      int rowblk = it * 32 + w * 8;
      gld16(aob + (size_t)(m0 + rowblk + r_in) * 1024 + kt * 64 + cb, As + rowblk * 64);
      gld16(fc_wb + (size_t)(n0 + rowblk + r_in) * 1024 + kt * 64 + cb, Bs + rowblk * 64);
    }
    __syncthreads();
#pragma unroll
    for (int kk = 0; kk < 2; ++kk) {
      bf16x8 bf = *(const bf16x8*)(Bs + (w * 16 + li) * 64 + kk * 32 + hi * 8);
#pragma unroll
      for (int m = 0; m < 4; ++m) {
        bf16x8 af = *(const bf16x8*)(As + (m * 16 + li) * 64 + kk * 32 + hi * 8);
        acc[m] = __builtin_amdgcn_mfma_f32_16x16x32_bf16(af, bf, acc[m], 0, 0, 0);
      }
    }
    __syncthreads();
  }
  int col = n0 + w * 16 + li;
  float* out = fco + (size_t)z * 262144;
#pragma unroll
  for (int m = 0; m < 4; ++m)
#pragma unroll
    for (int j = 0; j < 4; ++j)
      out[(size_t)(m0 + m * 16 + hi * 4 + j) * 256 + col] = acc[m][j];
}

// ---------------- final: sum fc partials + bias + xm + LN chain ----------------
__device__ __forceinline__ float block_ln(float v, int t, float eps, const float* g,
                                          const float* b, float* s_part) {
  int w = t >> 6, lane = t & 63;
  __syncthreads();
  float s = wred_sum(v), q = wred_sum(v * v);
  if (lane == 0) { s_part[w] = s; s_part[4 + w] = q; }
  __syncthreads();
  float sum = s_part[0] + s_part[1] + s_part[2] + s_part[3];
  float sq = s_part[4] + s_part[5] + s_part[6] + s_part[7];
  float mean = sum * (1.0f / 256.0f);
  float var = sq * (1.0f / 256.0f) - mean * mean;
  float rstd = rsqrtf(var + eps);
  return (v - mean) * rstd * g[t] + b[t];
}

__global__ __launch_bounds__(256) void final_kernel(
    const float* xmb, const float* fco, const float* fc_b,
    const float* sln_g, const float* sln_b, const float* ln1_g, const float* ln1_b,
    const float* ffln_g, const float* ffln_b, const float* ln2_g, const float* ln2_b,
    float* out) {
  __shared__ float s_part[8];
  int b = blockIdx.x, t = threadIdx.x;
  size_t o = (size_t)b * 256 + t;
  float xm = xmb[o];
  float v = fco[o] + fco[262144 + o] + fco[2 * 262144 + o] + fco[3 * 262144 + o] + fc_b[t];
  v = block_ln(v, t, 1e-5f, sln_g, sln_b, s_part);
  v = v + xm;
  v = block_ln(v, t, 1e-5f, ln1_g, ln1_b, s_part);
  float ff = block_ln(v, t, 1e-6f, ffln_g, ffln_b, s_part);
  float w2 = ff + v;
  float fin = block_ln(w2, t, 1e-5f, ln2_g, ln2_b, s_part);
  out[b * 256 + t] = fin;
}

extern "C" void kernel_launch(void* const* d_in, const int* in_sizes, int n_in,
                              void* d_out, int out_size, void* d_ws, size_t ws_size,
                              hipStream_t stream) {
  const int* char_code = (const int*)d_in[0];
  const float* emb    = (const float*)d_in[2];
  const float* qkv_w  = (const float*)d_in[3];
  const float* ln0_g  = (const float*)d_in[4];
  const float* ln0_b  = (const float*)d_in[5];
  const float* fc_w   = (const float*)d_in[6];
  const float* fc_b   = (const float*)d_in[7];
  const float* sln_g  = (const float*)d_in[8];
  const float* sln_b  = (const float*)d_in[9];
  const float* ln1_g  = (const float*)d_in[10];
  const float* ln1_b  = (const float*)d_in[11];
  const float* ffln_g = (const float*)d_in[16];
  const float* ffln_b = (const float*)d_in[17];
  const float* ln2_g  = (const float*)d_in[18];
  const float* ln2_b  = (const float*)d_in[19];

  float* ws = (float*)d_ws;
  float* posmean = ws;                                      // 256 f32
  unsigned short* x2tb  = (unsigned short*)(posmean + 256); // 8192*256
  unsigned short* yt    = x2tb + (size_t)8192 * 256;        // 8192*1024
  unsigned short* wqTb  = yt + (size_t)8192 * 1024;         // 4*256*256 (wq|wk|wv contiguous)
  unsigned short* wkTb  = wqTb + 262144;
  unsigned short* wvTb  = wkTb + 262144;
  unsigned short* fc_wb = wvTb + 262144;                    // 256*1024
  unsigned short* NTb   = fc_wb + 262144;                   // 4*256*256
  unsigned short* wfoldb= NTb + 262144;                     // 256*1024
  unsigned short* svb   = wfoldb + 262144;                  // 1024*1024
  float* fco = (float*)(svb + (size_t)1024 * 1024);         // 4 * 1024*256 f32
  float* xmb = fco + (size_t)4 * 262144;                    // 1024*256 f32

  prep_kernel<<<2497, 256, 0, stream>>>(qkv_w, fc_w, emb, ln0_g, ln0_b, posmean,
                                        fc_wb, wqTb, x2tb);
  gemm64x2_kernel<<<dim3(4, 4, 8), 256, 0, stream>>>(wkTb, wqTb, NTb, fc_wb, wvTb, wfoldb);
  gemm128_kernel<<<dim3(2, 64, 4), 256, 0, stream>>>(x2tb, NTb, yt);
  attn_kernel<<<1024, 512, 0, stream>>>(char_code, yt, x2tb, posmean, svb, xmb);
  fc_mfma_kernel<<<dim3(4, 16, 4), 256, 0, stream>>>(svb, wfoldb, fco);
  final_kernel<<<1024, 256, 0, stream>>>(xmb, fco, fc_b,
                                         sln_g, sln_b, ln1_g, ln1_b,
                                         ffln_g, ffln_b, ln2_g, ln2_b, (float*)d_out);
}

// Round 10
// 65.664 us; speedup vs baseline: 8.2226x; 1.0173x over previous
//
#include <hip/hip_runtime.h>

// Problem constants: V=128, E=256, H=4, B=1024, L=64
// Algebra: attn out folds V away: out = sv @ Wv^T, Wv folded into fc (W').
//          QK^T = Y @ x2^T with Y = X2 @ (Wq^T Wk) (NT precomputed, per head).
// 5 launches: prep (x2t + NT + wfold + posmean, all dependency-free block ranges)
//   -> gemm128 (Y) -> attn -> fc -> final.

typedef __attribute__((ext_vector_type(8))) short bf16x8;
typedef __attribute__((ext_vector_type(4))) float f32x4;

__device__ __forceinline__ float wred_sum(float v) {
#pragma unroll
  for (int off = 32; off > 0; off >>= 1) v += __shfl_xor(v, off, 64);
  return v;
}
__device__ __forceinline__ float bf2f(unsigned short u) {
  union { unsigned int i; float f; } x; x.i = ((unsigned int)u) << 16; return x.f;
}
__device__ __forceinline__ unsigned short f2bf(float f) {
  union { float f; unsigned int i; } x; x.f = f;
  unsigned int r = x.i + 0x7FFFu + ((x.i >> 16) & 1u);
  return (unsigned short)(r >> 16);
}
__device__ __forceinline__ void gld16(const unsigned short* g, unsigned short* l) {
  __builtin_amdgcn_global_load_lds(
      (const __attribute__((address_space(1))) unsigned int*)g,
      (__attribute__((address_space(3))) unsigned int*)l, 16, 0, 0);
}
// fast freq = 10000^(-i/128) = exp2(-i * log2(1e4)/128)
__device__ __forceinline__ float fast_freq(float i) {
  return exp2f(i * (-13.287712379549449f / 128.0f));
}

// ---------------- prep super-kernel ----------------
// blocks 0..63:    NT[h] tiles:    NT[h][e2][e1] = sum_i Wk[i,e2] Wq[i,e1]
// blocks 64..127:  wfold tiles:    wfold[o][h*256+e] = sum_e' fc_w[o][h*256+e'] Wv_h[e'][e]
// block 128:       posmean
// blocks 129..2176: x2t rows (4/block)
__global__ __launch_bounds__(256) void prep_kernel(const float* qkv_w, const float* fc_w,
                                                   const float* emb, const float* ln0_g,
                                                   const float* ln0_b, float* posmean,
                                                   unsigned short* NTb, unsigned short* wfoldb,
                                                   unsigned short* x2tb) {
  __shared__ float T[64][65];
  __shared__ unsigned short As[64 * 64];
  __shared__ unsigned short Bs[64 * 64];
  int bid = blockIdx.x, t = threadIdx.x;

  if (bid < 128) {
    // ---- small GEMM tile with self-staged (transposed) operands ----
    int w = t >> 6, lane = t & 63;
    int li = lane & 15, hi = lane >> 4;
    int r = t >> 4, c4 = (t & 15) * 4;
    bool isNT = bid < 64;
    int sub = isNT ? bid : bid - 64;
    int h = sub >> 4;
    int tm = (sub >> 2) & 3;          // output row tile (e2 for NT, o for wfold)
    int tn = sub & 3;                 // output col tile (e1 for NT, e for wfold)
    int m0 = tm * 64, n0 = tn * 64;
    f32x4 acc[4] = {};
    for (int kt = 0; kt < 4; ++kt) {
      int k0 = kt * 64;
      // ---- stage A ----
      if (isNT) {
        // A[e2][i] = Wk[i][e2]: transpose qkv_w rows (h*768+256+k0+il), cols (m0+c4)
        __syncthreads();
#pragma unroll
        for (int rep = 0; rep < 4; ++rep) {
          int il = rep * 16 + r;
          float4 v = *(const float4*)(qkv_w + (size_t)(h * 768 + 256 + k0 + il) * 256 + m0 + c4);
          T[il][c4] = v.x; T[il][c4 + 1] = v.y; T[il][c4 + 2] = v.z; T[il][c4 + 3] = v.w;
        }
        __syncthreads();
#pragma unroll
        for (int rep = 0; rep < 4; ++rep) {
          int el = rep * 16 + r;
          As[el * 64 + c4 + 0] = f2bf(T[c4 + 0][el]);
          As[el * 64 + c4 + 1] = f2bf(T[c4 + 1][el]);
          As[el * 64 + c4 + 2] = f2bf(T[c4 + 2][el]);
          As[el * 64 + c4 + 3] = f2bf(T[c4 + 3][el]);
        }
      } else {
        // A[o][e'] = fc_w[o0+o][h*256 + k0 + e']: direct cvt
        __syncthreads();
#pragma unroll
        for (int rep = 0; rep < 4; ++rep) {
          int rl = rep * 16 + r;
          float4 v = *(const float4*)(fc_w + (size_t)(m0 + rl) * 1024 + h * 256 + k0 + c4);
          As[rl * 64 + c4 + 0] = f2bf(v.x);
          As[rl * 64 + c4 + 1] = f2bf(v.y);
          As[rl * 64 + c4 + 2] = f2bf(v.z);
          As[rl * 64 + c4 + 3] = f2bf(v.w);
        }
      }
      // ---- stage B (transposed slice: sel=0 for Wq (NT), sel=512 for Wv (wfold)) ----
      {
        int sel = isNT ? 0 : 512;
        __syncthreads();
#pragma unroll
        for (int rep = 0; rep < 4; ++rep) {
          int il = rep * 16 + r;
          float4 v = *(const float4*)(qkv_w + (size_t)(h * 768 + sel + k0 + il) * 256 + n0 + c4);
          T[il][c4] = v.x; T[il][c4 + 1] = v.y; T[il][c4 + 2] = v.z; T[il][c4 + 3] = v.w;
        }
        __syncthreads();
#pragma unroll
        for (int rep = 0; rep < 4; ++rep) {
          int el = rep * 16 + r;
          Bs[el * 64 + c4 + 0] = f2bf(T[c4 + 0][el]);
          Bs[el * 64 + c4 + 1] = f2bf(T[c4 + 1][el]);
          Bs[el * 64 + c4 + 2] = f2bf(T[c4 + 2][el]);
          Bs[el * 64 + c4 + 3] = f2bf(T[c4 + 3][el]);
        }
      }
      __syncthreads();
      // ---- MFMA: wave w owns output cols w*16..+15 ----
#pragma unroll
      for (int kk = 0; kk < 2; ++kk) {
        bf16x8 bf = *(const bf16x8*)(Bs + (w * 16 + li) * 64 + kk * 32 + hi * 8);
#pragma unroll
        for (int m = 0; m < 4; ++m) {
          bf16x8 af = *(const bf16x8*)(As + (m * 16 + li) * 64 + kk * 32 + hi * 8);
          acc[m] = __builtin_amdgcn_mfma_f32_16x16x32_bf16(af, bf, acc[m], 0, 0, 0);
        }
      }
    }
    // ---- write C ----
    if (isNT) {
      unsigned short* C = NTb + (size_t)h * 65536;
      int col = n0 + w * 16 + li;
#pragma unroll
      for (int m = 0; m < 4; ++m)
#pragma unroll
        for (int j = 0; j < 4; ++j)
          C[(size_t)(m0 + m * 16 + hi * 4 + j) * 256 + col] = f2bf(acc[m][j]);
    } else {
      int col = h * 256 + n0 + w * 16 + li;
#pragma unroll
      for (int m = 0; m < 4; ++m)
#pragma unroll
        for (int j = 0; j < 4; ++j)
          wfoldb[(size_t)(m0 + m * 16 + hi * 4 + j) * 1024 + col] = f2bf(acc[m][j]);
    }
  } else if (bid == 128) {
    int e = t;
    float freq = fast_freq((float)(e >> 1));
    float s = 0.f;
    for (int l = 0; l < 64; ++l) {
      float ph = (float)l * freq;
      s += (e & 1) ? __cosf(ph) : __sinf(ph);
    }
    posmean[e] = s * (1.0f / 64.0f);
  } else {
    // x2t: bf16(LN0(emb[c]+pos[l]) + pos[l]); pos inline (fast trig)
    int w = t >> 6, lane = t & 63;
    int row = (bid - 129) * 4 + w;
    int c = row >> 6, l = row & 63;
    int e0 = lane * 4;
    float fr0 = fast_freq((float)(e0 >> 1));
    float fr1 = fast_freq((float)(e0 >> 1) + 1.0f);
    float p0 = (float)l * fr0, p1 = (float)l * fr1;
    float4 pv = make_float4(__sinf(p0), __cosf(p0), __sinf(p1), __cosf(p1));
    float4 ev = *(const float4*)(emb + c * 256 + e0);
    float v0 = ev.x + pv.x, v1 = ev.y + pv.y, v2 = ev.z + pv.z, v3 = ev.w + pv.w;
    float s = wred_sum(v0 + v1 + v2 + v3);
    float q = wred_sum(v0 * v0 + v1 * v1 + v2 * v2 + v3 * v3);
    float mean = s * (1.0f / 256.0f);
    float var = q * (1.0f / 256.0f) - mean * mean;
    float rstd = rsqrtf(var + 1e-5f);
    float4 gv = *(const float4*)(ln0_g + e0);
    float4 bv = *(const float4*)(ln0_b + e0);
    *(ushort4*)(x2tb + (size_t)row * 256 + e0) = make_ushort4(
        f2bf((v0 - mean) * rstd * gv.x + bv.x + pv.x),
        f2bf((v1 - mean) * rstd * gv.y + bv.y + pv.y),
        f2bf((v2 - mean) * rstd * gv.z + bv.z + pv.z),
        f2bf((v3 - mean) * rstd * gv.w + bv.w + pv.w));
  }
}

// ---------------- Y GEMM: yt[r][h*256+e2] = sum_e1 x2tb[r][e1] * NT[h][e2][e1] ----------------
__global__ __launch_bounds__(256) void gemm128_kernel(const unsigned short* A,
                                                      const unsigned short* B,
                                                      unsigned short* C) {
  __shared__ unsigned short S[2 * 128 * 64];
  unsigned short* As = S;
  unsigned short* Bs = S + 128 * 64;
  int t = threadIdx.x, w = t >> 6, lane = t & 63;
  int m0 = blockIdx.y * 128, n0 = blockIdx.x * 128, z = blockIdx.z;
  B += (size_t)z * 65536;
  int wr = w >> 1, wc = w & 1;
  f32x4 acc[4][4] = {};
  int r_in = lane >> 3, cb = (lane & 7) * 8;
  for (int kt = 0; kt < 4; ++kt) {
#pragma unroll
    for (int it = 0; it < 4; ++it) {
      int rowblk = it * 32 + w * 8;
      gld16(A + (size_t)(m0 + rowblk + r_in) * 256 + kt * 64 + cb, As + rowblk * 64);
      gld16(B + (size_t)(n0 + rowblk + r_in) * 256 + kt * 64 + cb, Bs + rowblk * 64);
    }
    __syncthreads();
#pragma unroll
    for (int kk = 0; kk < 2; ++kk) {
      bf16x8 af[4], bfr[4];
#pragma unroll
      for (int m = 0; m < 4; ++m)
        af[m] = *(const bf16x8*)(As + (wr * 64 + m * 16 + (lane & 15)) * 64 + kk * 32 + (lane >> 4) * 8);
#pragma unroll
      for (int n = 0; n < 4; ++n)
        bfr[n] = *(const bf16x8*)(Bs + (wc * 64 + n * 16 + (lane & 15)) * 64 + kk * 32 + (lane >> 4) * 8);
#pragma unroll
      for (int m = 0; m < 4; ++m)
#pragma unroll
        for (int n = 0; n < 4; ++n)
          acc[m][n] = __builtin_amdgcn_mfma_f32_16x16x32_bf16(af[m], bfr[n], acc[m][n], 0, 0, 0);
    }
    __syncthreads();
  }
  unsigned short* Cs = S;
#pragma unroll
  for (int m = 0; m < 4; ++m)
#pragma unroll
    for (int n = 0; n < 4; ++n) {
      int row = wr * 64 + m * 16 + ((lane >> 4)) * 4;
      int col = wc * 64 + n * 16 + (lane & 15);
#pragma unroll
      for (int j = 0; j < 4; ++j)
        Cs[(row + j) * 128 + col] = f2bf(acc[m][n][j]);
    }
  __syncthreads();
#pragma unroll
  for (int it = 0; it < 8; ++it) {
    int row = it * 16 + (t >> 4);
    int ce = (t & 15) * 8;
    *(bf16x8*)(C + (size_t)(m0 + row) * 1024 + z * 256 + n0 + ce) =
        *(const bf16x8*)(Cs + row * 128 + ce);
  }
}

// ---------------- attention: block = b (512 thr, 8 waves); wave = (head, q-half) ----------------
// No-max softmax (exp args bounded ~|10|); 3 barriers; emits sv + xmean.
__global__ __launch_bounds__(512, 4) void attn_kernel(const int* cc, const unsigned short* yt,
                                                      const unsigned short* x2tb,
                                                      const float* posmean,
                                                      unsigned short* svb, float* xmb) {
  __shared__ unsigned short X2s[4 * 4112];
  __shared__ float s_sp[8][64];
  __shared__ float s_nm[64];
  __shared__ int s_cc[64];
  __shared__ float s_nwinv;
  int b = blockIdx.x;
  int t = threadIdx.x, w = t >> 6, lane = t & 63;
  int li = lane & 15, hi = lane >> 4;
  int h = w >> 1, mh = w & 1;

  if (t < 64) {
    int c = cc[b * 64 + t];
    s_cc[t] = c;
    s_nm[t] = (c != 0) ? 1.0f : 0.0f;
  }
  __syncthreads();
  if (t < 64) {
    float s = wred_sum(s_nm[t]);
    if (t == 0) s_nwinv = 1.0f / s;
  }

  // ---- stage X2 once: wave w stages rows w*8..w*8+7 of each 64-col chunk ----
  int sr = lane >> 3;                 // row within 8-row group
  int sg = (lane & 7) ^ sr;           // inverse-swizzled source granule
  {
    int idx = w * 8 + sr;
    size_t rbase = (size_t)(s_cc[idx] * 64 + idx) * 256;
#pragma unroll
    for (int ecc = 0; ecc < 4; ++ecc)
      gld16(x2tb + rbase + ecc * 64 + sg * 8, X2s + ecc * 4112 + w * 512);
  }

  // per-lane Y row pointers for this wave's q-rows (head h, half mh)
  const unsigned short* rowp[2];
#pragma unroll
  for (int m = 0; m < 2; ++m) {
    int idx = mh * 32 + m * 16 + li;
    rowp[m] = yt + (size_t)(s_cc[idx] * 64 + idx) * 1024 + h * 256;
  }
  float nmv[4];
#pragma unroll
  for (int n = 0; n < 4; ++n) nmv[n] = s_nm[n * 16 + li];

  // preload Y chunks 0,1
  bf16x8 ybuf[4][4];
#pragma unroll
  for (int ec = 0; ec < 2; ++ec)
#pragma unroll
    for (int kk = 0; kk < 2; ++kk)
#pragma unroll
      for (int m = 0; m < 2; ++m)
        ybuf[ec][kk * 2 + m] = *(const bf16x8*)(rowp[m] + ec * 64 + kk * 32 + hi * 8);

  __syncthreads();   // X2s staged

  // ---- QK^T: 4 chunks; 2-chunk-ahead register prefetch, no barriers ----
  f32x4 acc[2][4] = {};
#pragma unroll
  for (int ec = 0; ec < 4; ++ec) {
    if (ec < 2) {
#pragma unroll
      for (int kk = 0; kk < 2; ++kk)
#pragma unroll
        for (int m = 0; m < 2; ++m)
          ybuf[ec + 2][kk * 2 + m] = *(const bf16x8*)(rowp[m] + (ec + 2) * 64 + kk * 32 + hi * 8);
    }
    __builtin_amdgcn_sched_barrier(0);
    __builtin_amdgcn_s_setprio(1);
#pragma unroll
    for (int kk = 0; kk < 2; ++kk)
#pragma unroll
      for (int n = 0; n < 4; ++n) {
        int rk = n * 16 + li;
        bf16x8 bf = *(const bf16x8*)(X2s + ec * 4112 + rk * 64 + (((kk * 4 + hi) ^ (rk & 7)) * 8));
#pragma unroll
        for (int m = 0; m < 2; ++m)
          acc[m][n] = __builtin_amdgcn_mfma_f32_16x16x32_bf16(ybuf[ec][kk * 2 + m], bf, acc[m][n], 0, 0, 0);
      }
    __builtin_amdgcn_s_setprio(0);
  }

  // ---- per-wave masked softmax (no max subtraction; exp args bounded) ----
  // acc[m][n][j]: q = mh*32 + m*16 + hi*4 + j, k = n*16 + li
  float sc[4] = {0.f, 0.f, 0.f, 0.f};
#pragma unroll
  for (int m = 0; m < 2; ++m)
#pragma unroll
    for (int j = 0; j < 4; ++j) {
      float nmq = s_nm[mh * 32 + m * 16 + hi * 4 + j];
      float p[4];
#pragma unroll
      for (int n = 0; n < 4; ++n) p[n] = nmv[n] * __expf(acc[m][n][j] * 0.0625f);
      float s = (p[0] + p[1]) + (p[2] + p[3]);
      s += __shfl_xor(s, 1, 64);
      s += __shfl_xor(s, 2, 64);
      s += __shfl_xor(s, 4, 64);
      s += __shfl_xor(s, 8, 64);
      float f = nmq / s;
#pragma unroll
      for (int n = 0; n < 4; ++n) sc[n] += p[n] * f;
    }
#pragma unroll
  for (int n = 0; n < 4; ++n) {
    sc[n] += __shfl_xor(sc[n], 16, 64);
    sc[n] += __shfl_xor(sc[n], 32, 64);
  }
  if (hi == 0) {
#pragma unroll
    for (int n = 0; n < 4; ++n) s_sp[w][n * 16 + li] = sc[n];
  }
  __syncthreads();   // s_sp published

  // ---- PV: wave w covers cols mh*128 + lane*2 (+1) of head h; fold partials inline ----
  {
    float nwinv = s_nwinv;
    int c0 = mh * 128 + lane * 2;
    int chunk = c0 >> 6;
    int cin = c0 & 63;
    int cg = cin >> 3, ce = cin & 7;
    const unsigned short* Xc = X2s + chunk * 4112;
    const float* spa = s_sp[h * 2];
    const float* spb = s_sp[h * 2 + 1];
    float o0 = 0.f, o1 = 0.f;
#pragma unroll
    for (int k = 0; k < 64; ++k) {
      float sk = (spa[k] + spb[k]) * nwinv;
      const unsigned short* p = Xc + k * 64 + ((cg ^ (k & 7)) * 8) + ce;
      o0 = fmaf(sk, bf2f(p[0]), o0);
      o1 = fmaf(sk, bf2f(p[1]), o1);
    }
    ushort2 ov; ov.x = f2bf(o0); ov.y = f2bf(o1);
    *(ushort2*)(svb + (size_t)b * 1024 + h * 256 + c0) = ov;
  }

  // ---- xmean: wave w sums cols [w*32, w*32+32); lane parity splits rows ----
  {
    int cidx = w * 32 + (lane & 31);
    int chunk = cidx >> 6, cin = cidx & 63;
    int cg = cin >> 3, ce = cin & 7;
    const unsigned short* Xc = X2s + chunk * 4112;
    int r0 = lane >> 5;               // 0 or 1
    float s = 0.f;
#pragma unroll
    for (int kk = 0; kk < 32; ++kk) {
      int k = r0 + kk * 2;
      s += bf2f(Xc[k * 64 + ((cg ^ (k & 7)) * 8) + ce]);
    }
    s += __shfl_xor(s, 32, 64);
    if (lane < 32)
      xmb[(size_t)b * 256 + cidx] = s * (1.0f / 64.0f) - posmean[cidx];
  }
}

// ---------------- fc GEMM (K-split x4): fco_part[z] = svb @ wfold^T over K-quarter z ----------------
__global__ __launch_bounds__(256) void fc_mfma_kernel(const unsigned short* aob,
                                                      const unsigned short* fc_wb,
                                                      float* fco) {
  __shared__ unsigned short As[64 * 64];
  __shared__ unsigned short Bs[64 * 64];
  int t = threadIdx.x, w = t >> 6, lane = t & 63;
  int li = lane & 15, hi = lane >> 4;
  int n0 = blockIdx.x * 64;
  int m0 = blockIdx.y * 64;
  int z = blockIdx.z;
  int r_in = lane >> 3, cb = (lane & 7) * 8;
  f32x4 acc[4] = {};
  for (int kt = z * 4; kt < z * 4 + 4; ++kt) {
#pragma unroll
    for (int it = 0; it < 2; ++it) {
      int rowblk = it * 32 + w * 8;
      gld16(aob + (size_t)(m0 + rowblk + r_in) * 1024 + kt * 64 + cb, As + rowblk * 64);
      gld16(fc_wb + (size_t)(n0 + rowblk + r_in) * 1024 + kt * 64 + cb, Bs + rowblk * 64);
    }
    __syncthreads();
#pragma unroll
    for (int kk = 0; kk < 2; ++kk) {
      bf16x8 bf = *(const bf16x8*)(Bs + (w * 16 + li) * 64 + kk * 32 + hi * 8);
#pragma unroll
      for (int m = 0; m < 4; ++m) {
        bf16x8 af = *(const bf16x8*)(As + (m * 16 + li) * 64 + kk * 32 + hi * 8);
        acc[m] = __builtin_amdgcn_mfma_f32_16x16x32_bf16(af, bf, acc[m], 0, 0, 0);
      }
    }
    __syncthreads();
  }
  int col = n0 + w * 16 + li;
  float* out = fco + (size_t)z * 262144;
#pragma unroll
  for (int m = 0; m < 4; ++m)
#pragma unroll
    for (int j = 0; j < 4; ++j)
      out[(size_t)(m0 + m * 16 + hi * 4 + j) * 256 + col] = acc[m][j];
}

// ---------------- final: sum fc partials + bias + xm + LN chain ----------------
__device__ __forceinline__ float block_ln(float v, int t, float eps, const float* g,
                                          const float* b, float* s_part) {
  int w = t >> 6, lane = t & 63;
  __syncthreads();
  float s = wred_sum(v), q = wred_sum(v * v);
  if (lane == 0) { s_part[w] = s; s_part[4 + w] = q; }
  __syncthreads();
  float sum = s_part[0] + s_part[1] + s_part[2] + s_part[3];
  float sq = s_part[4] + s_part[5] + s_part[6] + s_part[7];
  float mean = sum * (1.0f / 256.0f);
  float var = sq * (1.0f / 256.0f) - mean * mean;
  float rstd = rsqrtf(var + eps);
  return (v - mean) * rstd * g[t] + b[t];
}

__global__ __launch_bounds__(256) void final_kernel(
    const float* xmb, const float* fco, const float* fc_b,
    const float* sln_g, const float* sln_b, const float* ln1_g, const float* ln1_b,
    const float* ffln_g, const float* ffln_b, const float* ln2_g, const float* ln2_b,
    float* out) {
  __shared__ float s_part[8];
  int b = blockIdx.x, t = threadIdx.x;
  size_t o = (size_t)b * 256 + t;
  float xm = xmb[o];
  float v = fco[o] + fco[262144 + o] + fco[2 * 262144 + o] + fco[3 * 262144 + o] + fc_b[t];
  v = block_ln(v, t, 1e-5f, sln_g, sln_b, s_part);
  v = v + xm;
  v = block_ln(v, t, 1e-5f, ln1_g, ln1_b, s_part);
  float ff = block_ln(v, t, 1e-6f, ffln_g, ffln_b, s_part);
  float w2 = ff + v;
  float fin = block_ln(w2, t, 1e-5f, ln2_g, ln2_b, s_part);
  out[b * 256 + t] = fin;
}

extern "C" void kernel_launch(void* const* d_in, const int* in_sizes, int n_in,
                              void* d_out, int out_size, void* d_ws, size_t ws_size,
                              hipStream_t stream) {
  const int* char_code = (const int*)d_in[0];
  const float* emb    = (const float*)d_in[2];
  const float* qkv_w  = (const float*)d_in[3];
  const float* ln0_g  = (const float*)d_in[4];
  const float* ln0_b  = (const float*)d_in[5];
  const float* fc_w   = (const float*)d_in[6];
  const float* fc_b   = (const float*)d_in[7];
  const float* sln_g  = (const float*)d_in[8];
  const float* sln_b  = (const float*)d_in[9];
  const float* ln1_g  = (const float*)d_in[10];
  const float* ln1_b  = (const float*)d_in[11];
  const float* ffln_g = (const float*)d_in[16];
  const float* ffln_b = (const float*)d_in[17];
  const float* ln2_g  = (const float*)d_in[18];
  const float* ln2_b  = (const float*)d_in[19];

  float* ws = (float*)d_ws;
  float* posmean = ws;                                      // 256 f32
  unsigned short* x2tb  = (unsigned short*)(posmean + 256); // 8192*256
  unsigned short* yt    = x2tb + (size_t)8192 * 256;        // 8192*1024
  unsigned short* NTb   = yt + (size_t)8192 * 1024;         // 4*256*256
  unsigned short* wfoldb= NTb + 262144;                     // 256*1024
  unsigned short* svb   = wfoldb + 262144;                  // 1024*1024
  float* fco = (float*)(svb + (size_t)1024 * 1024);         // 4 * 1024*256 f32
  float* xmb = fco + (size_t)4 * 262144;                    // 1024*256 f32

  prep_kernel<<<2177, 256, 0, stream>>>(qkv_w, fc_w, emb, ln0_g, ln0_b, posmean,
                                        NTb, wfoldb, x2tb);
  gemm128_kernel<<<dim3(2, 64, 4), 256, 0, stream>>>(x2tb, NTb, yt);
  attn_kernel<<<1024, 512, 0, stream>>>(char_code, yt, x2tb, posmean, svb, xmb);
  fc_mfma_kernel<<<dim3(4, 16, 4), 256, 0, stream>>>(svb, wfoldb, fco);
  final_kernel<<<1024, 256, 0, stream>>>(xmb, fco, fc_b,
                                         sln_g, sln_b, ln1_g, ln1_b,
                                         ffln_g, ffln_b, ln2_g, ln2_b, (float*)d_out);
}